// Round 1
// baseline (13945.192 us; speedup 1.0000x reference)
//
#include <hip/hip_runtime.h>
#include <math.h>

#define NN 2048
#define EE 65536
#define T_OBS 6
#define FIN 2
#define HE 256
#define LT 128
#define PREDN 6
#define TM 8

// ---------------- sparse graph prep ----------------
__global__ void k_deg(const int* __restrict__ src, const float* __restrict__ ew,
                      float* __restrict__ deg) {
    int e = blockIdx.x * blockDim.x + threadIdx.x;
    if (e < EE) atomicAdd(&deg[src[e]], ew[e]);
}

__global__ void k_dinv(const float* __restrict__ deg, float* __restrict__ dinv) {
    int i = blockIdx.x * blockDim.x + threadIdx.x;
    if (i < NN) {
        float d = deg[i];
        dinv[i] = d > 0.f ? 1.f / sqrtf(d) : 0.f;
    }
}

__global__ void k_norm(const int* __restrict__ src, const int* __restrict__ dst,
                       const float* __restrict__ ew, const float* __restrict__ dinv,
                       float* __restrict__ nrm) {
    int e = blockIdx.x * blockDim.x + threadIdx.x;
    if (e < EE) nrm[e] = -dinv[src[e]] * ew[e] * dinv[dst[e]];
}

__global__ void k_count(const int* __restrict__ dst, int* __restrict__ cnt) {
    int e = blockIdx.x * blockDim.x + threadIdx.x;
    if (e < EE) atomicAdd(&cnt[dst[e]], 1);
}

// single block, 256 threads, scans NN=2048 counts -> row offsets + cursor copy
__global__ void k_scan(const int* __restrict__ cnt, int* __restrict__ roff,
                       int* __restrict__ cur) {
    __shared__ int part[256];
    int t = threadIdx.x;
    int loc[8];
    int s = 0;
#pragma unroll
    for (int i = 0; i < 8; i++) { loc[i] = cnt[t * 8 + i]; s += loc[i]; }
    part[t] = s;
    __syncthreads();
    for (int off = 1; off < 256; off <<= 1) {
        int v = (t >= off) ? part[t - off] : 0;
        __syncthreads();
        part[t] += v;
        __syncthreads();
    }
    int run = (t == 0) ? 0 : part[t - 1];
#pragma unroll
    for (int i = 0; i < 8; i++) {
        int idx = t * 8 + i;
        roff[idx] = run;
        cur[idx] = run;
        run += loc[i];
    }
    if (t == 255) roff[NN] = run;
}

__global__ void k_scatter(const int* __restrict__ dst, int* __restrict__ cur,
                          int* __restrict__ eids) {
    int e = blockIdx.x * blockDim.x + threadIdx.x;
    if (e < EE) {
        int p = atomicAdd(&cur[dst[e]], 1);
        eids[p] = e;
    }
}

// CSR SpMM: out[nid,f] = sum_{e: dst[e]==nid} nrm[e] * X[src[e], f]
template <int F>
__global__ void k_spmm(const int* __restrict__ roff, const int* __restrict__ eids,
                       const int* __restrict__ src, const float* __restrict__ nrm,
                       const float* __restrict__ X, float* __restrict__ out) {
    int nid = blockIdx.x;
    int f = threadIdx.x;
    if (f >= F) return;
    int s0 = roff[nid], s1 = roff[nid + 1];
    float acc = 0.f;
    for (int s = s0; s < s1; ++s) {
        int e = eids[s];
        acc = fmaf(nrm[e], X[src[e] * F + f], acc);
    }
    out[nid * F + f] = acc;
}

// ---------------- dense graph prep (rollout) ----------------
// coords == y_hat because MIN_X=0, MAX_X=1 (identity rescale); w = 2*d masked.
__global__ void k_ddeg(const float* __restrict__ c, float* __restrict__ deg) {
    int i = blockIdx.x;
    int t = threadIdx.x;
    float xi = c[2 * i], yi = c[2 * i + 1];
    float s = 0.f;
    for (int j = t; j < NN; j += 256) {
        float dx = xi - c[2 * j], dy = yi - c[2 * j + 1];
        float d = sqrtf(dx * dx + dy * dy);
        if (d > 0.f && d < 0.5f) s += 2.f * d;
    }
    __shared__ float red[256];
    red[t] = s;
    __syncthreads();
    for (int off = 128; off > 0; off >>= 1) {
        if (t < off) red[t] += red[t + off];
        __syncthreads();
    }
    if (t == 0) deg[i] = red[0];
}

__global__ void k_dM(const float* __restrict__ c, const float* __restrict__ dinv,
                     float* __restrict__ M) {
    int idx = blockIdx.x * blockDim.x + threadIdx.x;  // < NN*NN
    int i = idx >> 11, j = idx & (NN - 1);
    float dx = c[2 * i] - c[2 * j], dy = c[2 * i + 1] - c[2 * j + 1];
    float d = sqrtf(dx * dx + dy * dy);
    float w = (d > 0.f && d < 0.5f) ? 2.f * d : 0.f;
    M[idx] = -(dinv[i] * w) * dinv[j];
}

// dense agg: out = M @ X, X is [NN, F]; 8-row micro-tile per thread
template <int F>
__global__ void k_dmm(const float* __restrict__ M, const float* __restrict__ X,
                      float* __restrict__ out) {
    int f = threadIdx.x;
    int i0 = blockIdx.x * TM;
    float acc[TM];
#pragma unroll
    for (int m = 0; m < TM; m++) acc[m] = 0.f;
    for (int j = 0; j < NN; j++) {
        float b = X[j * F + f];
#pragma unroll
        for (int m = 0; m < TM; m++) acc[m] = fmaf(M[(i0 + m) * NN + j], b, acc[m]);
    }
#pragma unroll
    for (int m = 0; m < TM; m++) out[(i0 + m) * F + f] = acc[m];
}

// dense agg for F=2 (x = y_hat): block-per-row reduction, coalesced M reads
__global__ void k_dmv2(const float* __restrict__ M, const float* __restrict__ X,
                       float* __restrict__ out) {
    int i = blockIdx.x;
    int t = threadIdx.x;
    float a0 = 0.f, a1 = 0.f;
    for (int j = t; j < NN; j += 256) {
        float m = M[i * NN + j];
        a0 = fmaf(m, X[2 * j], a0);
        a1 = fmaf(m, X[2 * j + 1], a1);
    }
    __shared__ float r0[256], r1[256];
    r0[t] = a0;
    r1[t] = a1;
    __syncthreads();
    for (int off = 128; off > 0; off >>= 1) {
        if (t < off) { r0[t] += r0[t + off]; r1[t] += r1[t + off]; }
        __syncthreads();
    }
    if (t == 0) { out[2 * i] = r0[0]; out[2 * i + 1] = r1[0]; }
}

// ---------------- GRU gate kernels ----------------
// z and r gates fused (share all 4 A operands).
// pre_g = A0@Wx(g,0) + A1@Wx(g,1) + A2@Wh(g,0) + A3@Wh(g,1) + bx[g] + bh[g]
__global__ void k_gates01(const float* __restrict__ A0, int K0,
                          const float* __restrict__ A1, const float* __restrict__ A2,
                          const float* __restrict__ A3, const float* __restrict__ Wx,
                          const float* __restrict__ Wh, const float* __restrict__ bx,
                          const float* __restrict__ bh, float* __restrict__ gz,
                          float* __restrict__ gr) {
    int n = threadIdx.x;  // 256
    int m0 = blockIdx.x * TM;
    float az[TM], ar[TM];
    float bz = bx[n] + bh[n];
    float br = bx[HE + n] + bh[HE + n];
#pragma unroll
    for (int m = 0; m < TM; m++) { az[m] = bz; ar[m] = br; }

    const int WXG = 2 * K0 * HE;  // stride from gate0 slices to gate1 slices
    for (int k = 0; k < K0; k++) {
        float wz = Wx[k * HE + n];
        float wr = Wx[WXG + k * HE + n];
#pragma unroll
        for (int m = 0; m < TM; m++) {
            float a = A0[(m0 + m) * K0 + k];
            az[m] = fmaf(a, wz, az[m]);
            ar[m] = fmaf(a, wr, ar[m]);
        }
    }
    for (int k = 0; k < K0; k++) {
        float wz = Wx[K0 * HE + k * HE + n];
        float wr = Wx[WXG + K0 * HE + k * HE + n];
#pragma unroll
        for (int m = 0; m < TM; m++) {
            float a = A1[(m0 + m) * K0 + k];
            az[m] = fmaf(a, wz, az[m]);
            ar[m] = fmaf(a, wr, ar[m]);
        }
    }
    const int WHG = 2 * HE * HE;
    for (int k = 0; k < HE; k++) {
        float wz = Wh[k * HE + n];
        float wr = Wh[WHG + k * HE + n];
#pragma unroll
        for (int m = 0; m < TM; m++) {
            float a = A2[(m0 + m) * HE + k];
            az[m] = fmaf(a, wz, az[m]);
            ar[m] = fmaf(a, wr, ar[m]);
        }
    }
    for (int k = 0; k < HE; k++) {
        float wz = Wh[HE * HE + k * HE + n];
        float wr = Wh[WHG + HE * HE + k * HE + n];
#pragma unroll
        for (int m = 0; m < TM; m++) {
            float a = A3[(m0 + m) * HE + k];
            az[m] = fmaf(a, wz, az[m]);
            ar[m] = fmaf(a, wr, ar[m]);
        }
    }
#pragma unroll
    for (int m = 0; m < TM; m++) {
        gz[(m0 + m) * HE + n] = 1.f / (1.f + expf(-az[m]));
        gr[(m0 + m) * HE + n] = 1.f / (1.f + expf(-ar[m]));
    }
}

// candidate gate (tanh); explicit B pointers (gate-2 weight slices)
__global__ void k_gate_t(const float* __restrict__ A0, const float* __restrict__ B0, int K0,
                         const float* __restrict__ A1, const float* __restrict__ B1,
                         const float* __restrict__ A2, const float* __restrict__ B2,
                         const float* __restrict__ A3, const float* __restrict__ B3,
                         const float* __restrict__ b0, const float* __restrict__ b1,
                         float* __restrict__ out) {
    int n = threadIdx.x;
    int m0 = blockIdx.x * TM;
    float acc[TM];
    float base = b0[n] + b1[n];
#pragma unroll
    for (int m = 0; m < TM; m++) acc[m] = base;
    for (int k = 0; k < K0; k++) {
        float b = B0[k * HE + n];
#pragma unroll
        for (int m = 0; m < TM; m++) acc[m] = fmaf(A0[(m0 + m) * K0 + k], b, acc[m]);
    }
    for (int k = 0; k < K0; k++) {
        float b = B1[k * HE + n];
#pragma unroll
        for (int m = 0; m < TM; m++) acc[m] = fmaf(A1[(m0 + m) * K0 + k], b, acc[m]);
    }
    for (int k = 0; k < HE; k++) {
        float b = B2[k * HE + n];
#pragma unroll
        for (int m = 0; m < TM; m++) acc[m] = fmaf(A2[(m0 + m) * HE + k], b, acc[m]);
    }
    for (int k = 0; k < HE; k++) {
        float b = B3[k * HE + n];
#pragma unroll
        for (int m = 0; m < TM; m++) acc[m] = fmaf(A3[(m0 + m) * HE + k], b, acc[m]);
    }
#pragma unroll
    for (int m = 0; m < TM; m++) out[(m0 + m) * HE + n] = tanhf(acc[m]);
}

// z_lat = relu(H) @ elinW + elinb   ([NN,HE] @ [HE,LT])
__global__ void k_linrelu(const float* __restrict__ A, const float* __restrict__ B,
                          const float* __restrict__ bias, float* __restrict__ out) {
    int n = threadIdx.x;  // 128
    int m0 = blockIdx.x * TM;
    float acc[TM];
    float bb = bias[n];
#pragma unroll
    for (int m = 0; m < TM; m++) acc[m] = bb;
    for (int k = 0; k < HE; k++) {
        float b = B[k * LT + n];
#pragma unroll
        for (int m = 0; m < TM; m++) {
            float a = fmaxf(A[(m0 + m) * HE + k], 0.f);
            acc[m] = fmaf(a, b, acc[m]);
        }
    }
#pragma unroll
    for (int m = 0; m < TM; m++) out[(m0 + m) * LT + n] = acc[m];
}

// y_hat = relu(H) @ dlinW + dlinb   ([NN,HE] @ [HE,2])
__global__ void k_declin(const float* __restrict__ A, const float* __restrict__ B,
                         const float* __restrict__ bias, float* __restrict__ out) {
    int m = blockIdx.x * blockDim.x + threadIdx.x;
    if (m < NN) {
        float a0 = bias[0], a1 = bias[1];
        for (int k = 0; k < HE; k++) {
            float a = fmaxf(A[m * HE + k], 0.f);
            a0 = fmaf(a, B[2 * k], a0);
            a1 = fmaf(a, B[2 * k + 1], a1);
        }
        out[2 * m] = a0;
        out[2 * m + 1] = a1;
    }
}

__global__ void k_mul(const float* __restrict__ a, const float* __restrict__ b,
                      float* __restrict__ o) {
    int i = blockIdx.x * blockDim.x + threadIdx.x;
    if (i < NN * HE) o[i] = a[i] * b[i];
}

__global__ void k_hupd(const float* __restrict__ z, const float* __restrict__ ht,
                       float* __restrict__ H) {
    int i = blockIdx.x * blockDim.x + threadIdx.x;
    if (i < NN * HE) {
        float zz = z[i];
        H[i] = zz * H[i] + (1.f - zz) * ht[i];
    }
}

extern "C" void kernel_launch(void* const* d_in, const int* in_sizes, int n_in,
                              void* d_out, int out_size, void* d_ws, size_t ws_size,
                              hipStream_t stream) {
    (void)in_sizes; (void)n_in; (void)out_size; (void)ws_size;
    const float* x_seq = (const float*)d_in[0];
    const int* ei = (const int*)d_in[1];
    const float* ews = (const float*)d_in[2];
    const float* h_enc_in = (const float*)d_in[3];
    const float* h_dec_in = (const float*)d_in[4];
    const float* encWx = (const float*)d_in[5];
    const float* encbx = (const float*)d_in[6];
    const float* encWh = (const float*)d_in[7];
    const float* encbh = (const float*)d_in[8];
    const float* elinW = (const float*)d_in[9];
    const float* elinb = (const float*)d_in[10];
    const float* decWx = (const float*)d_in[11];
    const float* decbx = (const float*)d_in[12];
    const float* decWh = (const float*)d_in[13];
    const float* decbh = (const float*)d_in[14];
    const float* dlinW = (const float*)d_in[15];
    const float* dlinb = (const float*)d_in[16];
    float* out = (float*)d_out;

    // workspace carve-up (~37.3 MB)
    float* W = (float*)d_ws;
    float* h_enc = W; W += (size_t)NN * HE;
    float* h_dec = W; W += (size_t)NN * HE;
    float* aggx  = W; W += (size_t)NN * HE;
    float* aggh  = W; W += (size_t)NN * HE;
    float* hr    = W; W += (size_t)NN * HE;
    float* agghr = W; W += (size_t)NN * HE;
    float* gz    = W; W += (size_t)NN * HE;
    float* gr    = W; W += (size_t)NN * HE;
    float* ght   = W; W += (size_t)NN * HE;
    float* zlat  = W; W += (size_t)NN * LT;
    float* yhat  = W; W += (size_t)NN * FIN;
    float* deg   = W; W += NN;
    float* dinv  = W; W += NN;
    float* nrm   = W; W += EE;
    float* Mm    = W; W += (size_t)NN * NN;
    int* cnt  = (int*)W;
    int* roff = cnt + NN;
    int* cur  = roff + (NN + 2);
    int* eids = cur + NN;

    hipMemcpyAsync(h_enc, h_enc_in, sizeof(float) * NN * HE, hipMemcpyDeviceToDevice, stream);
    hipMemcpyAsync(h_dec, h_dec_in, sizeof(float) * NN * HE, hipMemcpyDeviceToDevice, stream);

    for (int step = 0; step < T_OBS + PREDN - 1; ++step) {
        bool sparse = step < T_OBS;
        const int* srcp = nullptr;
        const float* xin;
        if (sparse) {
            srcp = ei + (size_t)step * 2 * EE;
            const int* dstp = srcp + EE;
            const float* ewt = ews + (size_t)step * EE;
            hipMemsetAsync(deg, 0, sizeof(float) * NN, stream);
            hipMemsetAsync(cnt, 0, sizeof(int) * NN, stream);
            k_deg<<<EE / 256, 256, 0, stream>>>(srcp, ewt, deg);
            k_dinv<<<NN / 256, 256, 0, stream>>>(deg, dinv);
            k_norm<<<EE / 256, 256, 0, stream>>>(srcp, dstp, ewt, dinv, nrm);
            k_count<<<EE / 256, 256, 0, stream>>>(dstp, cnt);
            k_scan<<<1, 256, 0, stream>>>(cnt, roff, cur);
            k_scatter<<<EE / 256, 256, 0, stream>>>(dstp, cur, eids);
            xin = x_seq + (size_t)step * NN * FIN;
        } else {
            k_ddeg<<<NN, 256, 0, stream>>>(yhat, deg);
            k_dinv<<<NN / 256, 256, 0, stream>>>(deg, dinv);
            k_dM<<<(NN * NN) / 256, 256, 0, stream>>>(yhat, dinv, Mm);
            xin = yhat;
        }

        // ======= encoder GRU (x: F=2, H: h_enc) =======
        if (sparse) k_spmm<FIN><<<NN, 64, 0, stream>>>(roff, eids, srcp, nrm, xin, aggx);
        else        k_dmv2<<<NN, 256, 0, stream>>>(Mm, xin, aggx);
        if (sparse) k_spmm<HE><<<NN, HE, 0, stream>>>(roff, eids, srcp, nrm, h_enc, aggh);
        else        k_dmm<HE><<<NN / TM, HE, 0, stream>>>(Mm, h_enc, aggh);
        k_gates01<<<NN / TM, HE, 0, stream>>>(xin, FIN, aggx, h_enc, aggh,
                                              encWx, encWh, encbx, encbh, gz, gr);
        k_mul<<<NN * HE / 256, 256, 0, stream>>>(h_enc, gr, hr);
        if (sparse) k_spmm<HE><<<NN, HE, 0, stream>>>(roff, eids, srcp, nrm, hr, agghr);
        else        k_dmm<HE><<<NN / TM, HE, 0, stream>>>(Mm, hr, agghr);
        k_gate_t<<<NN / TM, HE, 0, stream>>>(
            xin, encWx + 4 * FIN * HE, FIN, aggx, encWx + 5 * FIN * HE,
            hr, encWh + 4 * HE * HE, agghr, encWh + 5 * HE * HE,
            encbx + 2 * HE, encbh + 2 * HE, ght);
        k_hupd<<<NN * HE / 256, 256, 0, stream>>>(gz, ght, h_enc);
        k_linrelu<<<NN / TM, LT, 0, stream>>>(h_enc, elinW, elinb, zlat);

        // ======= decoder GRU (x: zlat F=128, H: h_dec) =======
        if (sparse) k_spmm<LT><<<NN, LT, 0, stream>>>(roff, eids, srcp, nrm, zlat, aggx);
        else        k_dmm<LT><<<NN / TM, LT, 0, stream>>>(Mm, zlat, aggx);
        if (sparse) k_spmm<HE><<<NN, HE, 0, stream>>>(roff, eids, srcp, nrm, h_dec, aggh);
        else        k_dmm<HE><<<NN / TM, HE, 0, stream>>>(Mm, h_dec, aggh);
        k_gates01<<<NN / TM, HE, 0, stream>>>(zlat, LT, aggx, h_dec, aggh,
                                              decWx, decWh, decbx, decbh, gz, gr);
        k_mul<<<NN * HE / 256, 256, 0, stream>>>(h_dec, gr, hr);
        if (sparse) k_spmm<HE><<<NN, HE, 0, stream>>>(roff, eids, srcp, nrm, hr, agghr);
        else        k_dmm<HE><<<NN / TM, HE, 0, stream>>>(Mm, hr, agghr);
        k_gate_t<<<NN / TM, HE, 0, stream>>>(
            zlat, decWx + 4 * LT * HE, LT, aggx, decWx + 5 * LT * HE,
            hr, decWh + 4 * HE * HE, agghr, decWh + 5 * HE * HE,
            decbx + 2 * HE, decbh + 2 * HE, ght);
        k_hupd<<<NN * HE / 256, 256, 0, stream>>>(gz, ght, h_dec);
        k_declin<<<NN / 256, 256, 0, stream>>>(h_dec, dlinW, dlinb, yhat);

        if (step >= T_OBS - 1) {
            hipMemcpyAsync(out + (size_t)(step - (T_OBS - 1)) * NN * FIN, yhat,
                           sizeof(float) * NN * FIN, hipMemcpyDeviceToDevice, stream);
        }
    }
}

// Round 2
// 8561.724 us; speedup vs baseline: 1.6288x; 1.6288x over previous
//
#include <hip/hip_runtime.h>
#include <math.h>

#define NN 2048
#define EE 65536
#define T_OBS 6
#define FIN 2
#define HE 256
#define LT 128
#define PREDN 6
#define TM 8

// ---------------- sparse graph prep ----------------
__global__ void k_deg(const int* __restrict__ src, const float* __restrict__ ew,
                      float* __restrict__ deg) {
    int e = blockIdx.x * blockDim.x + threadIdx.x;
    if (e < EE) atomicAdd(&deg[src[e]], ew[e]);
}

__global__ void k_dinv(const float* __restrict__ deg, float* __restrict__ dinv) {
    int i = blockIdx.x * blockDim.x + threadIdx.x;
    if (i < NN) {
        float d = deg[i];
        dinv[i] = d > 0.f ? 1.f / sqrtf(d) : 0.f;
    }
}

__global__ void k_norm(const int* __restrict__ src, const int* __restrict__ dst,
                       const float* __restrict__ ew, const float* __restrict__ dinv,
                       float* __restrict__ nrm) {
    int e = blockIdx.x * blockDim.x + threadIdx.x;
    if (e < EE) nrm[e] = -dinv[src[e]] * ew[e] * dinv[dst[e]];
}

__global__ void k_count(const int* __restrict__ dst, int* __restrict__ cnt) {
    int e = blockIdx.x * blockDim.x + threadIdx.x;
    if (e < EE) atomicAdd(&cnt[dst[e]], 1);
}

// single block, 256 threads, scans NN=2048 counts -> row offsets + cursor copy
__global__ void k_scan(const int* __restrict__ cnt, int* __restrict__ roff,
                       int* __restrict__ cur) {
    __shared__ int part[256];
    int t = threadIdx.x;
    int loc[8];
    int s = 0;
#pragma unroll
    for (int i = 0; i < 8; i++) { loc[i] = cnt[t * 8 + i]; s += loc[i]; }
    part[t] = s;
    __syncthreads();
    for (int off = 1; off < 256; off <<= 1) {
        int v = (t >= off) ? part[t - off] : 0;
        __syncthreads();
        part[t] += v;
        __syncthreads();
    }
    int run = (t == 0) ? 0 : part[t - 1];
#pragma unroll
    for (int i = 0; i < 8; i++) {
        int idx = t * 8 + i;
        roff[idx] = run;
        cur[idx] = run;
        run += loc[i];
    }
    if (t == 255) roff[NN] = run;
}

__global__ void k_scatter(const int* __restrict__ dst, int* __restrict__ cur,
                          int* __restrict__ eids) {
    int e = blockIdx.x * blockDim.x + threadIdx.x;
    if (e < EE) {
        int p = atomicAdd(&cur[dst[e]], 1);
        eids[p] = e;
    }
}

// CSR SpMM: out[nid,f] = sum_{e: dst[e]==nid} nrm[e] * X[src[e], f]
template <int F>
__global__ void k_spmm(const int* __restrict__ roff, const int* __restrict__ eids,
                       const int* __restrict__ src, const float* __restrict__ nrm,
                       const float* __restrict__ X, float* __restrict__ out) {
    int nid = blockIdx.x;
    int f = threadIdx.x;
    if (f >= F) return;
    int s0 = roff[nid], s1 = roff[nid + 1];
    float acc = 0.f;
    for (int s = s0; s < s1; ++s) {
        int e = eids[s];
        acc = fmaf(nrm[e], X[src[e] * F + f], acc);
    }
    out[nid * F + f] = acc;
}

// ---------------- dense graph prep (rollout) ----------------
__global__ void k_ddeg(const float* __restrict__ c, float* __restrict__ deg) {
    int i = blockIdx.x;
    int t = threadIdx.x;
    float xi = c[2 * i], yi = c[2 * i + 1];
    float s = 0.f;
    for (int j = t; j < NN; j += 256) {
        float dx = xi - c[2 * j], dy = yi - c[2 * j + 1];
        float d = sqrtf(dx * dx + dy * dy);
        if (d > 0.f && d < 0.5f) s += 2.f * d;
    }
    __shared__ float red[256];
    red[t] = s;
    __syncthreads();
    for (int off = 128; off > 0; off >>= 1) {
        if (t < off) red[t] += red[t + off];
        __syncthreads();
    }
    if (t == 0) deg[i] = red[0];
}

__global__ void k_dM(const float* __restrict__ c, const float* __restrict__ dinv,
                     float* __restrict__ M) {
    int idx = blockIdx.x * blockDim.x + threadIdx.x;  // < NN*NN
    int i = idx >> 11, j = idx & (NN - 1);
    float dx = c[2 * i] - c[2 * j], dy = c[2 * i + 1] - c[2 * j + 1];
    float d = sqrtf(dx * dx + dy * dy);
    float w = (d > 0.f && d < 0.5f) ? 2.f * d : 0.f;
    M[idx] = -(dinv[i] * w) * dinv[j];
}

// dense agg: out = M @ X, X is [NN, F].
// Split-K GEMM: blockDim = 2*F (two K-groups of F threads), BM=8 rows/block.
// M tile staged in LDS via coalesced float4; X columns stream through L2.
template <int F>
__global__ void k_dmm(const float* __restrict__ M, const float* __restrict__ X,
                      float* __restrict__ out) {
    const int BM = 8, BK = 256;
    __shared__ float Mt[2][BM][BK];
    __shared__ float Pt[BM][F];
    const int f = threadIdx.x % F;
    const int kh = threadIdx.x / F;  // 0 or 1
    const int i0 = blockIdx.x * BM;
    float acc[BM];
#pragma unroll
    for (int r = 0; r < BM; r++) acc[r] = 0.f;

    for (int c = 0; c < NN / (2 * BK); ++c) {
        const int k0 = (2 * c + kh) * BK;
        // stage this group's M tile: BM*BK floats = BM*BK/4 float4s over F threads
#pragma unroll
        for (int x4 = f; x4 < BM * BK / 4; x4 += F) {
            int r = x4 >> 6;          // / (BK/4)
            int c4 = x4 & 63;         // % (BK/4)
            float4 v = *(const float4*)&M[(size_t)(i0 + r) * NN + k0 + c4 * 4];
            *(float4*)&Mt[kh][r][c4 * 4] = v;
        }
        __syncthreads();
#pragma unroll 8
        for (int k = 0; k < BK; k++) {
            float b = X[(k0 + k) * F + f];
#pragma unroll
            for (int r = 0; r < BM; r++) acc[r] = fmaf(Mt[kh][r][k], b, acc[r]);
        }
        __syncthreads();
    }
    if (kh == 1) {
#pragma unroll
        for (int r = 0; r < BM; r++) Pt[r][f] = acc[r];
    }
    __syncthreads();
    if (kh == 0) {
#pragma unroll
        for (int r = 0; r < BM; r++) out[(i0 + r) * F + f] = acc[r] + Pt[r][f];
    }
}

// dense agg for F=2 (x = y_hat): block-per-row reduction, coalesced M reads
__global__ void k_dmv2(const float* __restrict__ M, const float* __restrict__ X,
                       float* __restrict__ out) {
    int i = blockIdx.x;
    int t = threadIdx.x;
    float a0 = 0.f, a1 = 0.f;
    for (int j = t; j < NN; j += 256) {
        float m = M[i * NN + j];
        a0 = fmaf(m, X[2 * j], a0);
        a1 = fmaf(m, X[2 * j + 1], a1);
    }
    __shared__ float r0[256], r1[256];
    r0[t] = a0;
    r1[t] = a1;
    __syncthreads();
    for (int off = 128; off > 0; off >>= 1) {
        if (t < off) { r0[t] += r0[t + off]; r1[t] += r1[t + off]; }
        __syncthreads();
    }
    if (t == 0) { out[2 * i] = r0[0]; out[2 * i + 1] = r1[0]; }
}

// ---------------- GRU gate kernels ----------------
// z and r gates fused; also emits hr = H * sigmoid(r) directly (k_mul fused).
__global__ void k_gates01(const float* __restrict__ A0, int K0,
                          const float* __restrict__ A1, const float* __restrict__ A2,
                          const float* __restrict__ A3, const float* __restrict__ Wx,
                          const float* __restrict__ Wh, const float* __restrict__ bx,
                          const float* __restrict__ bh, float* __restrict__ gz,
                          float* __restrict__ hr) {
    int n = threadIdx.x;  // 256
    int m0 = blockIdx.x * TM;
    float az[TM], ar[TM];
    float bz = bx[n] + bh[n];
    float br = bx[HE + n] + bh[HE + n];
#pragma unroll
    for (int m = 0; m < TM; m++) { az[m] = bz; ar[m] = br; }

    const int WXG = 2 * K0 * HE;
    for (int k = 0; k < K0; k++) {
        float wz = Wx[k * HE + n];
        float wr = Wx[WXG + k * HE + n];
#pragma unroll
        for (int m = 0; m < TM; m++) {
            float a = A0[(m0 + m) * K0 + k];
            az[m] = fmaf(a, wz, az[m]);
            ar[m] = fmaf(a, wr, ar[m]);
        }
    }
    for (int k = 0; k < K0; k++) {
        float wz = Wx[K0 * HE + k * HE + n];
        float wr = Wx[WXG + K0 * HE + k * HE + n];
#pragma unroll
        for (int m = 0; m < TM; m++) {
            float a = A1[(m0 + m) * K0 + k];
            az[m] = fmaf(a, wz, az[m]);
            ar[m] = fmaf(a, wr, ar[m]);
        }
    }
    const int WHG = 2 * HE * HE;
    for (int k = 0; k < HE; k++) {
        float wz = Wh[k * HE + n];
        float wr = Wh[WHG + k * HE + n];
#pragma unroll
        for (int m = 0; m < TM; m++) {
            float a = A2[(m0 + m) * HE + k];
            az[m] = fmaf(a, wz, az[m]);
            ar[m] = fmaf(a, wr, ar[m]);
        }
    }
    for (int k = 0; k < HE; k++) {
        float wz = Wh[HE * HE + k * HE + n];
        float wr = Wh[WHG + HE * HE + k * HE + n];
#pragma unroll
        for (int m = 0; m < TM; m++) {
            float a = A3[(m0 + m) * HE + k];
            az[m] = fmaf(a, wz, az[m]);
            ar[m] = fmaf(a, wr, ar[m]);
        }
    }
#pragma unroll
    for (int m = 0; m < TM; m++) {
        gz[(m0 + m) * HE + n] = 1.f / (1.f + expf(-az[m]));
        float rr = 1.f / (1.f + expf(-ar[m]));
        hr[(m0 + m) * HE + n] = A2[(m0 + m) * HE + n] * rr;
    }
}

// candidate gate (tanh) + fused hidden-state update: H = z*H + (1-z)*h_tilde
__global__ void k_gate_t(const float* __restrict__ A0, const float* __restrict__ B0, int K0,
                         const float* __restrict__ A1, const float* __restrict__ B1,
                         const float* __restrict__ A2, const float* __restrict__ B2,
                         const float* __restrict__ A3, const float* __restrict__ B3,
                         const float* __restrict__ b0, const float* __restrict__ b1,
                         const float* __restrict__ gz, float* __restrict__ H) {
    int n = threadIdx.x;
    int m0 = blockIdx.x * TM;
    float acc[TM];
    float base = b0[n] + b1[n];
#pragma unroll
    for (int m = 0; m < TM; m++) acc[m] = base;
    for (int k = 0; k < K0; k++) {
        float b = B0[k * HE + n];
#pragma unroll
        for (int m = 0; m < TM; m++) acc[m] = fmaf(A0[(m0 + m) * K0 + k], b, acc[m]);
    }
    for (int k = 0; k < K0; k++) {
        float b = B1[k * HE + n];
#pragma unroll
        for (int m = 0; m < TM; m++) acc[m] = fmaf(A1[(m0 + m) * K0 + k], b, acc[m]);
    }
    for (int k = 0; k < HE; k++) {
        float b = B2[k * HE + n];
#pragma unroll
        for (int m = 0; m < TM; m++) acc[m] = fmaf(A2[(m0 + m) * HE + k], b, acc[m]);
    }
    for (int k = 0; k < HE; k++) {
        float b = B3[k * HE + n];
#pragma unroll
        for (int m = 0; m < TM; m++) acc[m] = fmaf(A3[(m0 + m) * HE + k], b, acc[m]);
    }
#pragma unroll
    for (int m = 0; m < TM; m++) {
        size_t idx = (size_t)(m0 + m) * HE + n;
        float z = gz[idx];
        H[idx] = z * H[idx] + (1.f - z) * tanhf(acc[m]);
    }
}

// z_lat = relu(H) @ elinW + elinb   ([NN,HE] @ [HE,LT])
__global__ void k_linrelu(const float* __restrict__ A, const float* __restrict__ B,
                          const float* __restrict__ bias, float* __restrict__ out) {
    int n = threadIdx.x;  // 128
    int m0 = blockIdx.x * TM;
    float acc[TM];
    float bb = bias[n];
#pragma unroll
    for (int m = 0; m < TM; m++) acc[m] = bb;
    for (int k = 0; k < HE; k++) {
        float b = B[k * LT + n];
#pragma unroll
        for (int m = 0; m < TM; m++) {
            float a = fmaxf(A[(m0 + m) * HE + k], 0.f);
            acc[m] = fmaf(a, b, acc[m]);
        }
    }
#pragma unroll
    for (int m = 0; m < TM; m++) out[(m0 + m) * LT + n] = acc[m];
}

// y_hat = relu(H) @ dlinW + dlinb   ([NN,HE] @ [HE,2])
__global__ void k_declin(const float* __restrict__ A, const float* __restrict__ B,
                         const float* __restrict__ bias, float* __restrict__ out) {
    int m = blockIdx.x * blockDim.x + threadIdx.x;
    if (m < NN) {
        float a0 = bias[0], a1 = bias[1];
        for (int k = 0; k < HE; k++) {
            float a = fmaxf(A[m * HE + k], 0.f);
            a0 = fmaf(a, B[2 * k], a0);
            a1 = fmaf(a, B[2 * k + 1], a1);
        }
        out[2 * m] = a0;
        out[2 * m + 1] = a1;
    }
}

extern "C" void kernel_launch(void* const* d_in, const int* in_sizes, int n_in,
                              void* d_out, int out_size, void* d_ws, size_t ws_size,
                              hipStream_t stream) {
    (void)in_sizes; (void)n_in; (void)out_size; (void)ws_size;
    const float* x_seq = (const float*)d_in[0];
    const int* ei = (const int*)d_in[1];
    const float* ews = (const float*)d_in[2];
    const float* h_enc_in = (const float*)d_in[3];
    const float* h_dec_in = (const float*)d_in[4];
    const float* encWx = (const float*)d_in[5];
    const float* encbx = (const float*)d_in[6];
    const float* encWh = (const float*)d_in[7];
    const float* encbh = (const float*)d_in[8];
    const float* elinW = (const float*)d_in[9];
    const float* elinb = (const float*)d_in[10];
    const float* decWx = (const float*)d_in[11];
    const float* decbx = (const float*)d_in[12];
    const float* decWh = (const float*)d_in[13];
    const float* decbh = (const float*)d_in[14];
    const float* dlinW = (const float*)d_in[15];
    const float* dlinb = (const float*)d_in[16];
    float* out = (float*)d_out;

    float* W = (float*)d_ws;
    float* h_enc = W; W += (size_t)NN * HE;
    float* h_dec = W; W += (size_t)NN * HE;
    float* aggx  = W; W += (size_t)NN * HE;
    float* aggh  = W; W += (size_t)NN * HE;
    float* hr    = W; W += (size_t)NN * HE;
    float* agghr = W; W += (size_t)NN * HE;
    float* gz    = W; W += (size_t)NN * HE;
    float* ght   = W; W += (size_t)NN * HE;  // spare
    float* zlat  = W; W += (size_t)NN * LT;
    float* yhat  = W; W += (size_t)NN * FIN;
    float* deg   = W; W += NN;
    float* dinv  = W; W += NN;
    float* nrm   = W; W += EE;
    float* Mm    = W; W += (size_t)NN * NN;
    int* cnt  = (int*)W;
    int* roff = cnt + NN;
    int* cur  = roff + (NN + 2);
    int* eids = cur + NN;
    (void)ght;

    hipMemcpyAsync(h_enc, h_enc_in, sizeof(float) * NN * HE, hipMemcpyDeviceToDevice, stream);
    hipMemcpyAsync(h_dec, h_dec_in, sizeof(float) * NN * HE, hipMemcpyDeviceToDevice, stream);

    for (int step = 0; step < T_OBS + PREDN - 1; ++step) {
        bool sparse = step < T_OBS;
        const int* srcp = nullptr;
        const float* xin;
        if (sparse) {
            srcp = ei + (size_t)step * 2 * EE;
            const int* dstp = srcp + EE;
            const float* ewt = ews + (size_t)step * EE;
            hipMemsetAsync(deg, 0, sizeof(float) * NN, stream);
            hipMemsetAsync(cnt, 0, sizeof(int) * NN, stream);
            k_deg<<<EE / 256, 256, 0, stream>>>(srcp, ewt, deg);
            k_dinv<<<NN / 256, 256, 0, stream>>>(deg, dinv);
            k_norm<<<EE / 256, 256, 0, stream>>>(srcp, dstp, ewt, dinv, nrm);
            k_count<<<EE / 256, 256, 0, stream>>>(dstp, cnt);
            k_scan<<<1, 256, 0, stream>>>(cnt, roff, cur);
            k_scatter<<<EE / 256, 256, 0, stream>>>(dstp, cur, eids);
            xin = x_seq + (size_t)step * NN * FIN;
        } else {
            k_ddeg<<<NN, 256, 0, stream>>>(yhat, deg);
            k_dinv<<<NN / 256, 256, 0, stream>>>(deg, dinv);
            k_dM<<<(NN * NN) / 256, 256, 0, stream>>>(yhat, dinv, Mm);
            xin = yhat;
        }

        // ======= encoder GRU (x: F=2, H: h_enc) =======
        if (sparse) k_spmm<FIN><<<NN, 64, 0, stream>>>(roff, eids, srcp, nrm, xin, aggx);
        else        k_dmv2<<<NN, 256, 0, stream>>>(Mm, xin, aggx);
        if (sparse) k_spmm<HE><<<NN, HE, 0, stream>>>(roff, eids, srcp, nrm, h_enc, aggh);
        else        k_dmm<HE><<<NN / TM, 2 * HE, 0, stream>>>(Mm, h_enc, aggh);
        k_gates01<<<NN / TM, HE, 0, stream>>>(xin, FIN, aggx, h_enc, aggh,
                                              encWx, encWh, encbx, encbh, gz, hr);
        if (sparse) k_spmm<HE><<<NN, HE, 0, stream>>>(roff, eids, srcp, nrm, hr, agghr);
        else        k_dmm<HE><<<NN / TM, 2 * HE, 0, stream>>>(Mm, hr, agghr);
        k_gate_t<<<NN / TM, HE, 0, stream>>>(
            xin, encWx + 4 * FIN * HE, FIN, aggx, encWx + 5 * FIN * HE,
            hr, encWh + 4 * HE * HE, agghr, encWh + 5 * HE * HE,
            encbx + 2 * HE, encbh + 2 * HE, gz, h_enc);
        k_linrelu<<<NN / TM, LT, 0, stream>>>(h_enc, elinW, elinb, zlat);

        // ======= decoder GRU (x: zlat F=128, H: h_dec) =======
        if (sparse) k_spmm<LT><<<NN, LT, 0, stream>>>(roff, eids, srcp, nrm, zlat, aggx);
        else        k_dmm<LT><<<NN / TM, 2 * LT, 0, stream>>>(Mm, zlat, aggx);
        if (sparse) k_spmm<HE><<<NN, HE, 0, stream>>>(roff, eids, srcp, nrm, h_dec, aggh);
        else        k_dmm<HE><<<NN / TM, 2 * HE, 0, stream>>>(Mm, h_dec, aggh);
        k_gates01<<<NN / TM, HE, 0, stream>>>(zlat, LT, aggx, h_dec, aggh,
                                              decWx, decWh, decbx, decbh, gz, hr);
        if (sparse) k_spmm<HE><<<NN, HE, 0, stream>>>(roff, eids, srcp, nrm, hr, agghr);
        else        k_dmm<HE><<<NN / TM, 2 * HE, 0, stream>>>(Mm, hr, agghr);
        k_gate_t<<<NN / TM, HE, 0, stream>>>(
            zlat, decWx + 4 * LT * HE, LT, aggx, decWx + 5 * LT * HE,
            hr, decWh + 4 * HE * HE, agghr, decWh + 5 * HE * HE,
            decbx + 2 * HE, decbh + 2 * HE, gz, h_dec);
        k_declin<<<NN / 256, 256, 0, stream>>>(h_dec, dlinW, dlinb, yhat);

        if (step >= T_OBS - 1) {
            hipMemcpyAsync(out + (size_t)(step - (T_OBS - 1)) * NN * FIN, yhat,
                           sizeof(float) * NN * FIN, hipMemcpyDeviceToDevice, stream);
        }
    }
}

// Round 3
// 5677.766 us; speedup vs baseline: 2.4561x; 1.5079x over previous
//
#include <hip/hip_runtime.h>
#include <math.h>

#define NN 2048
#define EE 65536
#define T_OBS 6
#define FIN 2
#define HE 256
#define LT 128
#define PREDN 6
#define TM 8
#define PAD 68

// ---------------- sparse graph prep ----------------
__global__ void k_deg(const int* __restrict__ src, const float* __restrict__ ew,
                      float* __restrict__ deg) {
    int e = blockIdx.x * blockDim.x + threadIdx.x;
    if (e < EE) atomicAdd(&deg[src[e]], ew[e]);
}

__global__ void k_dinv(const float* __restrict__ deg, float* __restrict__ dinv) {
    int i = blockIdx.x * blockDim.x + threadIdx.x;
    if (i < NN) {
        float d = deg[i];
        dinv[i] = d > 0.f ? 1.f / sqrtf(d) : 0.f;
    }
}

__global__ void k_norm(const int* __restrict__ src, const int* __restrict__ dst,
                       const float* __restrict__ ew, const float* __restrict__ dinv,
                       float* __restrict__ nrm) {
    int e = blockIdx.x * blockDim.x + threadIdx.x;
    if (e < EE) nrm[e] = -dinv[src[e]] * ew[e] * dinv[dst[e]];
}

__global__ void k_count(const int* __restrict__ dst, int* __restrict__ cnt) {
    int e = blockIdx.x * blockDim.x + threadIdx.x;
    if (e < EE) atomicAdd(&cnt[dst[e]], 1);
}

__global__ void k_scan(const int* __restrict__ cnt, int* __restrict__ roff,
                       int* __restrict__ cur) {
    __shared__ int part[256];
    int t = threadIdx.x;
    int loc[8];
    int s = 0;
#pragma unroll
    for (int i = 0; i < 8; i++) { loc[i] = cnt[t * 8 + i]; s += loc[i]; }
    part[t] = s;
    __syncthreads();
    for (int off = 1; off < 256; off <<= 1) {
        int v = (t >= off) ? part[t - off] : 0;
        __syncthreads();
        part[t] += v;
        __syncthreads();
    }
    int run = (t == 0) ? 0 : part[t - 1];
#pragma unroll
    for (int i = 0; i < 8; i++) {
        int idx = t * 8 + i;
        roff[idx] = run;
        cur[idx] = run;
        run += loc[i];
    }
    if (t == 255) roff[NN] = run;
}

__global__ void k_scatter(const int* __restrict__ dst, int* __restrict__ cur,
                          int* __restrict__ eids) {
    int e = blockIdx.x * blockDim.x + threadIdx.x;
    if (e < EE) {
        int p = atomicAdd(&cur[dst[e]], 1);
        eids[p] = e;
    }
}

template <int F>
__global__ void k_spmm(const int* __restrict__ roff, const int* __restrict__ eids,
                       const int* __restrict__ src, const float* __restrict__ nrm,
                       const float* __restrict__ X, float* __restrict__ out) {
    int nid = blockIdx.x;
    int f = threadIdx.x;
    if (f >= F) return;
    int s0 = roff[nid], s1 = roff[nid + 1];
    float acc = 0.f;
    for (int s = s0; s < s1; ++s) {
        int e = eids[s];
        acc = fmaf(nrm[e], X[src[e] * F + f], acc);
    }
    out[nid * F + f] = acc;
}

// ---------------- dense graph prep (rollout) ----------------
__global__ void k_ddeg(const float* __restrict__ c, float* __restrict__ deg) {
    int i = blockIdx.x;
    int t = threadIdx.x;
    float xi = c[2 * i], yi = c[2 * i + 1];
    float s = 0.f;
    for (int j = t; j < NN; j += 256) {
        float dx = xi - c[2 * j], dy = yi - c[2 * j + 1];
        float d = sqrtf(dx * dx + dy * dy);
        if (d > 0.f && d < 0.5f) s += 2.f * d;
    }
    __shared__ float red[256];
    red[t] = s;
    __syncthreads();
    for (int off = 128; off > 0; off >>= 1) {
        if (t < off) red[t] += red[t + off];
        __syncthreads();
    }
    if (t == 0) deg[i] = red[0];
}

__global__ void k_dM(const float* __restrict__ c, const float* __restrict__ dinv,
                     float* __restrict__ M) {
    int idx = blockIdx.x * blockDim.x + threadIdx.x;
    int i = idx >> 11, j = idx & (NN - 1);
    float dx = c[2 * i] - c[2 * j], dy = c[2 * i + 1] - c[2 * j + 1];
    float d = sqrtf(dx * dx + dy * dy);
    float w = (d > 0.f && d < 0.5f) ? 2.f * d : 0.f;
    M[idx] = -(dinv[i] * w) * dinv[j];
}

// dense agg: out = M @ X; split-K, LDS-staged M tiles.
template <int F>
__global__ void k_dmm(const float* __restrict__ M, const float* __restrict__ X,
                      float* __restrict__ out) {
    const int BM = 8, BK = 256;
    __shared__ float Mt[2][BM][BK];
    __shared__ float Pt[BM][F];
    const int f = threadIdx.x % F;
    const int kh = threadIdx.x / F;
    const int i0 = blockIdx.x * BM;
    float acc[BM];
#pragma unroll
    for (int r = 0; r < BM; r++) acc[r] = 0.f;

    for (int c = 0; c < NN / (2 * BK); ++c) {
        const int k0 = (2 * c + kh) * BK;
#pragma unroll
        for (int x4 = f; x4 < BM * BK / 4; x4 += F) {
            int r = x4 >> 6;
            int c4 = x4 & 63;
            float4 v = *(const float4*)&M[(size_t)(i0 + r) * NN + k0 + c4 * 4];
            *(float4*)&Mt[kh][r][c4 * 4] = v;
        }
        __syncthreads();
#pragma unroll 8
        for (int k = 0; k < BK; k++) {
            float b = X[(k0 + k) * F + f];
#pragma unroll
            for (int r = 0; r < BM; r++) acc[r] = fmaf(Mt[kh][r][k], b, acc[r]);
        }
        __syncthreads();
    }
    if (kh == 1) {
#pragma unroll
        for (int r = 0; r < BM; r++) Pt[r][f] = acc[r];
    }
    __syncthreads();
    if (kh == 0) {
#pragma unroll
        for (int r = 0; r < BM; r++) out[(i0 + r) * F + f] = acc[r] + Pt[r][f];
    }
}

__global__ void k_dmv2(const float* __restrict__ M, const float* __restrict__ X,
                       float* __restrict__ out) {
    int i = blockIdx.x;
    int t = threadIdx.x;
    float a0 = 0.f, a1 = 0.f;
    for (int j = t; j < NN; j += 256) {
        float m = M[i * NN + j];
        a0 = fmaf(m, X[2 * j], a0);
        a1 = fmaf(m, X[2 * j + 1], a1);
    }
    __shared__ float r0[256], r1[256];
    r0[t] = a0;
    r1[t] = a1;
    __syncthreads();
    for (int off = 128; off > 0; off >>= 1) {
        if (t < off) { r0[t] += r0[t + off]; r1[t] += r1[t + off]; }
        __syncthreads();
    }
    if (t == 0) { out[2 * i] = r0[0]; out[2 * i + 1] = r1[0]; }
}

// ---------------- tiled GEMM core for gate kernels ----------------
// Accumulates A[M,K] @ B[K,64-col-tile] into acc[4][4]. A staged transposed in
// LDS so both fragments are float4 LDS reads. B pre-offset to the column tile.
template <bool RELU>
__device__ __forceinline__ void gemm_seg(
    float (*At)[PAD], float (*Bt)[PAD],
    const float* __restrict__ A, int lda,
    const float* __restrict__ B, int ldb, int K,
    int m0, int tid, int tm, int tn, float (&acc)[4][4])
{
    for (int k0 = 0; k0 < K; k0 += 32) {
        int kc = K - k0;
        if (kc > 32) kc = 32;
        for (int i = tid; i < (kc << 4); i += 256) {
            int k = i >> 4, c4 = (i & 15) << 2;
            *(float4*)&Bt[k][c4] = *(const float4*)&B[(size_t)(k0 + k) * ldb + c4];
        }
        if (kc == 32) {
            for (int i = tid; i < 2048; i += 256) {
                int r = i >> 5, k = i & 31;
                float v = A[(size_t)(m0 + r) * lda + k0 + k];
                At[k][r] = RELU ? fmaxf(v, 0.f) : v;
            }
        } else {
            for (int i = tid; i < kc * 64; i += 256) {
                int r = i / kc, k = i - r * kc;
                float v = A[(size_t)(m0 + r) * lda + k0 + k];
                At[k][r] = RELU ? fmaxf(v, 0.f) : v;
            }
        }
        __syncthreads();
        if (kc == 32) {
#pragma unroll
            for (int k = 0; k < 32; k++) {
                float4 a = *(float4*)&At[k][tm << 2];
                float4 b = *(float4*)&Bt[k][tn << 2];
                float av[4] = {a.x, a.y, a.z, a.w};
                float bv[4] = {b.x, b.y, b.z, b.w};
#pragma unroll
                for (int i = 0; i < 4; i++)
#pragma unroll
                    for (int j = 0; j < 4; j++)
                        acc[i][j] = fmaf(av[i], bv[j], acc[i][j]);
            }
        } else {
            for (int k = 0; k < kc; k++) {
                float4 a = *(float4*)&At[k][tm << 2];
                float4 b = *(float4*)&Bt[k][tn << 2];
                float av[4] = {a.x, a.y, a.z, a.w};
                float bv[4] = {b.x, b.y, b.z, b.w};
#pragma unroll
                for (int i = 0; i < 4; i++)
#pragma unroll
                    for (int j = 0; j < 4; j++)
                        acc[i][j] = fmaf(av[i], bv[j], acc[i][j]);
            }
        }
        __syncthreads();
    }
}

// z & r gates: pre = x@Wx[g,0] + aggx@Wx[g,1] + H@Wh[g,0] + aggH@Wh[g,1] + b
// g=0 -> gz = sigmoid(pre); g=1 -> hr = H * sigmoid(pre)
__global__ __launch_bounds__(256) void k_gates01_g(
    const float* __restrict__ A0, int K01, const float* __restrict__ A1,
    const float* __restrict__ H, const float* __restrict__ A3,
    const float* __restrict__ Wx, const float* __restrict__ Wh,
    const float* __restrict__ bx, const float* __restrict__ bh,
    float* __restrict__ gz, float* __restrict__ hr)
{
    __shared__ float At[32][PAD], Bt[32][PAD];
    int tid = threadIdx.x, tn = tid & 15, tm = tid >> 4;
    int m0 = blockIdx.x << 6;
    int g = blockIdx.y >> 2;
    int n0 = (blockIdx.y & 3) << 6;
    float acc[4][4] = {};
    const float* Bx = Wx + (size_t)g * 2 * K01 * HE + n0;
    const float* Bh = Wh + (size_t)g * 2 * HE * HE + n0;
    gemm_seg<false>(At, Bt, A0, K01, Bx, HE, K01, m0, tid, tm, tn, acc);
    gemm_seg<false>(At, Bt, A1, K01, Bx + (size_t)K01 * HE, HE, K01, m0, tid, tm, tn, acc);
    gemm_seg<false>(At, Bt, H, HE, Bh, HE, HE, m0, tid, tm, tn, acc);
    gemm_seg<false>(At, Bt, A3, HE, Bh + HE * HE, HE, HE, m0, tid, tm, tn, acc);

    int c0 = n0 + (tn << 2);
    float bb[4];
#pragma unroll
    for (int j = 0; j < 4; j++) bb[j] = bx[g * HE + c0 + j] + bh[g * HE + c0 + j];
#pragma unroll
    for (int i = 0; i < 4; i++) {
        size_t idx = (size_t)(m0 + (tm << 2) + i) * HE + c0;
        float4 v;
        v.x = 1.f / (1.f + expf(-(acc[i][0] + bb[0])));
        v.y = 1.f / (1.f + expf(-(acc[i][1] + bb[1])));
        v.z = 1.f / (1.f + expf(-(acc[i][2] + bb[2])));
        v.w = 1.f / (1.f + expf(-(acc[i][3] + bb[3])));
        if (g == 0) {
            *(float4*)&gz[idx] = v;
        } else {
            float4 h = *(const float4*)&H[idx];
            v.x *= h.x; v.y *= h.y; v.z *= h.z; v.w *= h.w;
            *(float4*)&hr[idx] = v;
        }
    }
}

// candidate gate + hidden update: H = z*H + (1-z)*tanh(pre)
__global__ __launch_bounds__(256) void k_gate_t_g(
    const float* __restrict__ A0, int K01, const float* __restrict__ A1,
    const float* __restrict__ hr, const float* __restrict__ A3,
    const float* __restrict__ B0base, const float* __restrict__ B2base,
    const float* __restrict__ b0, const float* __restrict__ b1,
    const float* __restrict__ gz, float* __restrict__ H)
{
    __shared__ float At[32][PAD], Bt[32][PAD];
    int tid = threadIdx.x, tn = tid & 15, tm = tid >> 4;
    int m0 = blockIdx.x << 6;
    int n0 = blockIdx.y << 6;
    float acc[4][4] = {};
    gemm_seg<false>(At, Bt, A0, K01, B0base + n0, HE, K01, m0, tid, tm, tn, acc);
    gemm_seg<false>(At, Bt, A1, K01, B0base + (size_t)K01 * HE + n0, HE, K01, m0, tid, tm, tn, acc);
    gemm_seg<false>(At, Bt, hr, HE, B2base + n0, HE, HE, m0, tid, tm, tn, acc);
    gemm_seg<false>(At, Bt, A3, HE, B2base + (size_t)HE * HE + n0, HE, HE, m0, tid, tm, tn, acc);

    int c0 = n0 + (tn << 2);
    float bb[4];
#pragma unroll
    for (int j = 0; j < 4; j++) bb[j] = b0[c0 + j] + b1[c0 + j];
#pragma unroll
    for (int i = 0; i < 4; i++) {
        size_t idx = (size_t)(m0 + (tm << 2) + i) * HE + c0;
        float4 z = *(const float4*)&gz[idx];
        float4 h = *(const float4*)&H[idx];
        float4 o;
        o.x = z.x * h.x + (1.f - z.x) * tanhf(acc[i][0] + bb[0]);
        o.y = z.y * h.y + (1.f - z.y) * tanhf(acc[i][1] + bb[1]);
        o.z = z.z * h.z + (1.f - z.z) * tanhf(acc[i][2] + bb[2]);
        o.w = z.w * h.w + (1.f - z.w) * tanhf(acc[i][3] + bb[3]);
        *(float4*)&H[idx] = o;
    }
}

// z_lat = relu(H) @ elinW + elinb
__global__ __launch_bounds__(256) void k_linrelu_g(
    const float* __restrict__ A, const float* __restrict__ B,
    const float* __restrict__ bias, float* __restrict__ out)
{
    __shared__ float At[32][PAD], Bt[32][PAD];
    int tid = threadIdx.x, tn = tid & 15, tm = tid >> 4;
    int m0 = blockIdx.x << 6;
    int n0 = blockIdx.y << 6;
    float acc[4][4] = {};
    gemm_seg<true>(At, Bt, A, HE, B + n0, LT, HE, m0, tid, tm, tn, acc);

    int c0 = n0 + (tn << 2);
    float bb[4];
#pragma unroll
    for (int j = 0; j < 4; j++) bb[j] = bias[c0 + j];
#pragma unroll
    for (int i = 0; i < 4; i++) {
        size_t idx = (size_t)(m0 + (tm << 2) + i) * LT + c0;
        float4 o;
        o.x = acc[i][0] + bb[0];
        o.y = acc[i][1] + bb[1];
        o.z = acc[i][2] + bb[2];
        o.w = acc[i][3] + bb[3];
        *(float4*)&out[idx] = o;
    }
}

// y_hat = relu(H) @ dlinW + dlinb   ([NN,HE] @ [HE,2])
__global__ void k_declin(const float* __restrict__ A, const float* __restrict__ B,
                         const float* __restrict__ bias, float* __restrict__ out) {
    int m = blockIdx.x * blockDim.x + threadIdx.x;
    if (m < NN) {
        float a0 = bias[0], a1 = bias[1];
        for (int k = 0; k < HE; k++) {
            float a = fmaxf(A[m * HE + k], 0.f);
            a0 = fmaf(a, B[2 * k], a0);
            a1 = fmaf(a, B[2 * k + 1], a1);
        }
        out[2 * m] = a0;
        out[2 * m + 1] = a1;
    }
}

extern "C" void kernel_launch(void* const* d_in, const int* in_sizes, int n_in,
                              void* d_out, int out_size, void* d_ws, size_t ws_size,
                              hipStream_t stream) {
    (void)in_sizes; (void)n_in; (void)out_size; (void)ws_size;
    const float* x_seq = (const float*)d_in[0];
    const int* ei = (const int*)d_in[1];
    const float* ews = (const float*)d_in[2];
    const float* h_enc_in = (const float*)d_in[3];
    const float* h_dec_in = (const float*)d_in[4];
    const float* encWx = (const float*)d_in[5];
    const float* encbx = (const float*)d_in[6];
    const float* encWh = (const float*)d_in[7];
    const float* encbh = (const float*)d_in[8];
    const float* elinW = (const float*)d_in[9];
    const float* elinb = (const float*)d_in[10];
    const float* decWx = (const float*)d_in[11];
    const float* decbx = (const float*)d_in[12];
    const float* decWh = (const float*)d_in[13];
    const float* decbh = (const float*)d_in[14];
    const float* dlinW = (const float*)d_in[15];
    const float* dlinb = (const float*)d_in[16];
    float* out = (float*)d_out;

    float* W = (float*)d_ws;
    float* h_enc = W; W += (size_t)NN * HE;
    float* h_dec = W; W += (size_t)NN * HE;
    float* aggx  = W; W += (size_t)NN * HE;
    float* aggh  = W; W += (size_t)NN * HE;
    float* hr    = W; W += (size_t)NN * HE;
    float* agghr = W; W += (size_t)NN * HE;
    float* gz    = W; W += (size_t)NN * HE;
    float* zlat  = W; W += (size_t)NN * LT;
    float* yhat  = W; W += (size_t)NN * FIN;
    float* deg   = W; W += NN;
    float* dinv  = W; W += NN;
    float* nrm   = W; W += EE;
    float* Mm    = W; W += (size_t)NN * NN;
    int* cnt  = (int*)W;
    int* roff = cnt + NN;
    int* cur  = roff + (NN + 2);
    int* eids = cur + NN;

    hipMemcpyAsync(h_enc, h_enc_in, sizeof(float) * NN * HE, hipMemcpyDeviceToDevice, stream);
    hipMemcpyAsync(h_dec, h_dec_in, sizeof(float) * NN * HE, hipMemcpyDeviceToDevice, stream);

    for (int step = 0; step < T_OBS + PREDN - 1; ++step) {
        bool sparse = step < T_OBS;
        const int* srcp = nullptr;
        const float* xin;
        if (sparse) {
            srcp = ei + (size_t)step * 2 * EE;
            const int* dstp = srcp + EE;
            const float* ewt = ews + (size_t)step * EE;
            hipMemsetAsync(deg, 0, sizeof(float) * NN, stream);
            hipMemsetAsync(cnt, 0, sizeof(int) * NN, stream);
            k_deg<<<EE / 256, 256, 0, stream>>>(srcp, ewt, deg);
            k_dinv<<<NN / 256, 256, 0, stream>>>(deg, dinv);
            k_norm<<<EE / 256, 256, 0, stream>>>(srcp, dstp, ewt, dinv, nrm);
            k_count<<<EE / 256, 256, 0, stream>>>(dstp, cnt);
            k_scan<<<1, 256, 0, stream>>>(cnt, roff, cur);
            k_scatter<<<EE / 256, 256, 0, stream>>>(dstp, cur, eids);
            xin = x_seq + (size_t)step * NN * FIN;
        } else {
            k_ddeg<<<NN, 256, 0, stream>>>(yhat, deg);
            k_dinv<<<NN / 256, 256, 0, stream>>>(deg, dinv);
            k_dM<<<(NN * NN) / 256, 256, 0, stream>>>(yhat, dinv, Mm);
            xin = yhat;
        }

        // ======= encoder GRU (x: F=2, H: h_enc) =======
        if (sparse) k_spmm<FIN><<<NN, 64, 0, stream>>>(roff, eids, srcp, nrm, xin, aggx);
        else        k_dmv2<<<NN, 256, 0, stream>>>(Mm, xin, aggx);
        if (sparse) k_spmm<HE><<<NN, HE, 0, stream>>>(roff, eids, srcp, nrm, h_enc, aggh);
        else        k_dmm<HE><<<NN / TM, 2 * HE, 0, stream>>>(Mm, h_enc, aggh);
        {
            dim3 g(NN / 64, 8);
            k_gates01_g<<<g, 256, 0, stream>>>(xin, FIN, aggx, h_enc, aggh,
                                               encWx, encWh, encbx, encbh, gz, hr);
        }
        if (sparse) k_spmm<HE><<<NN, HE, 0, stream>>>(roff, eids, srcp, nrm, hr, agghr);
        else        k_dmm<HE><<<NN / TM, 2 * HE, 0, stream>>>(Mm, hr, agghr);
        {
            dim3 g(NN / 64, 4);
            k_gate_t_g<<<g, 256, 0, stream>>>(xin, FIN, aggx, hr, agghr,
                                              encWx + 4 * FIN * HE, encWh + 4 * HE * HE,
                                              encbx + 2 * HE, encbh + 2 * HE, gz, h_enc);
        }
        {
            dim3 g(NN / 64, 2);
            k_linrelu_g<<<g, 256, 0, stream>>>(h_enc, elinW, elinb, zlat);
        }

        // ======= decoder GRU (x: zlat F=128, H: h_dec) =======
        if (sparse) k_spmm<LT><<<NN, LT, 0, stream>>>(roff, eids, srcp, nrm, zlat, aggx);
        else        k_dmm<LT><<<NN / TM, 2 * LT, 0, stream>>>(Mm, zlat, aggx);
        if (sparse) k_spmm<HE><<<NN, HE, 0, stream>>>(roff, eids, srcp, nrm, h_dec, aggh);
        else        k_dmm<HE><<<NN / TM, 2 * HE, 0, stream>>>(Mm, h_dec, aggh);
        {
            dim3 g(NN / 64, 8);
            k_gates01_g<<<g, 256, 0, stream>>>(zlat, LT, aggx, h_dec, aggh,
                                               decWx, decWh, decbx, decbh, gz, hr);
        }
        if (sparse) k_spmm<HE><<<NN, HE, 0, stream>>>(roff, eids, srcp, nrm, hr, agghr);
        else        k_dmm<HE><<<NN / TM, 2 * HE, 0, stream>>>(Mm, hr, agghr);
        {
            dim3 g(NN / 64, 4);
            k_gate_t_g<<<g, 256, 0, stream>>>(zlat, LT, aggx, hr, agghr,
                                              decWx + 4 * LT * HE, decWh + 4 * HE * HE,
                                              decbx + 2 * HE, decbh + 2 * HE, gz, h_dec);
        }
        k_declin<<<NN / 256, 256, 0, stream>>>(h_dec, dlinW, dlinb, yhat);

        if (step >= T_OBS - 1) {
            hipMemcpyAsync(out + (size_t)(step - (T_OBS - 1)) * NN * FIN, yhat,
                           sizeof(float) * NN * FIN, hipMemcpyDeviceToDevice, stream);
        }
    }
}

// Round 4
// 5292.073 us; speedup vs baseline: 2.6351x; 1.0729x over previous
//
#include <hip/hip_runtime.h>
#include <math.h>

#define NN 2048
#define EE 65536
#define T_OBS 6
#define FIN 2
#define HE 256
#define LT 128
#define PREDN 6
#define PAD 68
#define KS 4

// ---------------- sparse graph prep ----------------
__global__ void k_deg(const int* __restrict__ src, const float* __restrict__ ew,
                      float* __restrict__ deg) {
    int e = blockIdx.x * blockDim.x + threadIdx.x;
    if (e < EE) atomicAdd(&deg[src[e]], ew[e]);
}

__global__ void k_dinv(const float* __restrict__ deg, float* __restrict__ dinv) {
    int i = blockIdx.x * blockDim.x + threadIdx.x;
    if (i < NN) {
        float d = deg[i];
        dinv[i] = d > 0.f ? 1.f / sqrtf(d) : 0.f;
    }
}

__global__ void k_norm(const int* __restrict__ src, const int* __restrict__ dst,
                       const float* __restrict__ ew, const float* __restrict__ dinv,
                       float* __restrict__ nrm) {
    int e = blockIdx.x * blockDim.x + threadIdx.x;
    if (e < EE) nrm[e] = -dinv[src[e]] * ew[e] * dinv[dst[e]];
}

__global__ void k_count(const int* __restrict__ dst, int* __restrict__ cnt) {
    int e = blockIdx.x * blockDim.x + threadIdx.x;
    if (e < EE) atomicAdd(&cnt[dst[e]], 1);
}

__global__ void k_scan(const int* __restrict__ cnt, int* __restrict__ roff,
                       int* __restrict__ cur) {
    __shared__ int part[256];
    int t = threadIdx.x;
    int loc[8];
    int s = 0;
#pragma unroll
    for (int i = 0; i < 8; i++) { loc[i] = cnt[t * 8 + i]; s += loc[i]; }
    part[t] = s;
    __syncthreads();
    for (int off = 1; off < 256; off <<= 1) {
        int v = (t >= off) ? part[t - off] : 0;
        __syncthreads();
        part[t] += v;
        __syncthreads();
    }
    int run = (t == 0) ? 0 : part[t - 1];
#pragma unroll
    for (int i = 0; i < 8; i++) {
        int idx = t * 8 + i;
        roff[idx] = run;
        cur[idx] = run;
        run += loc[i];
    }
    if (t == 255) roff[NN] = run;
}

__global__ void k_scatter(const int* __restrict__ dst, int* __restrict__ cur,
                          int* __restrict__ eids) {
    int e = blockIdx.x * blockDim.x + threadIdx.x;
    if (e < EE) {
        int p = atomicAdd(&cur[dst[e]], 1);
        eids[p] = e;
    }
}

template <int F>
__global__ void k_spmm(const int* __restrict__ roff, const int* __restrict__ eids,
                       const int* __restrict__ src, const float* __restrict__ nrm,
                       const float* __restrict__ X, float* __restrict__ out) {
    int nid = blockIdx.x;
    int f = threadIdx.x;
    if (f >= F) return;
    int s0 = roff[nid], s1 = roff[nid + 1];
    float acc = 0.f;
    for (int s = s0; s < s1; ++s) {
        int e = eids[s];
        acc = fmaf(nrm[e], X[src[e] * F + f], acc);
    }
    out[nid * F + f] = acc;
}

// ---------------- dense graph prep (rollout) ----------------
__global__ void k_ddeg(const float* __restrict__ c, float* __restrict__ deg) {
    int i = blockIdx.x;
    int t = threadIdx.x;
    float xi = c[2 * i], yi = c[2 * i + 1];
    float s = 0.f;
    for (int j = t; j < NN; j += 256) {
        float dx = xi - c[2 * j], dy = yi - c[2 * j + 1];
        float d = sqrtf(dx * dx + dy * dy);
        if (d > 0.f && d < 0.5f) s += 2.f * d;
    }
    __shared__ float red[256];
    red[t] = s;
    __syncthreads();
    for (int off = 128; off > 0; off >>= 1) {
        if (t < off) red[t] += red[t + off];
        __syncthreads();
    }
    if (t == 0) deg[i] = red[0];
}

__global__ void k_dM(const float* __restrict__ c, const float* __restrict__ dinv,
                     float* __restrict__ M) {
    int idx = blockIdx.x * blockDim.x + threadIdx.x;
    int i = idx >> 11, j = idx & (NN - 1);
    float dx = c[2 * i] - c[2 * j], dy = c[2 * i + 1] - c[2 * j + 1];
    float d = sqrtf(dx * dx + dy * dy);
    float w = (d > 0.f && d < 0.5f) ? 2.f * d : 0.f;
    M[idx] = -(dinv[i] * w) * dinv[j];
}

// dense agg: out = M @ X via K-split tiled GEMM.
// grid (NN/64, F/64, KS), 256 threads, 64x64 tile, 4x4 micro-tile,
// both operands LDS-staged; partial per K-slice to pbuf.
template <int F>
__global__ __launch_bounds__(256) void k_dmm_ks(
    const float* __restrict__ M, const float* __restrict__ X,
    float* __restrict__ pbuf)
{
    __shared__ float At[32][PAD], Bt[32][PAD];
    const int tid = threadIdx.x, tn = tid & 15, tm = tid >> 4;
    const int m0 = blockIdx.x << 6;
    const int n0 = blockIdx.y << 6;
    const int kb = blockIdx.z * (NN / KS);
    float acc[4][4] = {};
    for (int k0 = kb; k0 < kb + NN / KS; k0 += 32) {
        for (int i = tid; i < 2048; i += 256) {
            int r = i >> 5, k = i & 31;
            At[k][r] = M[(size_t)(m0 + r) * NN + k0 + k];
        }
        for (int i = tid; i < 512; i += 256) {
            int k = i >> 4, c4 = (i & 15) << 2;
            *(float4*)&Bt[k][c4] = *(const float4*)&X[(size_t)(k0 + k) * F + n0 + c4];
        }
        __syncthreads();
#pragma unroll
        for (int k = 0; k < 32; k++) {
            float4 a = *(float4*)&At[k][tm << 2];
            float4 b = *(float4*)&Bt[k][tn << 2];
            float av[4] = {a.x, a.y, a.z, a.w};
            float bv[4] = {b.x, b.y, b.z, b.w};
#pragma unroll
            for (int i = 0; i < 4; i++)
#pragma unroll
                for (int j = 0; j < 4; j++)
                    acc[i][j] = fmaf(av[i], bv[j], acc[i][j]);
        }
        __syncthreads();
    }
    float* p = pbuf + (size_t)blockIdx.z * NN * F;
#pragma unroll
    for (int i = 0; i < 4; i++) {
        *(float4*)&p[(size_t)(m0 + (tm << 2) + i) * F + n0 + (tn << 2)] =
            make_float4(acc[i][0], acc[i][1], acc[i][2], acc[i][3]);
    }
}

template <int F>
__global__ void k_redks(const float* __restrict__ pbuf, float* __restrict__ out) {
    const int TOT = NN * F / 4;
    int i = blockIdx.x * blockDim.x + threadIdx.x;
    if (i < TOT) {
        const float4* p = (const float4*)pbuf;
        float4 s = p[i];
        float4 b = p[TOT + i];
        float4 c = p[2 * TOT + i];
        float4 d = p[3 * TOT + i];
        s.x += b.x + c.x + d.x;
        s.y += b.y + c.y + d.y;
        s.z += b.z + c.z + d.z;
        s.w += b.w + c.w + d.w;
        ((float4*)out)[i] = s;
    }
}

__global__ void k_dmv2(const float* __restrict__ M, const float* __restrict__ X,
                       float* __restrict__ out) {
    int i = blockIdx.x;
    int t = threadIdx.x;
    float a0 = 0.f, a1 = 0.f;
    for (int j = t; j < NN; j += 256) {
        float m = M[i * NN + j];
        a0 = fmaf(m, X[2 * j], a0);
        a1 = fmaf(m, X[2 * j + 1], a1);
    }
    __shared__ float r0[256], r1[256];
    r0[t] = a0;
    r1[t] = a1;
    __syncthreads();
    for (int off = 128; off > 0; off >>= 1) {
        if (t < off) { r0[t] += r0[t + off]; r1[t] += r1[t + off]; }
        __syncthreads();
    }
    if (t == 0) { out[2 * i] = r0[0]; out[2 * i + 1] = r1[0]; }
}

// ---------------- tiled GEMM core for gate kernels ----------------
template <bool RELU>
__device__ __forceinline__ void gemm_seg(
    float (*At)[PAD], float (*Bt)[PAD],
    const float* __restrict__ A, int lda,
    const float* __restrict__ B, int ldb, int K,
    int m0, int tid, int tm, int tn, float (&acc)[4][4])
{
    for (int k0 = 0; k0 < K; k0 += 32) {
        int kc = K - k0;
        if (kc > 32) kc = 32;
        for (int i = tid; i < (kc << 4); i += 256) {
            int k = i >> 4, c4 = (i & 15) << 2;
            *(float4*)&Bt[k][c4] = *(const float4*)&B[(size_t)(k0 + k) * ldb + c4];
        }
        if (kc == 32) {
            for (int i = tid; i < 2048; i += 256) {
                int r = i >> 5, k = i & 31;
                float v = A[(size_t)(m0 + r) * lda + k0 + k];
                At[k][r] = RELU ? fmaxf(v, 0.f) : v;
            }
        } else {
            for (int i = tid; i < kc * 64; i += 256) {
                int r = i / kc, k = i - r * kc;
                float v = A[(size_t)(m0 + r) * lda + k0 + k];
                At[k][r] = RELU ? fmaxf(v, 0.f) : v;
            }
        }
        __syncthreads();
        if (kc == 32) {
#pragma unroll
            for (int k = 0; k < 32; k++) {
                float4 a = *(float4*)&At[k][tm << 2];
                float4 b = *(float4*)&Bt[k][tn << 2];
                float av[4] = {a.x, a.y, a.z, a.w};
                float bv[4] = {b.x, b.y, b.z, b.w};
#pragma unroll
                for (int i = 0; i < 4; i++)
#pragma unroll
                    for (int j = 0; j < 4; j++)
                        acc[i][j] = fmaf(av[i], bv[j], acc[i][j]);
            }
        } else {
            for (int k = 0; k < kc; k++) {
                float4 a = *(float4*)&At[k][tm << 2];
                float4 b = *(float4*)&Bt[k][tn << 2];
                float av[4] = {a.x, a.y, a.z, a.w};
                float bv[4] = {b.x, b.y, b.z, b.w};
#pragma unroll
                for (int i = 0; i < 4; i++)
#pragma unroll
                    for (int j = 0; j < 4; j++)
                        acc[i][j] = fmaf(av[i], bv[j], acc[i][j]);
            }
        }
        __syncthreads();
    }
}

// z & r gates: pre = x@Wx[g,0] + aggx@Wx[g,1] + H@Wh[g,0] + aggH@Wh[g,1] + b
__global__ __launch_bounds__(256) void k_gates01_g(
    const float* __restrict__ A0, int K01, const float* __restrict__ A1,
    const float* __restrict__ H, const float* __restrict__ A3,
    const float* __restrict__ Wx, const float* __restrict__ Wh,
    const float* __restrict__ bx, const float* __restrict__ bh,
    float* __restrict__ gz, float* __restrict__ hr)
{
    __shared__ float At[32][PAD], Bt[32][PAD];
    int tid = threadIdx.x, tn = tid & 15, tm = tid >> 4;
    int m0 = blockIdx.x << 6;
    int g = blockIdx.y >> 2;
    int n0 = (blockIdx.y & 3) << 6;
    float acc[4][4] = {};
    const float* Bx = Wx + (size_t)g * 2 * K01 * HE + n0;
    const float* Bh = Wh + (size_t)g * 2 * HE * HE + n0;
    gemm_seg<false>(At, Bt, A0, K01, Bx, HE, K01, m0, tid, tm, tn, acc);
    gemm_seg<false>(At, Bt, A1, K01, Bx + (size_t)K01 * HE, HE, K01, m0, tid, tm, tn, acc);
    gemm_seg<false>(At, Bt, H, HE, Bh, HE, HE, m0, tid, tm, tn, acc);
    gemm_seg<false>(At, Bt, A3, HE, Bh + HE * HE, HE, HE, m0, tid, tm, tn, acc);

    int c0 = n0 + (tn << 2);
    float bb[4];
#pragma unroll
    for (int j = 0; j < 4; j++) bb[j] = bx[g * HE + c0 + j] + bh[g * HE + c0 + j];
#pragma unroll
    for (int i = 0; i < 4; i++) {
        size_t idx = (size_t)(m0 + (tm << 2) + i) * HE + c0;
        float4 v;
        v.x = 1.f / (1.f + expf(-(acc[i][0] + bb[0])));
        v.y = 1.f / (1.f + expf(-(acc[i][1] + bb[1])));
        v.z = 1.f / (1.f + expf(-(acc[i][2] + bb[2])));
        v.w = 1.f / (1.f + expf(-(acc[i][3] + bb[3])));
        if (g == 0) {
            *(float4*)&gz[idx] = v;
        } else {
            float4 h = *(const float4*)&H[idx];
            v.x *= h.x; v.y *= h.y; v.z *= h.z; v.w *= h.w;
            *(float4*)&hr[idx] = v;
        }
    }
}

// candidate gate + hidden update: H = z*H + (1-z)*tanh(pre)
__global__ __launch_bounds__(256) void k_gate_t_g(
    const float* __restrict__ A0, int K01, const float* __restrict__ A1,
    const float* __restrict__ hr, const float* __restrict__ A3,
    const float* __restrict__ B0base, const float* __restrict__ B2base,
    const float* __restrict__ b0, const float* __restrict__ b1,
    const float* __restrict__ gz, float* __restrict__ H)
{
    __shared__ float At[32][PAD], Bt[32][PAD];
    int tid = threadIdx.x, tn = tid & 15, tm = tid >> 4;
    int m0 = blockIdx.x << 6;
    int n0 = blockIdx.y << 6;
    float acc[4][4] = {};
    gemm_seg<false>(At, Bt, A0, K01, B0base + n0, HE, K01, m0, tid, tm, tn, acc);
    gemm_seg<false>(At, Bt, A1, K01, B0base + (size_t)K01 * HE + n0, HE, K01, m0, tid, tm, tn, acc);
    gemm_seg<false>(At, Bt, hr, HE, B2base + n0, HE, HE, m0, tid, tm, tn, acc);
    gemm_seg<false>(At, Bt, A3, HE, B2base + (size_t)HE * HE + n0, HE, HE, m0, tid, tm, tn, acc);

    int c0 = n0 + (tn << 2);
    float bb[4];
#pragma unroll
    for (int j = 0; j < 4; j++) bb[j] = b0[c0 + j] + b1[c0 + j];
#pragma unroll
    for (int i = 0; i < 4; i++) {
        size_t idx = (size_t)(m0 + (tm << 2) + i) * HE + c0;
        float4 z = *(const float4*)&gz[idx];
        float4 h = *(const float4*)&H[idx];
        float4 o;
        o.x = z.x * h.x + (1.f - z.x) * tanhf(acc[i][0] + bb[0]);
        o.y = z.y * h.y + (1.f - z.y) * tanhf(acc[i][1] + bb[1]);
        o.z = z.z * h.z + (1.f - z.z) * tanhf(acc[i][2] + bb[2]);
        o.w = z.w * h.w + (1.f - z.w) * tanhf(acc[i][3] + bb[3]);
        *(float4*)&H[idx] = o;
    }
}

// z_lat = relu(H) @ elinW + elinb
__global__ __launch_bounds__(256) void k_linrelu_g(
    const float* __restrict__ A, const float* __restrict__ B,
    const float* __restrict__ bias, float* __restrict__ out)
{
    __shared__ float At[32][PAD], Bt[32][PAD];
    int tid = threadIdx.x, tn = tid & 15, tm = tid >> 4;
    int m0 = blockIdx.x << 6;
    int n0 = blockIdx.y << 6;
    float acc[4][4] = {};
    gemm_seg<true>(At, Bt, A, HE, B + n0, LT, HE, m0, tid, tm, tn, acc);

    int c0 = n0 + (tn << 2);
    float bb[4];
#pragma unroll
    for (int j = 0; j < 4; j++) bb[j] = bias[c0 + j];
#pragma unroll
    for (int i = 0; i < 4; i++) {
        size_t idx = (size_t)(m0 + (tm << 2) + i) * LT + c0;
        float4 o;
        o.x = acc[i][0] + bb[0];
        o.y = acc[i][1] + bb[1];
        o.z = acc[i][2] + bb[2];
        o.w = acc[i][3] + bb[3];
        *(float4*)&out[idx] = o;
    }
}

// y_hat = relu(H) @ dlinW + dlinb   ([NN,HE] @ [HE,2])
__global__ void k_declin(const float* __restrict__ A, const float* __restrict__ B,
                         const float* __restrict__ bias, float* __restrict__ out) {
    int m = blockIdx.x * blockDim.x + threadIdx.x;
    if (m < NN) {
        float a0 = bias[0], a1 = bias[1];
        for (int k = 0; k < HE; k++) {
            float a = fmaxf(A[m * HE + k], 0.f);
            a0 = fmaf(a, B[2 * k], a0);
            a1 = fmaf(a, B[2 * k + 1], a1);
        }
        out[2 * m] = a0;
        out[2 * m + 1] = a1;
    }
}

extern "C" void kernel_launch(void* const* d_in, const int* in_sizes, int n_in,
                              void* d_out, int out_size, void* d_ws, size_t ws_size,
                              hipStream_t stream) {
    (void)in_sizes; (void)n_in; (void)out_size; (void)ws_size;
    const float* x_seq = (const float*)d_in[0];
    const int* ei = (const int*)d_in[1];
    const float* ews = (const float*)d_in[2];
    const float* h_enc_in = (const float*)d_in[3];
    const float* h_dec_in = (const float*)d_in[4];
    const float* encWx = (const float*)d_in[5];
    const float* encbx = (const float*)d_in[6];
    const float* encWh = (const float*)d_in[7];
    const float* encbh = (const float*)d_in[8];
    const float* elinW = (const float*)d_in[9];
    const float* elinb = (const float*)d_in[10];
    const float* decWx = (const float*)d_in[11];
    const float* decbx = (const float*)d_in[12];
    const float* decWh = (const float*)d_in[13];
    const float* decbh = (const float*)d_in[14];
    const float* dlinW = (const float*)d_in[15];
    const float* dlinb = (const float*)d_in[16];
    float* out = (float*)d_out;

    float* W = (float*)d_ws;
    float* h_enc = W; W += (size_t)NN * HE;
    float* h_dec = W; W += (size_t)NN * HE;
    float* aggx  = W; W += (size_t)NN * HE;
    float* aggh  = W; W += (size_t)NN * HE;
    float* hr    = W; W += (size_t)NN * HE;
    float* agghr = W; W += (size_t)NN * HE;
    float* gz    = W; W += (size_t)NN * HE;
    float* zlat  = W; W += (size_t)NN * LT;
    float* yhat  = W; W += (size_t)NN * FIN;
    float* deg   = W; W += NN;
    float* dinv  = W; W += NN;
    float* nrm   = W; W += EE;
    float* Mm    = W; W += (size_t)NN * NN;
    float* pbuf  = W; W += (size_t)KS * NN * HE;
    int* cnt  = (int*)W;
    int* roff = cnt + NN;
    int* cur  = roff + (NN + 2);
    int* eids = cur + NN;

    hipMemcpyAsync(h_enc, h_enc_in, sizeof(float) * NN * HE, hipMemcpyDeviceToDevice, stream);
    hipMemcpyAsync(h_dec, h_dec_in, sizeof(float) * NN * HE, hipMemcpyDeviceToDevice, stream);

    for (int step = 0; step < T_OBS + PREDN - 1; ++step) {
        bool sparse = step < T_OBS;
        const int* srcp = nullptr;
        const float* xin;
        if (sparse) {
            srcp = ei + (size_t)step * 2 * EE;
            const int* dstp = srcp + EE;
            const float* ewt = ews + (size_t)step * EE;
            hipMemsetAsync(deg, 0, sizeof(float) * NN, stream);
            hipMemsetAsync(cnt, 0, sizeof(int) * NN, stream);
            k_deg<<<EE / 256, 256, 0, stream>>>(srcp, ewt, deg);
            k_dinv<<<NN / 256, 256, 0, stream>>>(deg, dinv);
            k_norm<<<EE / 256, 256, 0, stream>>>(srcp, dstp, ewt, dinv, nrm);
            k_count<<<EE / 256, 256, 0, stream>>>(dstp, cnt);
            k_scan<<<1, 256, 0, stream>>>(cnt, roff, cur);
            k_scatter<<<EE / 256, 256, 0, stream>>>(dstp, cur, eids);
            xin = x_seq + (size_t)step * NN * FIN;
        } else {
            k_ddeg<<<NN, 256, 0, stream>>>(yhat, deg);
            k_dinv<<<NN / 256, 256, 0, stream>>>(deg, dinv);
            k_dM<<<(NN * NN) / 256, 256, 0, stream>>>(yhat, dinv, Mm);
            xin = yhat;
        }

        // ======= encoder GRU (x: F=2, H: h_enc) =======
        if (sparse) k_spmm<FIN><<<NN, 64, 0, stream>>>(roff, eids, srcp, nrm, xin, aggx);
        else        k_dmv2<<<NN, 256, 0, stream>>>(Mm, xin, aggx);
        if (sparse) {
            k_spmm<HE><<<NN, HE, 0, stream>>>(roff, eids, srcp, nrm, h_enc, aggh);
        } else {
            k_dmm_ks<HE><<<dim3(NN / 64, HE / 64, KS), 256, 0, stream>>>(Mm, h_enc, pbuf);
            k_redks<HE><<<NN * HE / 4 / 256, 256, 0, stream>>>(pbuf, aggh);
        }
        {
            dim3 g(NN / 64, 8);
            k_gates01_g<<<g, 256, 0, stream>>>(xin, FIN, aggx, h_enc, aggh,
                                               encWx, encWh, encbx, encbh, gz, hr);
        }
        if (sparse) {
            k_spmm<HE><<<NN, HE, 0, stream>>>(roff, eids, srcp, nrm, hr, agghr);
        } else {
            k_dmm_ks<HE><<<dim3(NN / 64, HE / 64, KS), 256, 0, stream>>>(Mm, hr, pbuf);
            k_redks<HE><<<NN * HE / 4 / 256, 256, 0, stream>>>(pbuf, agghr);
        }
        {
            dim3 g(NN / 64, 4);
            k_gate_t_g<<<g, 256, 0, stream>>>(xin, FIN, aggx, hr, agghr,
                                              encWx + 4 * FIN * HE, encWh + 4 * HE * HE,
                                              encbx + 2 * HE, encbh + 2 * HE, gz, h_enc);
        }
        {
            dim3 g(NN / 64, 2);
            k_linrelu_g<<<g, 256, 0, stream>>>(h_enc, elinW, elinb, zlat);
        }

        // ======= decoder GRU (x: zlat F=128, H: h_dec) =======
        if (sparse) {
            k_spmm<LT><<<NN, LT, 0, stream>>>(roff, eids, srcp, nrm, zlat, aggx);
        } else {
            k_dmm_ks<LT><<<dim3(NN / 64, LT / 64, KS), 256, 0, stream>>>(Mm, zlat, pbuf);
            k_redks<LT><<<NN * LT / 4 / 256, 256, 0, stream>>>(pbuf, aggx);
        }
        if (sparse) {
            k_spmm<HE><<<NN, HE, 0, stream>>>(roff, eids, srcp, nrm, h_dec, aggh);
        } else {
            k_dmm_ks<HE><<<dim3(NN / 64, HE / 64, KS), 256, 0, stream>>>(Mm, h_dec, pbuf);
            k_redks<HE><<<NN * HE / 4 / 256, 256, 0, stream>>>(pbuf, aggh);
        }
        {
            dim3 g(NN / 64, 8);
            k_gates01_g<<<g, 256, 0, stream>>>(zlat, LT, aggx, h_dec, aggh,
                                               decWx, decWh, decbx, decbh, gz, hr);
        }
        if (sparse) {
            k_spmm<HE><<<NN, HE, 0, stream>>>(roff, eids, srcp, nrm, hr, agghr);
        } else {
            k_dmm_ks<HE><<<dim3(NN / 64, HE / 64, KS), 256, 0, stream>>>(Mm, hr, pbuf);
            k_redks<HE><<<NN * HE / 4 / 256, 256, 0, stream>>>(pbuf, agghr);
        }
        {
            dim3 g(NN / 64, 4);
            k_gate_t_g<<<g, 256, 0, stream>>>(zlat, LT, aggx, hr, agghr,
                                              decWx + 4 * LT * HE, decWh + 4 * HE * HE,
                                              decbx + 2 * HE, decbh + 2 * HE, gz, h_dec);
        }
        k_declin<<<NN / 256, 256, 0, stream>>>(h_dec, dlinW, dlinb, yhat);

        if (step >= T_OBS - 1) {
            hipMemcpyAsync(out + (size_t)(step - (T_OBS - 1)) * NN * FIN, yhat,
                           sizeof(float) * NN * FIN, hipMemcpyDeviceToDevice, stream);
        }
    }
}

// Round 5
// 3943.597 us; speedup vs baseline: 3.5362x; 1.3419x over previous
//
#include <hip/hip_runtime.h>
#include <math.h>

#define NN 2048
#define EE 65536
#define T_OBS 6
#define FIN 2
#define HE 256
#define LT 128
#define PREDN 6
#define PAD 68
#define KS 4

// ---------------- sparse graph prep ----------------
__global__ void k_deg(const int* __restrict__ src, const float* __restrict__ ew,
                      float* __restrict__ deg) {
    int e = blockIdx.x * blockDim.x + threadIdx.x;
    if (e < EE) atomicAdd(&deg[src[e]], ew[e]);
}

__global__ void k_dinv(const float* __restrict__ deg, float* __restrict__ dinv) {
    int i = blockIdx.x * blockDim.x + threadIdx.x;
    if (i < NN) {
        float d = deg[i];
        dinv[i] = d > 0.f ? 1.f / sqrtf(d) : 0.f;
    }
}

__global__ void k_norm(const int* __restrict__ src, const int* __restrict__ dst,
                       const float* __restrict__ ew, const float* __restrict__ dinv,
                       float* __restrict__ nrm) {
    int e = blockIdx.x * blockDim.x + threadIdx.x;
    if (e < EE) nrm[e] = -dinv[src[e]] * ew[e] * dinv[dst[e]];
}

__global__ void k_count(const int* __restrict__ dst, int* __restrict__ cnt) {
    int e = blockIdx.x * blockDim.x + threadIdx.x;
    if (e < EE) atomicAdd(&cnt[dst[e]], 1);
}

__global__ void k_scan(const int* __restrict__ cnt, int* __restrict__ roff,
                       int* __restrict__ cur) {
    __shared__ int part[256];
    int t = threadIdx.x;
    int loc[8];
    int s = 0;
#pragma unroll
    for (int i = 0; i < 8; i++) { loc[i] = cnt[t * 8 + i]; s += loc[i]; }
    part[t] = s;
    __syncthreads();
    for (int off = 1; off < 256; off <<= 1) {
        int v = (t >= off) ? part[t - off] : 0;
        __syncthreads();
        part[t] += v;
        __syncthreads();
    }
    int run = (t == 0) ? 0 : part[t - 1];
#pragma unroll
    for (int i = 0; i < 8; i++) {
        int idx = t * 8 + i;
        roff[idx] = run;
        cur[idx] = run;
        run += loc[i];
    }
    if (t == 255) roff[NN] = run;
}

__global__ void k_scatter(const int* __restrict__ dst, int* __restrict__ cur,
                          int* __restrict__ eids) {
    int e = blockIdx.x * blockDim.x + threadIdx.x;
    if (e < EE) {
        int p = atomicAdd(&cur[dst[e]], 1);
        eids[p] = e;
    }
}

template <int F>
__global__ void k_spmm(const int* __restrict__ roff, const int* __restrict__ eids,
                       const int* __restrict__ src, const float* __restrict__ nrm,
                       const float* __restrict__ X, float* __restrict__ out) {
    int nid = blockIdx.x;
    int f = threadIdx.x;
    if (f >= F) return;
    int s0 = roff[nid], s1 = roff[nid + 1];
    float acc = 0.f;
    for (int s = s0; s < s1; ++s) {
        int e = eids[s];
        acc = fmaf(nrm[e], X[src[e] * F + f], acc);
    }
    out[nid * F + f] = acc;
}

// ---------------- dense graph prep (rollout) ----------------
__global__ void k_ddeg(const float* __restrict__ c, float* __restrict__ deg) {
    int i = blockIdx.x;
    int t = threadIdx.x;
    float xi = c[2 * i], yi = c[2 * i + 1];
    float s = 0.f;
    for (int j = t; j < NN; j += 256) {
        float dx = xi - c[2 * j], dy = yi - c[2 * j + 1];
        float d = sqrtf(dx * dx + dy * dy);
        if (d > 0.f && d < 0.5f) s += 2.f * d;
    }
    __shared__ float red[256];
    red[t] = s;
    __syncthreads();
    for (int off = 128; off > 0; off >>= 1) {
        if (t < off) red[t] += red[t + off];
        __syncthreads();
    }
    if (t == 0) deg[i] = red[0];
}

__global__ void k_dM(const float* __restrict__ c, const float* __restrict__ dinv,
                     float* __restrict__ M) {
    int idx = blockIdx.x * blockDim.x + threadIdx.x;
    int i = idx >> 11, j = idx & (NN - 1);
    float dx = c[2 * i] - c[2 * j], dy = c[2 * i + 1] - c[2 * j + 1];
    float d = sqrtf(dx * dx + dy * dy);
    float w = (d > 0.f && d < 0.5f) ? 2.f * d : 0.f;
    M[idx] = -(dinv[i] * w) * dinv[j];
}

// dense agg: out = M @ X via K-split tiled GEMM.
template <int F>
__global__ __launch_bounds__(256) void k_dmm_ks(
    const float* __restrict__ M, const float* __restrict__ X,
    float* __restrict__ pbuf)
{
    __shared__ float At[32][PAD], Bt[32][PAD];
    const int tid = threadIdx.x, tn = tid & 15, tm = tid >> 4;
    const int m0 = blockIdx.x << 6;
    const int n0 = blockIdx.y << 6;
    const int kb = blockIdx.z * (NN / KS);
    float acc[4][4] = {};
    for (int k0 = kb; k0 < kb + NN / KS; k0 += 32) {
        for (int i = tid; i < 2048; i += 256) {
            int r = i >> 5, k = i & 31;
            At[k][r] = M[(size_t)(m0 + r) * NN + k0 + k];
        }
        for (int i = tid; i < 512; i += 256) {
            int k = i >> 4, c4 = (i & 15) << 2;
            *(float4*)&Bt[k][c4] = *(const float4*)&X[(size_t)(k0 + k) * F + n0 + c4];
        }
        __syncthreads();
#pragma unroll
        for (int k = 0; k < 32; k++) {
            float4 a = *(float4*)&At[k][tm << 2];
            float4 b = *(float4*)&Bt[k][tn << 2];
            float av[4] = {a.x, a.y, a.z, a.w};
            float bv[4] = {b.x, b.y, b.z, b.w};
#pragma unroll
            for (int i = 0; i < 4; i++)
#pragma unroll
                for (int j = 0; j < 4; j++)
                    acc[i][j] = fmaf(av[i], bv[j], acc[i][j]);
        }
        __syncthreads();
    }
    float* p = pbuf + (size_t)blockIdx.z * NN * F;
#pragma unroll
    for (int i = 0; i < 4; i++) {
        *(float4*)&p[(size_t)(m0 + (tm << 2) + i) * F + n0 + (tn << 2)] =
            make_float4(acc[i][0], acc[i][1], acc[i][2], acc[i][3]);
    }
}

template <int F>
__global__ void k_redks(const float* __restrict__ pbuf, float* __restrict__ out) {
    const int TOT = NN * F / 4;
    int i = blockIdx.x * blockDim.x + threadIdx.x;
    if (i < TOT) {
        const float4* p = (const float4*)pbuf;
        float4 s = p[i];
        float4 b = p[TOT + i];
        float4 c = p[2 * TOT + i];
        float4 d = p[3 * TOT + i];
        s.x += b.x + c.x + d.x;
        s.y += b.y + c.y + d.y;
        s.z += b.z + c.z + d.z;
        s.w += b.w + c.w + d.w;
        ((float4*)out)[i] = s;
    }
}

__global__ void k_dmv2(const float* __restrict__ M, const float* __restrict__ X,
                       float* __restrict__ out) {
    int i = blockIdx.x;
    int t = threadIdx.x;
    float a0 = 0.f, a1 = 0.f;
    for (int j = t; j < NN; j += 256) {
        float m = M[i * NN + j];
        a0 = fmaf(m, X[2 * j], a0);
        a1 = fmaf(m, X[2 * j + 1], a1);
    }
    __shared__ float r0[256], r1[256];
    r0[t] = a0;
    r1[t] = a1;
    __syncthreads();
    for (int off = 128; off > 0; off >>= 1) {
        if (t < off) { r0[t] += r0[t + off]; r1[t] += r1[t + off]; }
        __syncthreads();
    }
    if (t == 0) { out[2 * i] = r0[0]; out[2 * i + 1] = r1[0]; }
}

// ---------------- tiled GEMM core ----------------
template <bool RELU>
__device__ __forceinline__ void gemm_seg(
    float (*At)[PAD], float (*Bt)[PAD],
    const float* __restrict__ A, int lda,
    const float* __restrict__ B, int ldb, int K,
    int m0, int tid, int tm, int tn, float (&acc)[4][4])
{
    for (int k0 = 0; k0 < K; k0 += 32) {
        int kc = K - k0;
        if (kc > 32) kc = 32;
        for (int i = tid; i < (kc << 4); i += 256) {
            int k = i >> 4, c4 = (i & 15) << 2;
            *(float4*)&Bt[k][c4] = *(const float4*)&B[(size_t)(k0 + k) * ldb + c4];
        }
        if (kc == 32) {
            for (int i = tid; i < 2048; i += 256) {
                int r = i >> 5, k = i & 31;
                float v = A[(size_t)(m0 + r) * lda + k0 + k];
                At[k][r] = RELU ? fmaxf(v, 0.f) : v;
            }
        } else {
            for (int i = tid; i < kc * 64; i += 256) {
                int r = i / kc, k = i - r * kc;
                float v = A[(size_t)(m0 + r) * lda + k0 + k];
                At[k][r] = RELU ? fmaxf(v, 0.f) : v;
            }
        }
        __syncthreads();
        if (kc == 32) {
#pragma unroll
            for (int k = 0; k < 32; k++) {
                float4 a = *(float4*)&At[k][tm << 2];
                float4 b = *(float4*)&Bt[k][tn << 2];
                float av[4] = {a.x, a.y, a.z, a.w};
                float bv[4] = {b.x, b.y, b.z, b.w};
#pragma unroll
                for (int i = 0; i < 4; i++)
#pragma unroll
                    for (int j = 0; j < 4; j++)
                        acc[i][j] = fmaf(av[i], bv[j], acc[i][j]);
            }
        } else {
            for (int k = 0; k < kc; k++) {
                float4 a = *(float4*)&At[k][tm << 2];
                float4 b = *(float4*)&Bt[k][tn << 2];
                float av[4] = {a.x, a.y, a.z, a.w};
                float bv[4] = {b.x, b.y, b.z, b.w};
#pragma unroll
                for (int i = 0; i < 4; i++)
#pragma unroll
                    for (int j = 0; j < 4; j++)
                        acc[i][j] = fmaf(av[i], bv[j], acc[i][j]);
            }
        }
        __syncthreads();
    }
}

// z/r gates, K-split partial: pre_g = x@Wx[g,0] + aggx@Wx[g,1] + H@Wh[g,0] + aggH@Wh[g,1]
// grid (NN/64, 8, 2); pbuf slab z: [NN][512]
__global__ __launch_bounds__(256) void k_zr_ks(
    const float* __restrict__ A0, int K01, const float* __restrict__ A1,
    const float* __restrict__ H, const float* __restrict__ A3,
    const float* __restrict__ Wx, const float* __restrict__ Wh,
    float* __restrict__ pbuf)
{
    __shared__ float At[32][PAD], Bt[32][PAD];
    int tid = threadIdx.x, tn = tid & 15, tm = tid >> 4;
    int m0 = blockIdx.x << 6;
    int g = blockIdx.y >> 2;
    int n0 = (blockIdx.y & 3) << 6;
    float acc[4][4] = {};
    const float* As[4] = {A0, A1, H, A3};
    const int ldas[4] = {K01, K01, HE, HE};
    const float* Bs[4] = {
        Wx + (size_t)(g * 2 + 0) * K01 * HE + n0,
        Wx + (size_t)(g * 2 + 1) * K01 * HE + n0,
        Wh + (size_t)(g * 2 + 0) * HE * HE + n0,
        Wh + (size_t)(g * 2 + 1) * HE * HE + n0};
    const int Ks[4] = {K01, K01, HE, HE};
    int chunk = (2 * K01 + 2 * HE) >> 1;
    int lo = blockIdx.z * chunk, hi = lo + chunk;
    int off = 0;
#pragma unroll
    for (int s = 0; s < 4; s++) {
        int a = lo - off; a = a < 0 ? 0 : a;
        int b = hi - off; b = b > Ks[s] ? Ks[s] : b;
        if (b > a)
            gemm_seg<false>(At, Bt, As[s] + a, ldas[s], Bs[s] + (size_t)a * HE, HE,
                            b - a, m0, tid, tm, tn, acc);
        off += Ks[s];
    }
    float* p = pbuf + (size_t)blockIdx.z * NN * 512;
    int c = (g << 8) + n0 + (tn << 2);
#pragma unroll
    for (int i = 0; i < 4; i++)
        *(float4*)&p[(size_t)(m0 + (tm << 2) + i) * 512 + c] =
            make_float4(acc[i][0], acc[i][1], acc[i][2], acc[i][3]);
}

// epilogue: z = sigmoid(p0+p1+b) -> gz ; r -> hr = H * sigmoid(...)
__global__ void k_zr_ep(const float* __restrict__ pbuf,
                        const float* __restrict__ bx, const float* __restrict__ bh,
                        const float* __restrict__ H,
                        float* __restrict__ gz, float* __restrict__ hr)
{
    int i = blockIdx.x * 256 + threadIdx.x;  // < NN*512/4
    const float4* p0 = (const float4*)pbuf;
    const float4* p1 = p0 + (size_t)NN * 512 / 4;
    float4 a = p0[i], b = p1[i];
    int row = i >> 7, c = (i & 127) << 2;
    float4 b0 = *(const float4*)&bx[c];
    float4 b1 = *(const float4*)&bh[c];
    float4 s;
    s.x = 1.f / (1.f + expf(-(a.x + b.x + b0.x + b1.x)));
    s.y = 1.f / (1.f + expf(-(a.y + b.y + b0.y + b1.y)));
    s.z = 1.f / (1.f + expf(-(a.z + b.z + b0.z + b1.z)));
    s.w = 1.f / (1.f + expf(-(a.w + b.w + b0.w + b1.w)));
    if (c < HE) {
        *(float4*)&gz[(size_t)row * HE + c] = s;
    } else {
        float4 h = *(const float4*)&H[(size_t)row * HE + c - HE];
        s.x *= h.x; s.y *= h.y; s.z *= h.z; s.w *= h.w;
        *(float4*)&hr[(size_t)row * HE + c - HE] = s;
    }
}

// candidate gate, K-split partial: pre = x@Wx2[0] + aggx@Wx2[1] + hr@Wh2[0] + agghr@Wh2[1]
// grid (NN/64, 4, 4); pbuf slab z: [NN][256]
__global__ __launch_bounds__(256) void k_gt_ks(
    const float* __restrict__ A0, int K01, const float* __restrict__ A1,
    const float* __restrict__ hr, const float* __restrict__ A3,
    const float* __restrict__ Wx2, const float* __restrict__ Wh2,
    float* __restrict__ pbuf)
{
    __shared__ float At[32][PAD], Bt[32][PAD];
    int tid = threadIdx.x, tn = tid & 15, tm = tid >> 4;
    int m0 = blockIdx.x << 6;
    int n0 = blockIdx.y << 6;
    float acc[4][4] = {};
    const float* As[4] = {A0, A1, hr, A3};
    const int ldas[4] = {K01, K01, HE, HE};
    const float* Bs[4] = {
        Wx2 + n0,
        Wx2 + (size_t)K01 * HE + n0,
        Wh2 + n0,
        Wh2 + (size_t)HE * HE + n0};
    const int Ks[4] = {K01, K01, HE, HE};
    int chunk = (2 * K01 + 2 * HE) >> 2;
    int lo = blockIdx.z * chunk, hi = lo + chunk;
    int off = 0;
#pragma unroll
    for (int s = 0; s < 4; s++) {
        int a = lo - off; a = a < 0 ? 0 : a;
        int b = hi - off; b = b > Ks[s] ? Ks[s] : b;
        if (b > a)
            gemm_seg<false>(At, Bt, As[s] + a, ldas[s], Bs[s] + (size_t)a * HE, HE,
                            b - a, m0, tid, tm, tn, acc);
        off += Ks[s];
    }
    float* p = pbuf + (size_t)blockIdx.z * NN * HE;
    int c = n0 + (tn << 2);
#pragma unroll
    for (int i = 0; i < 4; i++)
        *(float4*)&p[(size_t)(m0 + (tm << 2) + i) * HE + c] =
            make_float4(acc[i][0], acc[i][1], acc[i][2], acc[i][3]);
}

// epilogue: H = z*H + (1-z)*tanh(sum + b)
__global__ void k_gt_ep(const float* __restrict__ pbuf,
                        const float* __restrict__ bx2, const float* __restrict__ bh2,
                        const float* __restrict__ gz, float* __restrict__ H)
{
    int i = blockIdx.x * 256 + threadIdx.x;  // < NN*256/4
    const float4* p = (const float4*)pbuf;
    const size_t S = (size_t)NN * HE / 4;
    float4 a = p[i], b = p[S + i], c4 = p[2 * S + i], d = p[3 * S + i];
    int row = i >> 6, c = (i & 63) << 2;
    float4 b0 = *(const float4*)&bx2[c];
    float4 b1 = *(const float4*)&bh2[c];
    size_t idx = (size_t)row * HE + c;
    float4 z = *(const float4*)&gz[idx];
    float4 h = *(const float4*)&H[idx];
    float4 o;
    o.x = z.x * h.x + (1.f - z.x) * tanhf(a.x + b.x + c4.x + d.x + b0.x + b1.x);
    o.y = z.y * h.y + (1.f - z.y) * tanhf(a.y + b.y + c4.y + d.y + b0.y + b1.y);
    o.z = z.z * h.z + (1.f - z.z) * tanhf(a.z + b.z + c4.z + d.z + b0.z + b1.z);
    o.w = z.w * h.w + (1.f - z.w) * tanhf(a.w + b.w + c4.w + d.w + b0.w + b1.w);
    *(float4*)&H[idx] = o;
}

// latent linear, K-split: relu(H) @ elinW ; grid (NN/64, 2, 8); slab z: [NN][128]
__global__ __launch_bounds__(256) void k_lin_ks(
    const float* __restrict__ A, const float* __restrict__ B,
    float* __restrict__ pbuf)
{
    __shared__ float At[32][PAD], Bt[32][PAD];
    int tid = threadIdx.x, tn = tid & 15, tm = tid >> 4;
    int m0 = blockIdx.x << 6;
    int n0 = blockIdx.y << 6;
    int lo = blockIdx.z << 5;  // 32 per slice
    float acc[4][4] = {};
    gemm_seg<true>(At, Bt, A + lo, HE, B + (size_t)lo * LT + n0, LT, 32,
                   m0, tid, tm, tn, acc);
    float* p = pbuf + (size_t)blockIdx.z * NN * LT;
    int c = n0 + (tn << 2);
#pragma unroll
    for (int i = 0; i < 4; i++)
        *(float4*)&p[(size_t)(m0 + (tm << 2) + i) * LT + c] =
            make_float4(acc[i][0], acc[i][1], acc[i][2], acc[i][3]);
}

__global__ void k_lin_ep(const float* __restrict__ pbuf,
                         const float* __restrict__ bias, float* __restrict__ out)
{
    int i = blockIdx.x * 256 + threadIdx.x;  // < NN*128/4
    const float4* p = (const float4*)pbuf;
    const size_t S = (size_t)NN * LT / 4;
    int c = (i & 31) << 2;
    float4 bb = *(const float4*)&bias[c];
    float4 s = make_float4(bb.x, bb.y, bb.z, bb.w);
#pragma unroll
    for (int z = 0; z < 8; z++) {
        float4 v = p[z * S + i];
        s.x += v.x; s.y += v.y; s.z += v.z; s.w += v.w;
    }
    ((float4*)out)[i] = s;
}

// y_hat = relu(H) @ dlinW + dlinb : one wave per row
__global__ void k_declin(const float* __restrict__ A, const float* __restrict__ B,
                         const float* __restrict__ bias, float* __restrict__ out) {
    int w = threadIdx.x >> 6, lane = threadIdx.x & 63;
    int m = blockIdx.x * 4 + w;
    float4 a = *(const float4*)&A[(size_t)m * HE + (lane << 2)];
    float av[4] = {a.x, a.y, a.z, a.w};
    float a0 = 0.f, a1 = 0.f;
#pragma unroll
    for (int j = 0; j < 4; j++) {
        float v = fmaxf(av[j], 0.f);
        float2 b = *(const float2*)&B[((lane << 2) + j) * 2];
        a0 = fmaf(v, b.x, a0);
        a1 = fmaf(v, b.y, a1);
    }
    for (int off = 32; off > 0; off >>= 1) {
        a0 += __shfl_down(a0, off, 64);
        a1 += __shfl_down(a1, off, 64);
    }
    if (lane == 0) {
        out[2 * m] = a0 + bias[0];
        out[2 * m + 1] = a1 + bias[1];
    }
}

extern "C" void kernel_launch(void* const* d_in, const int* in_sizes, int n_in,
                              void* d_out, int out_size, void* d_ws, size_t ws_size,
                              hipStream_t stream) {
    (void)in_sizes; (void)n_in; (void)out_size; (void)ws_size;
    const float* x_seq = (const float*)d_in[0];
    const int* ei = (const int*)d_in[1];
    const float* ews = (const float*)d_in[2];
    const float* h_enc_in = (const float*)d_in[3];
    const float* h_dec_in = (const float*)d_in[4];
    const float* encWx = (const float*)d_in[5];
    const float* encbx = (const float*)d_in[6];
    const float* encWh = (const float*)d_in[7];
    const float* encbh = (const float*)d_in[8];
    const float* elinW = (const float*)d_in[9];
    const float* elinb = (const float*)d_in[10];
    const float* decWx = (const float*)d_in[11];
    const float* decbx = (const float*)d_in[12];
    const float* decWh = (const float*)d_in[13];
    const float* decbh = (const float*)d_in[14];
    const float* dlinW = (const float*)d_in[15];
    const float* dlinb = (const float*)d_in[16];
    float* out = (float*)d_out;

    float* W = (float*)d_ws;
    float* h_enc = W; W += (size_t)NN * HE;
    float* h_dec = W; W += (size_t)NN * HE;
    float* aggx  = W; W += (size_t)NN * HE;
    float* aggh  = W; W += (size_t)NN * HE;
    float* hr    = W; W += (size_t)NN * HE;
    float* agghr = W; W += (size_t)NN * HE;
    float* gz    = W; W += (size_t)NN * HE;
    float* zlat  = W; W += (size_t)NN * LT;
    float* yhat  = W; W += (size_t)NN * FIN;
    float* deg   = W; W += NN;
    float* dinv  = W; W += NN;
    float* nrm   = W; W += EE;
    float* Mm    = W; W += (size_t)NN * NN;
    float* pbuf  = W; W += (size_t)KS * NN * HE;
    int* cnt  = (int*)W;
    int* roff = cnt + NN;
    int* cur  = roff + (NN + 2);
    int* eids = cur + NN;

    hipMemcpyAsync(h_enc, h_enc_in, sizeof(float) * NN * HE, hipMemcpyDeviceToDevice, stream);
    hipMemcpyAsync(h_dec, h_dec_in, sizeof(float) * NN * HE, hipMemcpyDeviceToDevice, stream);

    for (int step = 0; step < T_OBS + PREDN - 1; ++step) {
        bool sparse = step < T_OBS;
        const int* srcp = nullptr;
        const float* xin;
        if (sparse) {
            srcp = ei + (size_t)step * 2 * EE;
            const int* dstp = srcp + EE;
            const float* ewt = ews + (size_t)step * EE;
            hipMemsetAsync(deg, 0, sizeof(float) * NN, stream);
            hipMemsetAsync(cnt, 0, sizeof(int) * NN, stream);
            k_deg<<<EE / 256, 256, 0, stream>>>(srcp, ewt, deg);
            k_dinv<<<NN / 256, 256, 0, stream>>>(deg, dinv);
            k_norm<<<EE / 256, 256, 0, stream>>>(srcp, dstp, ewt, dinv, nrm);
            k_count<<<EE / 256, 256, 0, stream>>>(dstp, cnt);
            k_scan<<<1, 256, 0, stream>>>(cnt, roff, cur);
            k_scatter<<<EE / 256, 256, 0, stream>>>(dstp, cur, eids);
            xin = x_seq + (size_t)step * NN * FIN;
        } else {
            k_ddeg<<<NN, 256, 0, stream>>>(yhat, deg);
            k_dinv<<<NN / 256, 256, 0, stream>>>(deg, dinv);
            k_dM<<<(NN * NN) / 256, 256, 0, stream>>>(yhat, dinv, Mm);
            xin = yhat;
        }

        // ======= encoder GRU (x: F=2, H: h_enc) =======
        if (sparse) k_spmm<FIN><<<NN, 64, 0, stream>>>(roff, eids, srcp, nrm, xin, aggx);
        else        k_dmv2<<<NN, 256, 0, stream>>>(Mm, xin, aggx);
        if (sparse) {
            k_spmm<HE><<<NN, HE, 0, stream>>>(roff, eids, srcp, nrm, h_enc, aggh);
        } else {
            k_dmm_ks<HE><<<dim3(NN / 64, HE / 64, KS), 256, 0, stream>>>(Mm, h_enc, pbuf);
            k_redks<HE><<<NN * HE / 4 / 256, 256, 0, stream>>>(pbuf, aggh);
        }
        k_zr_ks<<<dim3(NN / 64, 8, 2), 256, 0, stream>>>(xin, FIN, aggx, h_enc, aggh,
                                                         encWx, encWh, pbuf);
        k_zr_ep<<<NN * 512 / 4 / 256, 256, 0, stream>>>(pbuf, encbx, encbh, h_enc, gz, hr);
        if (sparse) {
            k_spmm<HE><<<NN, HE, 0, stream>>>(roff, eids, srcp, nrm, hr, agghr);
        } else {
            k_dmm_ks<HE><<<dim3(NN / 64, HE / 64, KS), 256, 0, stream>>>(Mm, hr, pbuf);
            k_redks<HE><<<NN * HE / 4 / 256, 256, 0, stream>>>(pbuf, agghr);
        }
        k_gt_ks<<<dim3(NN / 64, 4, 4), 256, 0, stream>>>(xin, FIN, aggx, hr, agghr,
                                                         encWx + 4 * FIN * HE,
                                                         encWh + 4 * HE * HE, pbuf);
        k_gt_ep<<<NN * HE / 4 / 256, 256, 0, stream>>>(pbuf, encbx + 2 * HE,
                                                       encbh + 2 * HE, gz, h_enc);
        k_lin_ks<<<dim3(NN / 64, 2, 8), 256, 0, stream>>>(h_enc, elinW, pbuf);
        k_lin_ep<<<NN * LT / 4 / 256, 256, 0, stream>>>(pbuf, elinb, zlat);

        // ======= decoder GRU (x: zlat F=128, H: h_dec) =======
        if (sparse) {
            k_spmm<LT><<<NN, LT, 0, stream>>>(roff, eids, srcp, nrm, zlat, aggx);
        } else {
            k_dmm_ks<LT><<<dim3(NN / 64, LT / 64, KS), 256, 0, stream>>>(Mm, zlat, pbuf);
            k_redks<LT><<<NN * LT / 4 / 256, 256, 0, stream>>>(pbuf, aggx);
        }
        if (sparse) {
            k_spmm<HE><<<NN, HE, 0, stream>>>(roff, eids, srcp, nrm, h_dec, aggh);
        } else {
            k_dmm_ks<HE><<<dim3(NN / 64, HE / 64, KS), 256, 0, stream>>>(Mm, h_dec, pbuf);
            k_redks<HE><<<NN * HE / 4 / 256, 256, 0, stream>>>(pbuf, aggh);
        }
        k_zr_ks<<<dim3(NN / 64, 8, 2), 256, 0, stream>>>(zlat, LT, aggx, h_dec, aggh,
                                                         decWx, decWh, pbuf);
        k_zr_ep<<<NN * 512 / 4 / 256, 256, 0, stream>>>(pbuf, decbx, decbh, h_dec, gz, hr);
        if (sparse) {
            k_spmm<HE><<<NN, HE, 0, stream>>>(roff, eids, srcp, nrm, hr, agghr);
        } else {
            k_dmm_ks<HE><<<dim3(NN / 64, HE / 64, KS), 256, 0, stream>>>(Mm, hr, pbuf);
            k_redks<HE><<<NN * HE / 4 / 256, 256, 0, stream>>>(pbuf, agghr);
        }
        k_gt_ks<<<dim3(NN / 64, 4, 4), 256, 0, stream>>>(zlat, LT, aggx, hr, agghr,
                                                         decWx + 4 * LT * HE,
                                                         decWh + 4 * HE * HE, pbuf);
        k_gt_ep<<<NN * HE / 4 / 256, 256, 0, stream>>>(pbuf, decbx + 2 * HE,
                                                       decbh + 2 * HE, gz, h_dec);
        k_declin<<<NN / 4, 256, 0, stream>>>(h_dec, dlinW, dlinb, yhat);

        if (step >= T_OBS - 1) {
            hipMemcpyAsync(out + (size_t)(step - (T_OBS - 1)) * NN * FIN, yhat,
                           sizeof(float) * NN * FIN, hipMemcpyDeviceToDevice, stream);
        }
    }
}

// Round 6
// 3298.701 us; speedup vs baseline: 4.2275x; 1.1955x over previous
//
#include <hip/hip_runtime.h>
#include <math.h>

#define NN 2048
#define EE 65536
#define T_OBS 6
#define FIN 2
#define HE 256
#define LT 128
#define PREDN 6
#define PAD 68
#define DMM_NZ 8
#define ZR_NZ 4
#define GT_NZ 8
#define LIN_NZ 8

// ---------------- sparse graph prep ----------------
__global__ void k_degcnt(const int* __restrict__ src, const int* __restrict__ dst,
                         const float* __restrict__ ew,
                         float* __restrict__ deg, int* __restrict__ cnt) {
    int e = blockIdx.x * blockDim.x + threadIdx.x;
    if (e < EE) {
        atomicAdd(&deg[src[e]], ew[e]);
        atomicAdd(&cnt[dst[e]], 1);
    }
}

__global__ void k_dinv(const float* __restrict__ deg, float* __restrict__ dinv) {
    int i = blockIdx.x * blockDim.x + threadIdx.x;
    if (i < NN) {
        float d = deg[i];
        dinv[i] = d > 0.f ? 1.f / sqrtf(d) : 0.f;
    }
}

__global__ void k_scan(const int* __restrict__ cnt, int* __restrict__ roff,
                       int* __restrict__ cur) {
    __shared__ int part[256];
    int t = threadIdx.x;
    int loc[8];
    int s = 0;
#pragma unroll
    for (int i = 0; i < 8; i++) { loc[i] = cnt[t * 8 + i]; s += loc[i]; }
    part[t] = s;
    __syncthreads();
    for (int off = 1; off < 256; off <<= 1) {
        int v = (t >= off) ? part[t - off] : 0;
        __syncthreads();
        part[t] += v;
        __syncthreads();
    }
    int run = (t == 0) ? 0 : part[t - 1];
#pragma unroll
    for (int i = 0; i < 8; i++) {
        int idx = t * 8 + i;
        roff[idx] = run;
        cur[idx] = run;
        run += loc[i];
    }
    if (t == 255) roff[NN] = run;
}

// scatter + fused normalization: csr_nrm[p] = -dinv[s]*ew*dinv[d]
__global__ void k_scatter2(const int* __restrict__ src, const int* __restrict__ dst,
                           const float* __restrict__ ew, const float* __restrict__ dinv,
                           int* __restrict__ cur,
                           int* __restrict__ csr_src, float* __restrict__ csr_nrm) {
    int e = blockIdx.x * blockDim.x + threadIdx.x;
    if (e < EE) {
        int s = src[e], d = dst[e];
        int p = atomicAdd(&cur[d], 1);
        csr_src[p] = s;
        csr_nrm[p] = -dinv[s] * ew[e] * dinv[d];
    }
}

// CSR SpMM, wave per node, float4 per lane, 8 edges batched (8 gathers in flight)
template <int F>
__global__ void k_spmm_v(const int* __restrict__ roff, const int* __restrict__ csr_src,
                         const float* __restrict__ csr_nrm,
                         const float* __restrict__ X, float* __restrict__ out) {
    int w = threadIdx.x >> 6, lane = threadIdx.x & 63;
    int nid = (blockIdx.x << 2) + w;
    int c = lane << 2;
    int s0 = roff[nid], s1 = roff[nid + 1];
    float4 acc = make_float4(0.f, 0.f, 0.f, 0.f);
    int s = s0;
    for (; s + 8 <= s1; s += 8) {
        int is[8]; float ws[8];
#pragma unroll
        for (int j = 0; j < 8; j++) { is[j] = csr_src[s + j]; ws[j] = csr_nrm[s + j]; }
        if (c < F) {
            float4 xv[8];
#pragma unroll
            for (int j = 0; j < 8; j++) xv[j] = *(const float4*)&X[(size_t)is[j] * F + c];
#pragma unroll
            for (int j = 0; j < 8; j++) {
                acc.x = fmaf(ws[j], xv[j].x, acc.x);
                acc.y = fmaf(ws[j], xv[j].y, acc.y);
                acc.z = fmaf(ws[j], xv[j].z, acc.z);
                acc.w = fmaf(ws[j], xv[j].w, acc.w);
            }
        }
    }
    for (; s < s1; ++s) {
        int i0 = csr_src[s]; float w0 = csr_nrm[s];
        if (c < F) {
            float4 xv = *(const float4*)&X[(size_t)i0 * F + c];
            acc.x = fmaf(w0, xv.x, acc.x);
            acc.y = fmaf(w0, xv.y, acc.y);
            acc.z = fmaf(w0, xv.z, acc.z);
            acc.w = fmaf(w0, xv.w, acc.w);
        }
    }
    if (c < F) *(float4*)&out[(size_t)nid * F + c] = acc;
}

// F=2 agg: node per thread
__global__ void k_spmm2(const int* __restrict__ roff, const int* __restrict__ csr_src,
                        const float* __restrict__ csr_nrm,
                        const float* __restrict__ X, float* __restrict__ out) {
    int nid = blockIdx.x * blockDim.x + threadIdx.x;
    if (nid < NN) {
        int s0 = roff[nid], s1 = roff[nid + 1];
        float a0 = 0.f, a1 = 0.f;
        for (int s = s0; s < s1; ++s) {
            int i = csr_src[s]; float w = csr_nrm[s];
            float2 xv = *(const float2*)&X[2 * i];
            a0 = fmaf(w, xv.x, a0);
            a1 = fmaf(w, xv.y, a1);
        }
        out[2 * nid] = a0;
        out[2 * nid + 1] = a1;
    }
}

// ---------------- dense graph prep (rollout) ----------------
// fused: deg reduce -> dinv
__global__ void k_ddeg(const float* __restrict__ c, float* __restrict__ dinv) {
    int i = blockIdx.x;
    int t = threadIdx.x;
    float xi = c[2 * i], yi = c[2 * i + 1];
    float s = 0.f;
    for (int j = t; j < NN; j += 256) {
        float dx = xi - c[2 * j], dy = yi - c[2 * j + 1];
        float d = sqrtf(dx * dx + dy * dy);
        if (d > 0.f && d < 0.5f) s += 2.f * d;
    }
    __shared__ float red[256];
    red[t] = s;
    __syncthreads();
    for (int off = 128; off > 0; off >>= 1) {
        if (t < off) red[t] += red[t + off];
        __syncthreads();
    }
    if (t == 0) {
        float d = red[0];
        dinv[i] = d > 0.f ? 1.f / sqrtf(d) : 0.f;
    }
}

__global__ void k_dM(const float* __restrict__ c, const float* __restrict__ dinv,
                     float* __restrict__ M) {
    int idx = blockIdx.x * blockDim.x + threadIdx.x;
    int i = idx >> 11, j = idx & (NN - 1);
    float dx = c[2 * i] - c[2 * j], dy = c[2 * i + 1] - c[2 * j + 1];
    float d = sqrtf(dx * dx + dy * dy);
    float w = (d > 0.f && d < 0.5f) ? 2.f * d : 0.f;
    M[idx] = -(dinv[i] * w) * dinv[j];
}

// dense agg: out = M @ X via K-split tiled GEMM (NZ=8 -> 1024 blocks for HE)
template <int F>
__global__ __launch_bounds__(256) void k_dmm_ks(
    const float* __restrict__ M, const float* __restrict__ X,
    float* __restrict__ pbuf)
{
    __shared__ float At[32][PAD], Bt[32][PAD];
    const int tid = threadIdx.x, tn = tid & 15, tm = tid >> 4;
    const int m0 = blockIdx.x << 6;
    const int n0 = blockIdx.y << 6;
    const int kb = blockIdx.z * (NN / DMM_NZ);
    float acc[4][4] = {};
    for (int k0 = kb; k0 < kb + NN / DMM_NZ; k0 += 32) {
        for (int i = tid; i < 2048; i += 256) {
            int r = i >> 5, k = i & 31;
            At[k][r] = M[(size_t)(m0 + r) * NN + k0 + k];
        }
        for (int i = tid; i < 512; i += 256) {
            int k = i >> 4, c4 = (i & 15) << 2;
            *(float4*)&Bt[k][c4] = *(const float4*)&X[(size_t)(k0 + k) * F + n0 + c4];
        }
        __syncthreads();
#pragma unroll
        for (int k = 0; k < 32; k++) {
            float4 a = *(float4*)&At[k][tm << 2];
            float4 b = *(float4*)&Bt[k][tn << 2];
            float av[4] = {a.x, a.y, a.z, a.w};
            float bv[4] = {b.x, b.y, b.z, b.w};
#pragma unroll
            for (int i = 0; i < 4; i++)
#pragma unroll
                for (int j = 0; j < 4; j++)
                    acc[i][j] = fmaf(av[i], bv[j], acc[i][j]);
        }
        __syncthreads();
    }
    float* p = pbuf + (size_t)blockIdx.z * NN * F;
#pragma unroll
    for (int i = 0; i < 4; i++) {
        *(float4*)&p[(size_t)(m0 + (tm << 2) + i) * F + n0 + (tn << 2)] =
            make_float4(acc[i][0], acc[i][1], acc[i][2], acc[i][3]);
    }
}

template <int F, int NZ>
__global__ void k_redks(const float* __restrict__ pbuf, float* __restrict__ out) {
    const int TOT = NN * F / 4;
    int i = blockIdx.x * blockDim.x + threadIdx.x;
    if (i < TOT) {
        const float4* p = (const float4*)pbuf;
        float4 s = p[i];
#pragma unroll
        for (int z = 1; z < NZ; z++) {
            float4 v = p[(size_t)z * TOT + i];
            s.x += v.x; s.y += v.y; s.z += v.z; s.w += v.w;
        }
        ((float4*)out)[i] = s;
    }
}

__global__ void k_dmv2(const float* __restrict__ M, const float* __restrict__ X,
                       float* __restrict__ out) {
    int i = blockIdx.x;
    int t = threadIdx.x;
    float a0 = 0.f, a1 = 0.f;
    for (int j = t; j < NN; j += 256) {
        float m = M[i * NN + j];
        a0 = fmaf(m, X[2 * j], a0);
        a1 = fmaf(m, X[2 * j + 1], a1);
    }
    __shared__ float r0[256], r1[256];
    r0[t] = a0;
    r1[t] = a1;
    __syncthreads();
    for (int off = 128; off > 0; off >>= 1) {
        if (t < off) { r0[t] += r0[t + off]; r1[t] += r1[t + off]; }
        __syncthreads();
    }
    if (t == 0) { out[2 * i] = r0[0]; out[2 * i + 1] = r1[0]; }
}

// ---------------- tiled GEMM core ----------------
template <bool RELU>
__device__ __forceinline__ void gemm_seg(
    float (*At)[PAD], float (*Bt)[PAD],
    const float* __restrict__ A, int lda,
    const float* __restrict__ B, int ldb, int K,
    int m0, int tid, int tm, int tn, float (&acc)[4][4])
{
    for (int k0 = 0; k0 < K; k0 += 32) {
        int kc = K - k0;
        if (kc > 32) kc = 32;
        for (int i = tid; i < (kc << 4); i += 256) {
            int k = i >> 4, c4 = (i & 15) << 2;
            *(float4*)&Bt[k][c4] = *(const float4*)&B[(size_t)(k0 + k) * ldb + c4];
        }
        if (kc == 32) {
            for (int i = tid; i < 2048; i += 256) {
                int r = i >> 5, k = i & 31;
                float v = A[(size_t)(m0 + r) * lda + k0 + k];
                At[k][r] = RELU ? fmaxf(v, 0.f) : v;
            }
        } else {
            for (int i = tid; i < kc * 64; i += 256) {
                int r = i / kc, k = i - r * kc;
                float v = A[(size_t)(m0 + r) * lda + k0 + k];
                At[k][r] = RELU ? fmaxf(v, 0.f) : v;
            }
        }
        __syncthreads();
        if (kc == 32) {
#pragma unroll
            for (int k = 0; k < 32; k++) {
                float4 a = *(float4*)&At[k][tm << 2];
                float4 b = *(float4*)&Bt[k][tn << 2];
                float av[4] = {a.x, a.y, a.z, a.w};
                float bv[4] = {b.x, b.y, b.z, b.w};
#pragma unroll
                for (int i = 0; i < 4; i++)
#pragma unroll
                    for (int j = 0; j < 4; j++)
                        acc[i][j] = fmaf(av[i], bv[j], acc[i][j]);
            }
        } else {
            for (int k = 0; k < kc; k++) {
                float4 a = *(float4*)&At[k][tm << 2];
                float4 b = *(float4*)&Bt[k][tn << 2];
                float av[4] = {a.x, a.y, a.z, a.w};
                float bv[4] = {b.x, b.y, b.z, b.w};
#pragma unroll
                for (int i = 0; i < 4; i++)
#pragma unroll
                    for (int j = 0; j < 4; j++)
                        acc[i][j] = fmaf(av[i], bv[j], acc[i][j]);
            }
        }
        __syncthreads();
    }
}

// z/r gates K-split: grid (NN/64, 8, ZR_NZ); pbuf slab z: [NN][512]
__global__ __launch_bounds__(256) void k_zr_ks(
    const float* __restrict__ A0, int K01, const float* __restrict__ A1,
    const float* __restrict__ H, const float* __restrict__ A3,
    const float* __restrict__ Wx, const float* __restrict__ Wh,
    float* __restrict__ pbuf)
{
    __shared__ float At[32][PAD], Bt[32][PAD];
    int tid = threadIdx.x, tn = tid & 15, tm = tid >> 4;
    int m0 = blockIdx.x << 6;
    int g = blockIdx.y >> 2;
    int n0 = (blockIdx.y & 3) << 6;
    float acc[4][4] = {};
    const float* As[4] = {A0, A1, H, A3};
    const int ldas[4] = {K01, K01, HE, HE};
    const float* Bs[4] = {
        Wx + (size_t)(g * 2 + 0) * K01 * HE + n0,
        Wx + (size_t)(g * 2 + 1) * K01 * HE + n0,
        Wh + (size_t)(g * 2 + 0) * HE * HE + n0,
        Wh + (size_t)(g * 2 + 1) * HE * HE + n0};
    const int Ks[4] = {K01, K01, HE, HE};
    int tot = 2 * K01 + 2 * HE;
    int chunk = (tot + ZR_NZ - 1) / ZR_NZ;
    int lo = blockIdx.z * chunk, hi = lo + chunk;
    int off = 0;
#pragma unroll
    for (int s = 0; s < 4; s++) {
        int a = lo - off; a = a < 0 ? 0 : a;
        int b = hi - off; b = b > Ks[s] ? Ks[s] : b;
        if (b > a)
            gemm_seg<false>(At, Bt, As[s] + a, ldas[s], Bs[s] + (size_t)a * HE, HE,
                            b - a, m0, tid, tm, tn, acc);
        off += Ks[s];
    }
    float* p = pbuf + (size_t)blockIdx.z * NN * 512;
    int c = (g << 8) + n0 + (tn << 2);
#pragma unroll
    for (int i = 0; i < 4; i++)
        *(float4*)&p[(size_t)(m0 + (tm << 2) + i) * 512 + c] =
            make_float4(acc[i][0], acc[i][1], acc[i][2], acc[i][3]);
}

__global__ void k_zr_ep(const float* __restrict__ pbuf,
                        const float* __restrict__ bx, const float* __restrict__ bh,
                        const float* __restrict__ H,
                        float* __restrict__ gz, float* __restrict__ hr)
{
    int i = blockIdx.x * 256 + threadIdx.x;  // < NN*512/4
    const float4* p = (const float4*)pbuf;
    const size_t S = (size_t)NN * 512 / 4;
    float4 a = p[i];
#pragma unroll
    for (int z = 1; z < ZR_NZ; z++) {
        float4 v = p[(size_t)z * S + i];
        a.x += v.x; a.y += v.y; a.z += v.z; a.w += v.w;
    }
    int row = i >> 7, c = (i & 127) << 2;
    float4 b0 = *(const float4*)&bx[c];
    float4 b1 = *(const float4*)&bh[c];
    float4 s;
    s.x = 1.f / (1.f + expf(-(a.x + b0.x + b1.x)));
    s.y = 1.f / (1.f + expf(-(a.y + b0.y + b1.y)));
    s.z = 1.f / (1.f + expf(-(a.z + b0.z + b1.z)));
    s.w = 1.f / (1.f + expf(-(a.w + b0.w + b1.w)));
    if (c < HE) {
        *(float4*)&gz[(size_t)row * HE + c] = s;
    } else {
        float4 h = *(const float4*)&H[(size_t)row * HE + c - HE];
        s.x *= h.x; s.y *= h.y; s.z *= h.z; s.w *= h.w;
        *(float4*)&hr[(size_t)row * HE + c - HE] = s;
    }
}

// candidate gate K-split: grid (NN/64, 4, GT_NZ); pbuf slab z: [NN][256]
__global__ __launch_bounds__(256) void k_gt_ks(
    const float* __restrict__ A0, int K01, const float* __restrict__ A1,
    const float* __restrict__ hr, const float* __restrict__ A3,
    const float* __restrict__ Wx2, const float* __restrict__ Wh2,
    float* __restrict__ pbuf)
{
    __shared__ float At[32][PAD], Bt[32][PAD];
    int tid = threadIdx.x, tn = tid & 15, tm = tid >> 4;
    int m0 = blockIdx.x << 6;
    int n0 = blockIdx.y << 6;
    float acc[4][4] = {};
    const float* As[4] = {A0, A1, hr, A3};
    const int ldas[4] = {K01, K01, HE, HE};
    const float* Bs[4] = {
        Wx2 + n0,
        Wx2 + (size_t)K01 * HE + n0,
        Wh2 + n0,
        Wh2 + (size_t)HE * HE + n0};
    const int Ks[4] = {K01, K01, HE, HE};
    int tot = 2 * K01 + 2 * HE;
    int chunk = (tot + GT_NZ - 1) / GT_NZ;
    int lo = blockIdx.z * chunk, hi = lo + chunk;
    int off = 0;
#pragma unroll
    for (int s = 0; s < 4; s++) {
        int a = lo - off; a = a < 0 ? 0 : a;
        int b = hi - off; b = b > Ks[s] ? Ks[s] : b;
        if (b > a)
            gemm_seg<false>(At, Bt, As[s] + a, ldas[s], Bs[s] + (size_t)a * HE, HE,
                            b - a, m0, tid, tm, tn, acc);
        off += Ks[s];
    }
    float* p = pbuf + (size_t)blockIdx.z * NN * HE;
    int c = n0 + (tn << 2);
#pragma unroll
    for (int i = 0; i < 4; i++)
        *(float4*)&p[(size_t)(m0 + (tm << 2) + i) * HE + c] =
            make_float4(acc[i][0], acc[i][1], acc[i][2], acc[i][3]);
}

__global__ void k_gt_ep(const float* __restrict__ pbuf,
                        const float* __restrict__ bx2, const float* __restrict__ bh2,
                        const float* __restrict__ gz, float* __restrict__ H)
{
    int i = blockIdx.x * 256 + threadIdx.x;  // < NN*256/4
    const float4* p = (const float4*)pbuf;
    const size_t S = (size_t)NN * HE / 4;
    float4 a = p[i];
#pragma unroll
    for (int z = 1; z < GT_NZ; z++) {
        float4 v = p[(size_t)z * S + i];
        a.x += v.x; a.y += v.y; a.z += v.z; a.w += v.w;
    }
    int row = i >> 6, c = (i & 63) << 2;
    float4 b0 = *(const float4*)&bx2[c];
    float4 b1 = *(const float4*)&bh2[c];
    size_t idx = (size_t)row * HE + c;
    float4 z = *(const float4*)&gz[idx];
    float4 h = *(const float4*)&H[idx];
    float4 o;
    o.x = z.x * h.x + (1.f - z.x) * tanhf(a.x + b0.x + b1.x);
    o.y = z.y * h.y + (1.f - z.y) * tanhf(a.y + b0.y + b1.y);
    o.z = z.z * h.z + (1.f - z.z) * tanhf(a.z + b0.z + b1.z);
    o.w = z.w * h.w + (1.f - z.w) * tanhf(a.w + b0.w + b1.w);
    *(float4*)&H[idx] = o;
}

// latent linear K-split: relu(H) @ elinW ; grid (NN/64, 2, LIN_NZ); slab: [NN][128]
__global__ __launch_bounds__(256) void k_lin_ks(
    const float* __restrict__ A, const float* __restrict__ B,
    float* __restrict__ pbuf)
{
    __shared__ float At[32][PAD], Bt[32][PAD];
    int tid = threadIdx.x, tn = tid & 15, tm = tid >> 4;
    int m0 = blockIdx.x << 6;
    int n0 = blockIdx.y << 6;
    int lo = blockIdx.z << 5;  // 32 per slice
    float acc[4][4] = {};
    gemm_seg<true>(At, Bt, A + lo, HE, B + (size_t)lo * LT + n0, LT, 32,
                   m0, tid, tm, tn, acc);
    float* p = pbuf + (size_t)blockIdx.z * NN * LT;
    int c = n0 + (tn << 2);
#pragma unroll
    for (int i = 0; i < 4; i++)
        *(float4*)&p[(size_t)(m0 + (tm << 2) + i) * LT + c] =
            make_float4(acc[i][0], acc[i][1], acc[i][2], acc[i][3]);
}

__global__ void k_lin_ep(const float* __restrict__ pbuf,
                         const float* __restrict__ bias, float* __restrict__ out)
{
    int i = blockIdx.x * 256 + threadIdx.x;  // < NN*128/4
    const float4* p = (const float4*)pbuf;
    const size_t S = (size_t)NN * LT / 4;
    int c = (i & 31) << 2;
    float4 bb = *(const float4*)&bias[c];
    float4 s = make_float4(bb.x, bb.y, bb.z, bb.w);
#pragma unroll
    for (int z = 0; z < LIN_NZ; z++) {
        float4 v = p[z * S + i];
        s.x += v.x; s.y += v.y; s.z += v.z; s.w += v.w;
    }
    ((float4*)out)[i] = s;
}

// y_hat = relu(H) @ dlinW + dlinb : one wave per row
__global__ void k_declin(const float* __restrict__ A, const float* __restrict__ B,
                         const float* __restrict__ bias, float* __restrict__ out) {
    int w = threadIdx.x >> 6, lane = threadIdx.x & 63;
    int m = blockIdx.x * 4 + w;
    float4 a = *(const float4*)&A[(size_t)m * HE + (lane << 2)];
    float av[4] = {a.x, a.y, a.z, a.w};
    float a0 = 0.f, a1 = 0.f;
#pragma unroll
    for (int j = 0; j < 4; j++) {
        float v = fmaxf(av[j], 0.f);
        float2 b = *(const float2*)&B[((lane << 2) + j) * 2];
        a0 = fmaf(v, b.x, a0);
        a1 = fmaf(v, b.y, a1);
    }
    for (int off = 32; off > 0; off >>= 1) {
        a0 += __shfl_down(a0, off, 64);
        a1 += __shfl_down(a1, off, 64);
    }
    if (lane == 0) {
        out[2 * m] = a0 + bias[0];
        out[2 * m + 1] = a1 + bias[1];
    }
}

extern "C" void kernel_launch(void* const* d_in, const int* in_sizes, int n_in,
                              void* d_out, int out_size, void* d_ws, size_t ws_size,
                              hipStream_t stream) {
    (void)in_sizes; (void)n_in; (void)out_size; (void)ws_size;
    const float* x_seq = (const float*)d_in[0];
    const int* ei = (const int*)d_in[1];
    const float* ews = (const float*)d_in[2];
    const float* h_enc_in = (const float*)d_in[3];
    const float* h_dec_in = (const float*)d_in[4];
    const float* encWx = (const float*)d_in[5];
    const float* encbx = (const float*)d_in[6];
    const float* encWh = (const float*)d_in[7];
    const float* encbh = (const float*)d_in[8];
    const float* elinW = (const float*)d_in[9];
    const float* elinb = (const float*)d_in[10];
    const float* decWx = (const float*)d_in[11];
    const float* decbx = (const float*)d_in[12];
    const float* decWh = (const float*)d_in[13];
    const float* decbh = (const float*)d_in[14];
    const float* dlinW = (const float*)d_in[15];
    const float* dlinb = (const float*)d_in[16];
    float* out = (float*)d_out;

    float* W = (float*)d_ws;
    float* h_enc = W; W += (size_t)NN * HE;
    float* h_dec = W; W += (size_t)NN * HE;
    float* aggx  = W; W += (size_t)NN * HE;
    float* aggh  = W; W += (size_t)NN * HE;
    float* hr    = W; W += (size_t)NN * HE;
    float* agghr = W; W += (size_t)NN * HE;
    float* gz    = W; W += (size_t)NN * HE;
    float* zlat  = W; W += (size_t)NN * LT;
    float* yhat  = W; W += (size_t)NN * FIN;
    float* deg   = W; W += NN;
    float* dinv  = W; W += NN;
    float* csr_nrm = W; W += EE;
    float* Mm    = W; W += (size_t)NN * NN;
    float* pbuf  = W; W += (size_t)ZR_NZ * NN * 512;  // 16 MB, reused by all K-splits
    int* cnt  = (int*)W;
    int* roff = cnt + NN;
    int* cur  = roff + (NN + 2);
    int* csr_src = cur + NN;

    hipMemcpyAsync(h_enc, h_enc_in, sizeof(float) * NN * HE, hipMemcpyDeviceToDevice, stream);
    hipMemcpyAsync(h_dec, h_dec_in, sizeof(float) * NN * HE, hipMemcpyDeviceToDevice, stream);

    for (int step = 0; step < T_OBS + PREDN - 1; ++step) {
        bool sparse = step < T_OBS;
        const float* xin;
        if (sparse) {
            const int* srcp = ei + (size_t)step * 2 * EE;
            const int* dstp = srcp + EE;
            const float* ewt = ews + (size_t)step * EE;
            hipMemsetAsync(deg, 0, sizeof(float) * NN, stream);
            hipMemsetAsync(cnt, 0, sizeof(int) * NN, stream);
            k_degcnt<<<EE / 256, 256, 0, stream>>>(srcp, dstp, ewt, deg, cnt);
            k_dinv<<<NN / 256, 256, 0, stream>>>(deg, dinv);
            k_scan<<<1, 256, 0, stream>>>(cnt, roff, cur);
            k_scatter2<<<EE / 256, 256, 0, stream>>>(srcp, dstp, ewt, dinv, cur,
                                                     csr_src, csr_nrm);
            xin = x_seq + (size_t)step * NN * FIN;
        } else {
            k_ddeg<<<NN, 256, 0, stream>>>(yhat, dinv);
            k_dM<<<(NN * NN) / 256, 256, 0, stream>>>(yhat, dinv, Mm);
            xin = yhat;
        }

        // ======= encoder GRU (x: F=2, H: h_enc) =======
        if (sparse) k_spmm2<<<NN / 256, 256, 0, stream>>>(roff, csr_src, csr_nrm, xin, aggx);
        else        k_dmv2<<<NN, 256, 0, stream>>>(Mm, xin, aggx);
        if (sparse) {
            k_spmm_v<HE><<<NN / 4, 256, 0, stream>>>(roff, csr_src, csr_nrm, h_enc, aggh);
        } else {
            k_dmm_ks<HE><<<dim3(NN / 64, HE / 64, DMM_NZ), 256, 0, stream>>>(Mm, h_enc, pbuf);
            k_redks<HE, DMM_NZ><<<NN * HE / 4 / 256, 256, 0, stream>>>(pbuf, aggh);
        }
        k_zr_ks<<<dim3(NN / 64, 8, ZR_NZ), 256, 0, stream>>>(xin, FIN, aggx, h_enc, aggh,
                                                             encWx, encWh, pbuf);
        k_zr_ep<<<NN * 512 / 4 / 256, 256, 0, stream>>>(pbuf, encbx, encbh, h_enc, gz, hr);
        if (sparse) {
            k_spmm_v<HE><<<NN / 4, 256, 0, stream>>>(roff, csr_src, csr_nrm, hr, agghr);
        } else {
            k_dmm_ks<HE><<<dim3(NN / 64, HE / 64, DMM_NZ), 256, 0, stream>>>(Mm, hr, pbuf);
            k_redks<HE, DMM_NZ><<<NN * HE / 4 / 256, 256, 0, stream>>>(pbuf, agghr);
        }
        k_gt_ks<<<dim3(NN / 64, 4, GT_NZ), 256, 0, stream>>>(xin, FIN, aggx, hr, agghr,
                                                             encWx + 4 * FIN * HE,
                                                             encWh + 4 * HE * HE, pbuf);
        k_gt_ep<<<NN * HE / 4 / 256, 256, 0, stream>>>(pbuf, encbx + 2 * HE,
                                                       encbh + 2 * HE, gz, h_enc);
        k_lin_ks<<<dim3(NN / 64, 2, LIN_NZ), 256, 0, stream>>>(h_enc, elinW, pbuf);
        k_lin_ep<<<NN * LT / 4 / 256, 256, 0, stream>>>(pbuf, elinb, zlat);

        // ======= decoder GRU (x: zlat F=128, H: h_dec) =======
        if (sparse) {
            k_spmm_v<LT><<<NN / 4, 256, 0, stream>>>(roff, csr_src, csr_nrm, zlat, aggx);
        } else {
            k_dmm_ks<LT><<<dim3(NN / 64, LT / 64, DMM_NZ), 256, 0, stream>>>(Mm, zlat, pbuf);
            k_redks<LT, DMM_NZ><<<NN * LT / 4 / 256, 256, 0, stream>>>(pbuf, aggx);
        }
        if (sparse) {
            k_spmm_v<HE><<<NN / 4, 256, 0, stream>>>(roff, csr_src, csr_nrm, h_dec, aggh);
        } else {
            k_dmm_ks<HE><<<dim3(NN / 64, HE / 64, DMM_NZ), 256, 0, stream>>>(Mm, h_dec, pbuf);
            k_redks<HE, DMM_NZ><<<NN * HE / 4 / 256, 256, 0, stream>>>(pbuf, aggh);
        }
        k_zr_ks<<<dim3(NN / 64, 8, ZR_NZ), 256, 0, stream>>>(zlat, LT, aggx, h_dec, aggh,
                                                             decWx, decWh, pbuf);
        k_zr_ep<<<NN * 512 / 4 / 256, 256, 0, stream>>>(pbuf, decbx, decbh, h_dec, gz, hr);
        if (sparse) {
            k_spmm_v<HE><<<NN / 4, 256, 0, stream>>>(roff, csr_src, csr_nrm, hr, agghr);
        } else {
            k_dmm_ks<HE><<<dim3(NN / 64, HE / 64, DMM_NZ), 256, 0, stream>>>(Mm, hr, pbuf);
            k_redks<HE, DMM_NZ><<<NN * HE / 4 / 256, 256, 0, stream>>>(pbuf, agghr);
        }
        k_gt_ks<<<dim3(NN / 64, 4, GT_NZ), 256, 0, stream>>>(zlat, LT, aggx, hr, agghr,
                                                             decWx + 4 * LT * HE,
                                                             decWh + 4 * HE * HE, pbuf);
        k_gt_ep<<<NN * HE / 4 / 256, 256, 0, stream>>>(pbuf, decbx + 2 * HE,
                                                       decbh + 2 * HE, gz, h_dec);
        k_declin<<<NN / 4, 256, 0, stream>>>(h_dec, dlinW, dlinb, yhat);

        if (step >= T_OBS - 1) {
            hipMemcpyAsync(out + (size_t)(step - (T_OBS - 1)) * NN * FIN, yhat,
                           sizeof(float) * NN * FIN, hipMemcpyDeviceToDevice, stream);
        }
    }
}

// Round 7
// 2810.141 us; speedup vs baseline: 4.9625x; 1.1739x over previous
//
#include <hip/hip_runtime.h>
#include <math.h>

#define NN 2048
#define EE 65536
#define T_OBS 6
#define FIN 2
#define HE 256
#define LT 128
#define PREDN 6
#define PAD 68
#define DMM_NZ 8
#define ZR_NZ 4
#define GT_NZ 8
#define LIN_NZ 8

typedef __attribute__((ext_vector_type(8))) short short8v;
typedef __attribute__((ext_vector_type(4))) float float4v;

static __device__ __forceinline__ unsigned short f2bf(float f) {
    union { float f; unsigned u; } v; v.f = f;
    unsigned r = v.u + 0x7fff + ((v.u >> 16) & 1);
    return (unsigned short)(r >> 16);
}

// ---------------- sparse graph prep ----------------
__global__ void k_degcnt(const int* __restrict__ src, const int* __restrict__ dst,
                         const float* __restrict__ ew,
                         float* __restrict__ deg, int* __restrict__ cnt) {
    int e = blockIdx.x * blockDim.x + threadIdx.x;
    if (e < EE) {
        atomicAdd(&deg[src[e]], ew[e]);
        atomicAdd(&cnt[dst[e]], 1);
    }
}

// scan of cnt -> roff/cur, plus dinv = rsqrt(deg) fused
__global__ void k_scan(const int* __restrict__ cnt, const float* __restrict__ deg,
                       int* __restrict__ roff, int* __restrict__ cur,
                       float* __restrict__ dinv) {
    __shared__ int part[256];
    int t = threadIdx.x;
#pragma unroll
    for (int i = t; i < NN; i += 256) {
        float d = deg[i];
        dinv[i] = d > 0.f ? 1.f / sqrtf(d) : 0.f;
    }
    int loc[8];
    int s = 0;
#pragma unroll
    for (int i = 0; i < 8; i++) { loc[i] = cnt[t * 8 + i]; s += loc[i]; }
    part[t] = s;
    __syncthreads();
    for (int off = 1; off < 256; off <<= 1) {
        int v = (t >= off) ? part[t - off] : 0;
        __syncthreads();
        part[t] += v;
        __syncthreads();
    }
    int run = (t == 0) ? 0 : part[t - 1];
#pragma unroll
    for (int i = 0; i < 8; i++) {
        int idx = t * 8 + i;
        roff[idx] = run;
        cur[idx] = run;
        run += loc[i];
    }
    if (t == 255) roff[NN] = run;
}

__global__ void k_scatter2(const int* __restrict__ src, const int* __restrict__ dst,
                           const float* __restrict__ ew, const float* __restrict__ dinv,
                           int* __restrict__ cur,
                           int* __restrict__ csr_src, float* __restrict__ csr_nrm) {
    int e = blockIdx.x * blockDim.x + threadIdx.x;
    if (e < EE) {
        int s = src[e], d = dst[e];
        int p = atomicAdd(&cur[d], 1);
        csr_src[p] = s;
        csr_nrm[p] = -dinv[s] * ew[e] * dinv[d];
    }
}

// CSR SpMM, wave per node, float4 per lane, 8 edges batched
template <int F>
__global__ void k_spmm_v(const int* __restrict__ roff, const int* __restrict__ csr_src,
                         const float* __restrict__ csr_nrm,
                         const float* __restrict__ X, float* __restrict__ out) {
    int w = threadIdx.x >> 6, lane = threadIdx.x & 63;
    int nid = (blockIdx.x << 2) + w;
    int c = lane << 2;
    int s0 = roff[nid], s1 = roff[nid + 1];
    float4 acc = make_float4(0.f, 0.f, 0.f, 0.f);
    int s = s0;
    for (; s + 8 <= s1; s += 8) {
        int is[8]; float ws[8];
#pragma unroll
        for (int j = 0; j < 8; j++) { is[j] = csr_src[s + j]; ws[j] = csr_nrm[s + j]; }
        if (c < F) {
            float4 xv[8];
#pragma unroll
            for (int j = 0; j < 8; j++) xv[j] = *(const float4*)&X[(size_t)is[j] * F + c];
#pragma unroll
            for (int j = 0; j < 8; j++) {
                acc.x = fmaf(ws[j], xv[j].x, acc.x);
                acc.y = fmaf(ws[j], xv[j].y, acc.y);
                acc.z = fmaf(ws[j], xv[j].z, acc.z);
                acc.w = fmaf(ws[j], xv[j].w, acc.w);
            }
        }
    }
    for (; s < s1; ++s) {
        int i0 = csr_src[s]; float w0 = csr_nrm[s];
        if (c < F) {
            float4 xv = *(const float4*)&X[(size_t)i0 * F + c];
            acc.x = fmaf(w0, xv.x, acc.x);
            acc.y = fmaf(w0, xv.y, acc.y);
            acc.z = fmaf(w0, xv.z, acc.z);
            acc.w = fmaf(w0, xv.w, acc.w);
        }
    }
    if (c < F) *(float4*)&out[(size_t)nid * F + c] = acc;
}

__global__ void k_spmm2(const int* __restrict__ roff, const int* __restrict__ csr_src,
                        const float* __restrict__ csr_nrm,
                        const float* __restrict__ X, float* __restrict__ out) {
    int nid = blockIdx.x * blockDim.x + threadIdx.x;
    if (nid < NN) {
        int s0 = roff[nid], s1 = roff[nid + 1];
        float a0 = 0.f, a1 = 0.f;
        for (int s = s0; s < s1; ++s) {
            int i = csr_src[s]; float w = csr_nrm[s];
            float2 xv = *(const float2*)&X[2 * i];
            a0 = fmaf(w, xv.x, a0);
            a1 = fmaf(w, xv.y, a1);
        }
        out[2 * nid] = a0;
        out[2 * nid + 1] = a1;
    }
}

// ---------------- dense graph prep (rollout) ----------------
__global__ void k_ddeg(const float* __restrict__ c, float* __restrict__ dinv) {
    int i = blockIdx.x;
    int t = threadIdx.x;
    float xi = c[2 * i], yi = c[2 * i + 1];
    float s = 0.f;
    for (int j = t; j < NN; j += 256) {
        float dx = xi - c[2 * j], dy = yi - c[2 * j + 1];
        float d = sqrtf(dx * dx + dy * dy);
        if (d > 0.f && d < 0.5f) s += 2.f * d;
    }
    __shared__ float red[256];
    red[t] = s;
    __syncthreads();
    for (int off = 128; off > 0; off >>= 1) {
        if (t < off) red[t] += red[t + off];
        __syncthreads();
    }
    if (t == 0) {
        float d = red[0];
        dinv[i] = d > 0.f ? 1.f / sqrtf(d) : 0.f;
    }
}

// M in fp32 (for dmv2) and bf16 (for MFMA agg)
__global__ void k_dM(const float* __restrict__ c, const float* __restrict__ dinv,
                     float* __restrict__ M, unsigned short* __restrict__ Mb) {
    int idx = blockIdx.x * blockDim.x + threadIdx.x;
    int i = idx >> 11, j = idx & (NN - 1);
    float dx = c[2 * i] - c[2 * j], dy = c[2 * i + 1] - c[2 * j + 1];
    float d = sqrtf(dx * dx + dy * dy);
    float w = (d > 0.f && d < 0.5f) ? 2.f * d : 0.f;
    float v = -(dinv[i] * w) * dinv[j];
    M[idx] = v;
    Mb[idx] = f2bf(v);
}

// dense agg via bf16 MFMA: out = M @ X. grid (NN/64, F/64, DMM_NZ), 256 thr.
// per block: 64x64 C tile over K-chunk 256, BK=64. fp32 partial to pbuf.
template <int F>
__global__ __launch_bounds__(256) void k_dmm_mf(
    const unsigned short* __restrict__ Mb, const float* __restrict__ X,
    float* __restrict__ pbuf)
{
    __shared__ unsigned short Ms[64][72];  // [m][k] bf16
    __shared__ unsigned short Xs[64][72];  // [n][k] bf16 (transposed)
    const int tid = threadIdx.x;
    const int wid = tid >> 6, lane = tid & 63;
    const int m0 = blockIdx.x << 6, n0 = blockIdx.y << 6;
    const int kb0 = blockIdx.z << 8;
    const int lr = lane & 15;
    const int kg = lane >> 4;
    float4v acc[4];
#pragma unroll
    for (int t = 0; t < 4; t++) acc[t] = (float4v){0.f, 0.f, 0.f, 0.f};

    for (int kb = kb0; kb < kb0 + 256; kb += 64) {
        // stage M tile: 64 rows x 64 k bf16, 16B per thread x2
#pragma unroll
        for (int it = 0; it < 2; it++) {
            int i = tid + it * 256;          // 0..511
            int r = i >> 3, c8 = (i & 7) << 3;
            *(short8v*)&Ms[r][c8] =
                *(const short8v*)&Mb[(size_t)(m0 + r) * NN + kb + c8];
        }
        // stage X transposed + fp32->bf16; k-major write (conflict-free)
#pragma unroll
        for (int it = 0; it < 2; it++) {
            int i = tid + it * 256;          // 0..511
            int k2 = (i & 31) << 1;          // 0,2,..62
            int n4 = (i >> 5) << 2;          // 0,4,..60
            float4 va = *(const float4*)&X[(size_t)(kb + k2) * F + n0 + n4];
            float4 vb = *(const float4*)&X[(size_t)(kb + k2 + 1) * F + n0 + n4];
            unsigned pk;
            pk = (unsigned)f2bf(va.x) | ((unsigned)f2bf(vb.x) << 16);
            *(unsigned*)&Xs[n4 + 0][k2] = pk;
            pk = (unsigned)f2bf(va.y) | ((unsigned)f2bf(vb.y) << 16);
            *(unsigned*)&Xs[n4 + 1][k2] = pk;
            pk = (unsigned)f2bf(va.z) | ((unsigned)f2bf(vb.z) << 16);
            *(unsigned*)&Xs[n4 + 2][k2] = pk;
            pk = (unsigned)f2bf(va.w) | ((unsigned)f2bf(vb.w) << 16);
            *(unsigned*)&Xs[n4 + 3][k2] = pk;
        }
        __syncthreads();
#pragma unroll
        for (int kh = 0; kh < 2; kh++) {
            int kk = kh * 32 + kg * 8;
            short8v a = *(const short8v*)&Ms[(wid << 4) + lr][kk];
#pragma unroll
            for (int t = 0; t < 4; t++) {
                short8v b = *(const short8v*)&Xs[(t << 4) + lr][kk];
                acc[t] = __builtin_amdgcn_mfma_f32_16x16x32_bf16(a, b, acc[t], 0, 0, 0);
            }
        }
        __syncthreads();
    }
    // C/D layout: col = lane&15, row = (lane>>4)*4 + reg
    float* p = pbuf + (size_t)blockIdx.z * NN * F;
#pragma unroll
    for (int t = 0; t < 4; t++)
#pragma unroll
        for (int j = 0; j < 4; j++)
            p[(size_t)(m0 + (wid << 4) + (kg << 2) + j) * F + n0 + (t << 4) + lr] =
                acc[t][j];
}

template <int F, int NZ>
__global__ void k_redks(const float* __restrict__ pbuf, float* __restrict__ out) {
    const int TOT = NN * F / 4;
    int i = blockIdx.x * blockDim.x + threadIdx.x;
    if (i < TOT) {
        const float4* p = (const float4*)pbuf;
        float4 s = p[i];
#pragma unroll
        for (int z = 1; z < NZ; z++) {
            float4 v = p[(size_t)z * TOT + i];
            s.x += v.x; s.y += v.y; s.z += v.z; s.w += v.w;
        }
        ((float4*)out)[i] = s;
    }
}

__global__ void k_dmv2(const float* __restrict__ M, const float* __restrict__ X,
                       float* __restrict__ out) {
    int i = blockIdx.x;
    int t = threadIdx.x;
    float a0 = 0.f, a1 = 0.f;
    for (int j = t; j < NN; j += 256) {
        float m = M[i * NN + j];
        a0 = fmaf(m, X[2 * j], a0);
        a1 = fmaf(m, X[2 * j + 1], a1);
    }
    __shared__ float r0[256], r1[256];
    r0[t] = a0;
    r1[t] = a1;
    __syncthreads();
    for (int off = 128; off > 0; off >>= 1) {
        if (t < off) { r0[t] += r0[t + off]; r1[t] += r1[t + off]; }
        __syncthreads();
    }
    if (t == 0) { out[2 * i] = r0[0]; out[2 * i + 1] = r1[0]; }
}

// ---------------- tiled GEMM core ----------------
template <bool RELU>
__device__ __forceinline__ void gemm_seg(
    float (*At)[PAD], float (*Bt)[PAD],
    const float* __restrict__ A, int lda,
    const float* __restrict__ B, int ldb, int K,
    int m0, int tid, int tm, int tn, float (&acc)[4][4])
{
    for (int k0 = 0; k0 < K; k0 += 32) {
        int kc = K - k0;
        if (kc > 32) kc = 32;
        for (int i = tid; i < (kc << 4); i += 256) {
            int k = i >> 4, c4 = (i & 15) << 2;
            *(float4*)&Bt[k][c4] = *(const float4*)&B[(size_t)(k0 + k) * ldb + c4];
        }
        if (kc == 32) {
            for (int i = tid; i < 2048; i += 256) {
                int r = i >> 5, k = i & 31;
                float v = A[(size_t)(m0 + r) * lda + k0 + k];
                At[k][r] = RELU ? fmaxf(v, 0.f) : v;
            }
        } else {
            for (int i = tid; i < kc * 64; i += 256) {
                int r = i / kc, k = i - r * kc;
                float v = A[(size_t)(m0 + r) * lda + k0 + k];
                At[k][r] = RELU ? fmaxf(v, 0.f) : v;
            }
        }
        __syncthreads();
        if (kc == 32) {
#pragma unroll
            for (int k = 0; k < 32; k++) {
                float4 a = *(float4*)&At[k][tm << 2];
                float4 b = *(float4*)&Bt[k][tn << 2];
                float av[4] = {a.x, a.y, a.z, a.w};
                float bv[4] = {b.x, b.y, b.z, b.w};
#pragma unroll
                for (int i = 0; i < 4; i++)
#pragma unroll
                    for (int j = 0; j < 4; j++)
                        acc[i][j] = fmaf(av[i], bv[j], acc[i][j]);
            }
        } else {
            for (int k = 0; k < kc; k++) {
                float4 a = *(float4*)&At[k][tm << 2];
                float4 b = *(float4*)&Bt[k][tn << 2];
                float av[4] = {a.x, a.y, a.z, a.w};
                float bv[4] = {b.x, b.y, b.z, b.w};
#pragma unroll
                for (int i = 0; i < 4; i++)
#pragma unroll
                    for (int j = 0; j < 4; j++)
                        acc[i][j] = fmaf(av[i], bv[j], acc[i][j]);
            }
        }
        __syncthreads();
    }
}

// z/r gates K-split: grid (NN/64, 8, ZR_NZ); pbuf slab z: [NN][512]
__global__ __launch_bounds__(256) void k_zr_ks(
    const float* __restrict__ A0, int K01, const float* __restrict__ A1,
    const float* __restrict__ H, const float* __restrict__ A3,
    const float* __restrict__ Wx, const float* __restrict__ Wh,
    float* __restrict__ pbuf)
{
    __shared__ float At[32][PAD], Bt[32][PAD];
    int tid = threadIdx.x, tn = tid & 15, tm = tid >> 4;
    int m0 = blockIdx.x << 6;
    int g = blockIdx.y >> 2;
    int n0 = (blockIdx.y & 3) << 6;
    float acc[4][4] = {};
    const float* As[4] = {A0, A1, H, A3};
    const int ldas[4] = {K01, K01, HE, HE};
    const float* Bs[4] = {
        Wx + (size_t)(g * 2 + 0) * K01 * HE + n0,
        Wx + (size_t)(g * 2 + 1) * K01 * HE + n0,
        Wh + (size_t)(g * 2 + 0) * HE * HE + n0,
        Wh + (size_t)(g * 2 + 1) * HE * HE + n0};
    const int Ks[4] = {K01, K01, HE, HE};
    int tot = 2 * K01 + 2 * HE;
    int chunk = (tot + ZR_NZ - 1) / ZR_NZ;
    int lo = blockIdx.z * chunk, hi = lo + chunk;
    int off = 0;
#pragma unroll
    for (int s = 0; s < 4; s++) {
        int a = lo - off; a = a < 0 ? 0 : a;
        int b = hi - off; b = b > Ks[s] ? Ks[s] : b;
        if (b > a)
            gemm_seg<false>(At, Bt, As[s] + a, ldas[s], Bs[s] + (size_t)a * HE, HE,
                            b - a, m0, tid, tm, tn, acc);
        off += Ks[s];
    }
    float* p = pbuf + (size_t)blockIdx.z * NN * 512;
    int c = (g << 8) + n0 + (tn << 2);
#pragma unroll
    for (int i = 0; i < 4; i++)
        *(float4*)&p[(size_t)(m0 + (tm << 2) + i) * 512 + c] =
            make_float4(acc[i][0], acc[i][1], acc[i][2], acc[i][3]);
}

__global__ void k_zr_ep(const float* __restrict__ pbuf,
                        const float* __restrict__ bx, const float* __restrict__ bh,
                        const float* __restrict__ H,
                        float* __restrict__ gz, float* __restrict__ hr)
{
    int i = blockIdx.x * 256 + threadIdx.x;  // < NN*512/4
    const float4* p = (const float4*)pbuf;
    const size_t S = (size_t)NN * 512 / 4;
    float4 a = p[i];
#pragma unroll
    for (int z = 1; z < ZR_NZ; z++) {
        float4 v = p[(size_t)z * S + i];
        a.x += v.x; a.y += v.y; a.z += v.z; a.w += v.w;
    }
    int row = i >> 7, c = (i & 127) << 2;
    float4 b0 = *(const float4*)&bx[c];
    float4 b1 = *(const float4*)&bh[c];
    float4 s;
    s.x = 1.f / (1.f + expf(-(a.x + b0.x + b1.x)));
    s.y = 1.f / (1.f + expf(-(a.y + b0.y + b1.y)));
    s.z = 1.f / (1.f + expf(-(a.z + b0.z + b1.z)));
    s.w = 1.f / (1.f + expf(-(a.w + b0.w + b1.w)));
    if (c < HE) {
        *(float4*)&gz[(size_t)row * HE + c] = s;
    } else {
        float4 h = *(const float4*)&H[(size_t)row * HE + c - HE];
        s.x *= h.x; s.y *= h.y; s.z *= h.z; s.w *= h.w;
        *(float4*)&hr[(size_t)row * HE + c - HE] = s;
    }
}

// candidate gate K-split: grid (NN/64, 4, GT_NZ); pbuf slab z: [NN][256]
__global__ __launch_bounds__(256) void k_gt_ks(
    const float* __restrict__ A0, int K01, const float* __restrict__ A1,
    const float* __restrict__ hr, const float* __restrict__ A3,
    const float* __restrict__ Wx2, const float* __restrict__ Wh2,
    float* __restrict__ pbuf)
{
    __shared__ float At[32][PAD], Bt[32][PAD];
    int tid = threadIdx.x, tn = tid & 15, tm = tid >> 4;
    int m0 = blockIdx.x << 6;
    int n0 = blockIdx.y << 6;
    float acc[4][4] = {};
    const float* As[4] = {A0, A1, hr, A3};
    const int ldas[4] = {K01, K01, HE, HE};
    const float* Bs[4] = {
        Wx2 + n0,
        Wx2 + (size_t)K01 * HE + n0,
        Wh2 + n0,
        Wh2 + (size_t)HE * HE + n0};
    const int Ks[4] = {K01, K01, HE, HE};
    int tot = 2 * K01 + 2 * HE;
    int chunk = (tot + GT_NZ - 1) / GT_NZ;
    int lo = blockIdx.z * chunk, hi = lo + chunk;
    int off = 0;
#pragma unroll
    for (int s = 0; s < 4; s++) {
        int a = lo - off; a = a < 0 ? 0 : a;
        int b = hi - off; b = b > Ks[s] ? Ks[s] : b;
        if (b > a)
            gemm_seg<false>(At, Bt, As[s] + a, ldas[s], Bs[s] + (size_t)a * HE, HE,
                            b - a, m0, tid, tm, tn, acc);
        off += Ks[s];
    }
    float* p = pbuf + (size_t)blockIdx.z * NN * HE;
    int c = n0 + (tn << 2);
#pragma unroll
    for (int i = 0; i < 4; i++)
        *(float4*)&p[(size_t)(m0 + (tm << 2) + i) * HE + c] =
            make_float4(acc[i][0], acc[i][1], acc[i][2], acc[i][3]);
}

__global__ void k_gt_ep(const float* __restrict__ pbuf,
                        const float* __restrict__ bx2, const float* __restrict__ bh2,
                        const float* __restrict__ gz, float* __restrict__ H)
{
    int i = blockIdx.x * 256 + threadIdx.x;  // < NN*256/4
    const float4* p = (const float4*)pbuf;
    const size_t S = (size_t)NN * HE / 4;
    float4 a = p[i];
#pragma unroll
    for (int z = 1; z < GT_NZ; z++) {
        float4 v = p[(size_t)z * S + i];
        a.x += v.x; a.y += v.y; a.z += v.z; a.w += v.w;
    }
    int row = i >> 6, c = (i & 63) << 2;
    float4 b0 = *(const float4*)&bx2[c];
    float4 b1 = *(const float4*)&bh2[c];
    size_t idx = (size_t)row * HE + c;
    float4 z = *(const float4*)&gz[idx];
    float4 h = *(const float4*)&H[idx];
    float4 o;
    o.x = z.x * h.x + (1.f - z.x) * tanhf(a.x + b0.x + b1.x);
    o.y = z.y * h.y + (1.f - z.y) * tanhf(a.y + b0.y + b1.y);
    o.z = z.z * h.z + (1.f - z.z) * tanhf(a.z + b0.z + b1.z);
    o.w = z.w * h.w + (1.f - z.w) * tanhf(a.w + b0.w + b1.w);
    *(float4*)&H[idx] = o;
}

// latent linear K-split: relu(H) @ elinW ; grid (NN/64, 2, LIN_NZ); slab: [NN][128]
__global__ __launch_bounds__(256) void k_lin_ks(
    const float* __restrict__ A, const float* __restrict__ B,
    float* __restrict__ pbuf)
{
    __shared__ float At[32][PAD], Bt[32][PAD];
    int tid = threadIdx.x, tn = tid & 15, tm = tid >> 4;
    int m0 = blockIdx.x << 6;
    int n0 = blockIdx.y << 6;
    int lo = blockIdx.z << 5;  // 32 per slice
    float acc[4][4] = {};
    gemm_seg<true>(At, Bt, A + lo, HE, B + (size_t)lo * LT + n0, LT, 32,
                   m0, tid, tm, tn, acc);
    float* p = pbuf + (size_t)blockIdx.z * NN * LT;
    int c = n0 + (tn << 2);
#pragma unroll
    for (int i = 0; i < 4; i++)
        *(float4*)&p[(size_t)(m0 + (tm << 2) + i) * LT + c] =
            make_float4(acc[i][0], acc[i][1], acc[i][2], acc[i][3]);
}

__global__ void k_lin_ep(const float* __restrict__ pbuf,
                         const float* __restrict__ bias, float* __restrict__ out)
{
    int i = blockIdx.x * 256 + threadIdx.x;  // < NN*128/4
    const float4* p = (const float4*)pbuf;
    const size_t S = (size_t)NN * LT / 4;
    int c = (i & 31) << 2;
    float4 bb = *(const float4*)&bias[c];
    float4 s = make_float4(bb.x, bb.y, bb.z, bb.w);
#pragma unroll
    for (int z = 0; z < LIN_NZ; z++) {
        float4 v = p[z * S + i];
        s.x += v.x; s.y += v.y; s.z += v.z; s.w += v.w;
    }
    ((float4*)out)[i] = s;
}

// y_hat = relu(H) @ dlinW + dlinb : one wave per row
__global__ void k_declin(const float* __restrict__ A, const float* __restrict__ B,
                         const float* __restrict__ bias, float* __restrict__ out) {
    int w = threadIdx.x >> 6, lane = threadIdx.x & 63;
    int m = blockIdx.x * 4 + w;
    float4 a = *(const float4*)&A[(size_t)m * HE + (lane << 2)];
    float av[4] = {a.x, a.y, a.z, a.w};
    float a0 = 0.f, a1 = 0.f;
#pragma unroll
    for (int j = 0; j < 4; j++) {
        float v = fmaxf(av[j], 0.f);
        float2 b = *(const float2*)&B[((lane << 2) + j) * 2];
        a0 = fmaf(v, b.x, a0);
        a1 = fmaf(v, b.y, a1);
    }
    for (int off = 32; off > 0; off >>= 1) {
        a0 += __shfl_down(a0, off, 64);
        a1 += __shfl_down(a1, off, 64);
    }
    if (lane == 0) {
        out[2 * m] = a0 + bias[0];
        out[2 * m + 1] = a1 + bias[1];
    }
}

extern "C" void kernel_launch(void* const* d_in, const int* in_sizes, int n_in,
                              void* d_out, int out_size, void* d_ws, size_t ws_size,
                              hipStream_t stream) {
    (void)in_sizes; (void)n_in; (void)out_size; (void)ws_size;
    const float* x_seq = (const float*)d_in[0];
    const int* ei = (const int*)d_in[1];
    const float* ews = (const float*)d_in[2];
    const float* h_enc_in = (const float*)d_in[3];
    const float* h_dec_in = (const float*)d_in[4];
    const float* encWx = (const float*)d_in[5];
    const float* encbx = (const float*)d_in[6];
    const float* encWh = (const float*)d_in[7];
    const float* encbh = (const float*)d_in[8];
    const float* elinW = (const float*)d_in[9];
    const float* elinb = (const float*)d_in[10];
    const float* decWx = (const float*)d_in[11];
    const float* decbx = (const float*)d_in[12];
    const float* decWh = (const float*)d_in[13];
    const float* decbh = (const float*)d_in[14];
    const float* dlinW = (const float*)d_in[15];
    const float* dlinb = (const float*)d_in[16];
    float* out = (float*)d_out;

    float* W = (float*)d_ws;
    float* h_enc = W; W += (size_t)NN * HE;
    float* h_dec = W; W += (size_t)NN * HE;
    float* aggx  = W; W += (size_t)NN * HE;
    float* aggh  = W; W += (size_t)NN * HE;
    float* hr    = W; W += (size_t)NN * HE;
    float* agghr = W; W += (size_t)NN * HE;
    float* gz    = W; W += (size_t)NN * HE;
    float* zlat  = W; W += (size_t)NN * LT;
    float* yhat  = W; W += (size_t)NN * FIN;
    float* deg   = W; W += NN;          // deg + cnt adjacent: one memset
    int*   cnt   = (int*)W; W += NN;
    float* dinv  = W; W += NN;
    float* csr_nrm = W; W += EE;
    float* Mm    = W; W += (size_t)NN * NN;
    unsigned short* Mb = (unsigned short*)W; W += (size_t)NN * NN / 2;
    float* pbuf  = W; W += (size_t)ZR_NZ * NN * 512;  // 16 MB, shared by all K-splits
    int* roff = (int*)W;
    int* cur  = roff + (NN + 2);
    int* csr_src = cur + NN;

    hipMemcpyAsync(h_enc, h_enc_in, sizeof(float) * NN * HE, hipMemcpyDeviceToDevice, stream);
    hipMemcpyAsync(h_dec, h_dec_in, sizeof(float) * NN * HE, hipMemcpyDeviceToDevice, stream);

    for (int step = 0; step < T_OBS + PREDN - 1; ++step) {
        bool sparse = step < T_OBS;
        const float* xin;
        if (sparse) {
            const int* srcp = ei + (size_t)step * 2 * EE;
            const int* dstp = srcp + EE;
            const float* ewt = ews + (size_t)step * EE;
            hipMemsetAsync(deg, 0, sizeof(float) * NN * 2, stream);  // deg + cnt
            k_degcnt<<<EE / 256, 256, 0, stream>>>(srcp, dstp, ewt, deg, cnt);
            k_scan<<<1, 256, 0, stream>>>(cnt, deg, roff, cur, dinv);
            k_scatter2<<<EE / 256, 256, 0, stream>>>(srcp, dstp, ewt, dinv, cur,
                                                     csr_src, csr_nrm);
            xin = x_seq + (size_t)step * NN * FIN;
        } else {
            k_ddeg<<<NN, 256, 0, stream>>>(yhat, dinv);
            k_dM<<<(NN * NN) / 256, 256, 0, stream>>>(yhat, dinv, Mm, Mb);
            xin = yhat;
        }

        // ======= encoder GRU (x: F=2, H: h_enc) =======
        if (sparse) k_spmm2<<<NN / 256, 256, 0, stream>>>(roff, csr_src, csr_nrm, xin, aggx);
        else        k_dmv2<<<NN, 256, 0, stream>>>(Mm, xin, aggx);
        if (sparse) {
            k_spmm_v<HE><<<NN / 4, 256, 0, stream>>>(roff, csr_src, csr_nrm, h_enc, aggh);
        } else {
            k_dmm_mf<HE><<<dim3(NN / 64, HE / 64, DMM_NZ), 256, 0, stream>>>(Mb, h_enc, pbuf);
            k_redks<HE, DMM_NZ><<<NN * HE / 4 / 256, 256, 0, stream>>>(pbuf, aggh);
        }
        k_zr_ks<<<dim3(NN / 64, 8, ZR_NZ), 256, 0, stream>>>(xin, FIN, aggx, h_enc, aggh,
                                                             encWx, encWh, pbuf);
        k_zr_ep<<<NN * 512 / 4 / 256, 256, 0, stream>>>(pbuf, encbx, encbh, h_enc, gz, hr);
        if (sparse) {
            k_spmm_v<HE><<<NN / 4, 256, 0, stream>>>(roff, csr_src, csr_nrm, hr, agghr);
        } else {
            k_dmm_mf<HE><<<dim3(NN / 64, HE / 64, DMM_NZ), 256, 0, stream>>>(Mb, hr, pbuf);
            k_redks<HE, DMM_NZ><<<NN * HE / 4 / 256, 256, 0, stream>>>(pbuf, agghr);
        }
        k_gt_ks<<<dim3(NN / 64, 4, GT_NZ), 256, 0, stream>>>(xin, FIN, aggx, hr, agghr,
                                                             encWx + 4 * FIN * HE,
                                                             encWh + 4 * HE * HE, pbuf);
        k_gt_ep<<<NN * HE / 4 / 256, 256, 0, stream>>>(pbuf, encbx + 2 * HE,
                                                       encbh + 2 * HE, gz, h_enc);
        k_lin_ks<<<dim3(NN / 64, 2, LIN_NZ), 256, 0, stream>>>(h_enc, elinW, pbuf);
        k_lin_ep<<<NN * LT / 4 / 256, 256, 0, stream>>>(pbuf, elinb, zlat);

        // ======= decoder GRU (x: zlat F=128, H: h_dec) =======
        if (sparse) {
            k_spmm_v<LT><<<NN / 4, 256, 0, stream>>>(roff, csr_src, csr_nrm, zlat, aggx);
        } else {
            k_dmm_mf<LT><<<dim3(NN / 64, LT / 64, DMM_NZ), 256, 0, stream>>>(Mb, zlat, pbuf);
            k_redks<LT, DMM_NZ><<<NN * LT / 4 / 256, 256, 0, stream>>>(pbuf, aggx);
        }
        if (sparse) {
            k_spmm_v<HE><<<NN / 4, 256, 0, stream>>>(roff, csr_src, csr_nrm, h_dec, aggh);
        } else {
            k_dmm_mf<HE><<<dim3(NN / 64, HE / 64, DMM_NZ), 256, 0, stream>>>(Mb, h_dec, pbuf);
            k_redks<HE, DMM_NZ><<<NN * HE / 4 / 256, 256, 0, stream>>>(pbuf, aggh);
        }
        k_zr_ks<<<dim3(NN / 64, 8, ZR_NZ), 256, 0, stream>>>(zlat, LT, aggx, h_dec, aggh,
                                                             decWx, decWh, pbuf);
        k_zr_ep<<<NN * 512 / 4 / 256, 256, 0, stream>>>(pbuf, decbx, decbh, h_dec, gz, hr);
        if (sparse) {
            k_spmm_v<HE><<<NN / 4, 256, 0, stream>>>(roff, csr_src, csr_nrm, hr, agghr);
        } else {
            k_dmm_mf<HE><<<dim3(NN / 64, HE / 64, DMM_NZ), 256, 0, stream>>>(Mb, hr, pbuf);
            k_redks<HE, DMM_NZ><<<NN * HE / 4 / 256, 256, 0, stream>>>(pbuf, agghr);
        }
        k_gt_ks<<<dim3(NN / 64, 4, GT_NZ), 256, 0, stream>>>(zlat, LT, aggx, hr, agghr,
                                                             decWx + 4 * LT * HE,
                                                             decWh + 4 * HE * HE, pbuf);
        k_gt_ep<<<NN * HE / 4 / 256, 256, 0, stream>>>(pbuf, decbx + 2 * HE,
                                                       decbh + 2 * HE, gz, h_dec);
        k_declin<<<NN / 4, 256, 0, stream>>>(h_dec, dlinW, dlinb, yhat);

        if (step >= T_OBS - 1) {
            hipMemcpyAsync(out + (size_t)(step - (T_OBS - 1)) * NN * FIN, yhat,
                           sizeof(float) * NN * FIN, hipMemcpyDeviceToDevice, stream);
        }
    }
}

// Round 8
// 1982.859 us; speedup vs baseline: 7.0329x; 1.4172x over previous
//
#include <hip/hip_runtime.h>
#include <math.h>

#define NN 2048
#define EE 65536
#define T_OBS 6
#define FIN 2
#define HE 256
#define LT 128
#define PREDN 6
#define DMM_NZ 8
#define ZR_NZ 4
#define GT_NZ 8
#define LIN_NZ 8

typedef __attribute__((ext_vector_type(8))) short short8v;
typedef __attribute__((ext_vector_type(4))) float float4v;

static __device__ __forceinline__ unsigned short f2bf(float f) {
    union { float f; unsigned u; } v; v.f = f;
    unsigned r = v.u + 0x7fff + ((v.u >> 16) & 1);
    return (unsigned short)(r >> 16);
}

// truncation split: f ~= hi + lo, |err| <= 2^-16 |f|
static __device__ __forceinline__ void bfsplit(float f, unsigned short& h,
                                               unsigned short& l) {
    unsigned u = __float_as_uint(f);
    h = (unsigned short)(u >> 16);
    float hf = __uint_as_float(u & 0xffff0000u);
    l = (unsigned short)(__float_as_uint(f - hf) >> 16);
}

// ---------------- sparse graph prep ----------------
__global__ void k_degcnt(const int* __restrict__ src, const int* __restrict__ dst,
                         const float* __restrict__ ew,
                         float* __restrict__ deg, int* __restrict__ cnt) {
    int e = blockIdx.x * blockDim.x + threadIdx.x;
    if (e < EE) {
        atomicAdd(&deg[src[e]], ew[e]);
        atomicAdd(&cnt[dst[e]], 1);
    }
}

__global__ void k_scan(const int* __restrict__ cnt, const float* __restrict__ deg,
                       int* __restrict__ roff, int* __restrict__ cur,
                       float* __restrict__ dinv) {
    __shared__ int part[256];
    int t = threadIdx.x;
#pragma unroll
    for (int i = t; i < NN; i += 256) {
        float d = deg[i];
        dinv[i] = d > 0.f ? 1.f / sqrtf(d) : 0.f;
    }
    int loc[8];
    int s = 0;
#pragma unroll
    for (int i = 0; i < 8; i++) { loc[i] = cnt[t * 8 + i]; s += loc[i]; }
    part[t] = s;
    __syncthreads();
    for (int off = 1; off < 256; off <<= 1) {
        int v = (t >= off) ? part[t - off] : 0;
        __syncthreads();
        part[t] += v;
        __syncthreads();
    }
    int run = (t == 0) ? 0 : part[t - 1];
#pragma unroll
    for (int i = 0; i < 8; i++) {
        int idx = t * 8 + i;
        roff[idx] = run;
        cur[idx] = run;
        run += loc[i];
    }
    if (t == 255) roff[NN] = run;
}

__global__ void k_scatter2(const int* __restrict__ src, const int* __restrict__ dst,
                           const float* __restrict__ ew, const float* __restrict__ dinv,
                           int* __restrict__ cur,
                           int* __restrict__ csr_src, float* __restrict__ csr_nrm) {
    int e = blockIdx.x * blockDim.x + threadIdx.x;
    if (e < EE) {
        int s = src[e], d = dst[e];
        int p = atomicAdd(&cur[d], 1);
        csr_src[p] = s;
        csr_nrm[p] = -dinv[s] * ew[e] * dinv[d];
    }
}

// CSR SpMM, wave per node, float4 per lane, 8 edges batched
template <int F>
__global__ void k_spmm_v(const int* __restrict__ roff, const int* __restrict__ csr_src,
                         const float* __restrict__ csr_nrm,
                         const float* __restrict__ X, float* __restrict__ out) {
    int w = threadIdx.x >> 6, lane = threadIdx.x & 63;
    int nid = (blockIdx.x << 2) + w;
    int c = lane << 2;
    int s0 = roff[nid], s1 = roff[nid + 1];
    float4 acc = make_float4(0.f, 0.f, 0.f, 0.f);
    int s = s0;
    for (; s + 8 <= s1; s += 8) {
        int is[8]; float ws[8];
#pragma unroll
        for (int j = 0; j < 8; j++) { is[j] = csr_src[s + j]; ws[j] = csr_nrm[s + j]; }
        if (c < F) {
            float4 xv[8];
#pragma unroll
            for (int j = 0; j < 8; j++) xv[j] = *(const float4*)&X[(size_t)is[j] * F + c];
#pragma unroll
            for (int j = 0; j < 8; j++) {
                acc.x = fmaf(ws[j], xv[j].x, acc.x);
                acc.y = fmaf(ws[j], xv[j].y, acc.y);
                acc.z = fmaf(ws[j], xv[j].z, acc.z);
                acc.w = fmaf(ws[j], xv[j].w, acc.w);
            }
        }
    }
    for (; s < s1; ++s) {
        int i0 = csr_src[s]; float w0 = csr_nrm[s];
        if (c < F) {
            float4 xv = *(const float4*)&X[(size_t)i0 * F + c];
            acc.x = fmaf(w0, xv.x, acc.x);
            acc.y = fmaf(w0, xv.y, acc.y);
            acc.z = fmaf(w0, xv.z, acc.z);
            acc.w = fmaf(w0, xv.w, acc.w);
        }
    }
    if (c < F) *(float4*)&out[(size_t)nid * F + c] = acc;
}

__global__ void k_spmm2(const int* __restrict__ roff, const int* __restrict__ csr_src,
                        const float* __restrict__ csr_nrm,
                        const float* __restrict__ X, float* __restrict__ out) {
    int nid = blockIdx.x * blockDim.x + threadIdx.x;
    if (nid < NN) {
        int s0 = roff[nid], s1 = roff[nid + 1];
        float a0 = 0.f, a1 = 0.f;
        for (int s = s0; s < s1; ++s) {
            int i = csr_src[s]; float w = csr_nrm[s];
            float2 xv = *(const float2*)&X[2 * i];
            a0 = fmaf(w, xv.x, a0);
            a1 = fmaf(w, xv.y, a1);
        }
        out[2 * nid] = a0;
        out[2 * nid + 1] = a1;
    }
}

// ---------------- dense graph prep (rollout) ----------------
__global__ void k_ddeg(const float* __restrict__ c, float* __restrict__ dinv) {
    int i = blockIdx.x;
    int t = threadIdx.x;
    float xi = c[2 * i], yi = c[2 * i + 1];
    float s = 0.f;
    for (int j = t; j < NN; j += 256) {
        float dx = xi - c[2 * j], dy = yi - c[2 * j + 1];
        float d = sqrtf(dx * dx + dy * dy);
        if (d > 0.f && d < 0.5f) s += 2.f * d;
    }
    __shared__ float red[256];
    red[t] = s;
    __syncthreads();
    for (int off = 128; off > 0; off >>= 1) {
        if (t < off) red[t] += red[t + off];
        __syncthreads();
    }
    if (t == 0) {
        float d = red[0];
        dinv[i] = d > 0.f ? 1.f / sqrtf(d) : 0.f;
    }
}

__global__ void k_dM(const float* __restrict__ c, const float* __restrict__ dinv,
                     float* __restrict__ M, unsigned short* __restrict__ Mb) {
    int idx = blockIdx.x * blockDim.x + threadIdx.x;
    int i = idx >> 11, j = idx & (NN - 1);
    float dx = c[2 * i] - c[2 * j], dy = c[2 * i + 1] - c[2 * j + 1];
    float d = sqrtf(dx * dx + dy * dy);
    float w = (d > 0.f && d < 0.5f) ? 2.f * d : 0.f;
    float v = -(dinv[i] * w) * dinv[j];
    M[idx] = v;
    Mb[idx] = f2bf(v);
}

// dense agg via bf16 MFMA (plain bf16; M,X small-magnitude => safe)
template <int F>
__global__ __launch_bounds__(256) void k_dmm_mf(
    const unsigned short* __restrict__ Mb, const float* __restrict__ X,
    float* __restrict__ pbuf)
{
    __shared__ __align__(16) unsigned short Ms[64][72];
    __shared__ __align__(16) unsigned short Xs[64][72];
    const int tid = threadIdx.x;
    const int wid = tid >> 6, lane = tid & 63;
    const int m0 = blockIdx.x << 6, n0 = blockIdx.y << 6;
    const int kb0 = blockIdx.z << 8;
    const int lr = lane & 15;
    const int kg = lane >> 4;
    float4v acc[4];
#pragma unroll
    for (int t = 0; t < 4; t++) acc[t] = (float4v){0.f, 0.f, 0.f, 0.f};

    for (int kb = kb0; kb < kb0 + 256; kb += 64) {
#pragma unroll
        for (int it = 0; it < 2; it++) {
            int i = tid + it * 256;
            int r = i >> 3, c8 = (i & 7) << 3;
            *(short8v*)&Ms[r][c8] =
                *(const short8v*)&Mb[(size_t)(m0 + r) * NN + kb + c8];
        }
#pragma unroll
        for (int it = 0; it < 2; it++) {
            int i = tid + it * 256;
            int k2 = (i & 31) << 1;
            int n4 = (i >> 5) << 2;
            float4 va = *(const float4*)&X[(size_t)(kb + k2) * F + n0 + n4];
            float4 vb = *(const float4*)&X[(size_t)(kb + k2 + 1) * F + n0 + n4];
            unsigned pk;
            pk = (unsigned)f2bf(va.x) | ((unsigned)f2bf(vb.x) << 16);
            *(unsigned*)&Xs[n4 + 0][k2] = pk;
            pk = (unsigned)f2bf(va.y) | ((unsigned)f2bf(vb.y) << 16);
            *(unsigned*)&Xs[n4 + 1][k2] = pk;
            pk = (unsigned)f2bf(va.z) | ((unsigned)f2bf(vb.z) << 16);
            *(unsigned*)&Xs[n4 + 2][k2] = pk;
            pk = (unsigned)f2bf(va.w) | ((unsigned)f2bf(vb.w) << 16);
            *(unsigned*)&Xs[n4 + 3][k2] = pk;
        }
        __syncthreads();
#pragma unroll
        for (int kh = 0; kh < 2; kh++) {
            int kk = kh * 32 + kg * 8;
            short8v a = *(const short8v*)&Ms[(wid << 4) + lr][kk];
#pragma unroll
            for (int t = 0; t < 4; t++) {
                short8v b = *(const short8v*)&Xs[(t << 4) + lr][kk];
                acc[t] = __builtin_amdgcn_mfma_f32_16x16x32_bf16(a, b, acc[t], 0, 0, 0);
            }
        }
        __syncthreads();
    }
    float* p = pbuf + (size_t)blockIdx.z * NN * F;
#pragma unroll
    for (int t = 0; t < 4; t++)
#pragma unroll
        for (int j = 0; j < 4; j++)
            p[(size_t)(m0 + (wid << 4) + (kg << 2) + j) * F + n0 + (t << 4) + lr] =
                acc[t][j];
}

template <int F, int NZ>
__global__ void k_redks(const float* __restrict__ pbuf, float* __restrict__ out) {
    const int TOT = NN * F / 4;
    int i = blockIdx.x * blockDim.x + threadIdx.x;
    if (i < TOT) {
        const float4* p = (const float4*)pbuf;
        float4 s = p[i];
#pragma unroll
        for (int z = 1; z < NZ; z++) {
            float4 v = p[(size_t)z * TOT + i];
            s.x += v.x; s.y += v.y; s.z += v.z; s.w += v.w;
        }
        ((float4*)out)[i] = s;
    }
}

__global__ void k_dmv2(const float* __restrict__ M, const float* __restrict__ X,
                       float* __restrict__ out) {
    int i = blockIdx.x;
    int t = threadIdx.x;
    float a0 = 0.f, a1 = 0.f;
    for (int j = t; j < NN; j += 256) {
        float m = M[i * NN + j];
        a0 = fmaf(m, X[2 * j], a0);
        a1 = fmaf(m, X[2 * j + 1], a1);
    }
    __shared__ float r0[256], r1[256];
    r0[t] = a0;
    r1[t] = a1;
    __syncthreads();
    for (int off = 128; off > 0; off >>= 1) {
        if (t < off) { r0[t] += r0[t + off]; r1[t] += r1[t + off]; }
        __syncthreads();
    }
    if (t == 0) { out[2 * i] = r0[0]; out[2 * i + 1] = r1[0]; }
}

// ---------------- bf16x3 MFMA GEMM segment core ----------------
// acc += A[m0..m0+64, k-seg] @ B[k-seg, 64 cols]; A row-major fp32 (lda),
// B row-major fp32 (ldb, pre-offset to col tile). K multiple of 32.
// Split a = a_hi + a_lo, w = w_hi + w_lo; 3 MFMAs: hi*hi + hi*lo + lo*hi.
template <bool RELU>
__device__ __forceinline__ void mfma_seg(
    unsigned short (*Ah)[40], unsigned short (*Al)[40],
    unsigned short (*Bh)[40], unsigned short (*Bl)[40],
    const float* __restrict__ A, int lda,
    const float* __restrict__ B, int ldb, int K,
    int m0, int tid, int wid, int lr, int kg, float4v (&acc)[4])
{
    for (int k0 = 0; k0 < K; k0 += 32) {
        {   // stage A: 64 rows x 32 k, hi/lo
            int r = tid >> 2, k8 = (tid & 3) << 3;
            const float* ap = &A[(size_t)(m0 + r) * lda + k0 + k8];
            float4 va = *(const float4*)ap;
            float4 vb = *(const float4*)(ap + 4);
            float v[8] = {va.x, va.y, va.z, va.w, vb.x, vb.y, vb.z, vb.w};
            short8v hv, lv;
#pragma unroll
            for (int j = 0; j < 8; j++) {
                float f = RELU ? fmaxf(v[j], 0.f) : v[j];
                unsigned short h, l;
                bfsplit(f, h, l);
                hv[j] = (short)h; lv[j] = (short)l;
            }
            *(short8v*)&Ah[r][k8] = hv;
            *(short8v*)&Al[r][k8] = lv;
        }
        {   // stage B transposed: 64 cols x 32 k, hi/lo
            int k2 = (tid & 15) << 1;
            int n4 = (tid >> 4) << 2;
            const float* bp = &B[(size_t)(k0 + k2) * ldb + n4];
            float4 va = *(const float4*)bp;
            float4 vb = *(const float4*)(bp + ldb);
            float v0[4] = {va.x, va.y, va.z, va.w};
            float v1[4] = {vb.x, vb.y, vb.z, vb.w};
#pragma unroll
            for (int j = 0; j < 4; j++) {
                unsigned short h0, l0, h1, l1;
                bfsplit(v0[j], h0, l0);
                bfsplit(v1[j], h1, l1);
                *(unsigned*)&Bh[n4 + j][k2] = (unsigned)h0 | ((unsigned)h1 << 16);
                *(unsigned*)&Bl[n4 + j][k2] = (unsigned)l0 | ((unsigned)l1 << 16);
            }
        }
        __syncthreads();
        short8v ah = *(short8v*)&Ah[(wid << 4) + lr][kg << 3];
        short8v al = *(short8v*)&Al[(wid << 4) + lr][kg << 3];
#pragma unroll
        for (int t = 0; t < 4; t++) {
            short8v bh = *(short8v*)&Bh[(t << 4) + lr][kg << 3];
            short8v bl = *(short8v*)&Bl[(t << 4) + lr][kg << 3];
            acc[t] = __builtin_amdgcn_mfma_f32_16x16x32_bf16(ah, bh, acc[t], 0, 0, 0);
            acc[t] = __builtin_amdgcn_mfma_f32_16x16x32_bf16(ah, bl, acc[t], 0, 0, 0);
            acc[t] = __builtin_amdgcn_mfma_f32_16x16x32_bf16(al, bh, acc[t], 0, 0, 0);
        }
        __syncthreads();
    }
}

// z/r gates K-split (MFMA). K01 = 0 (enc: x-parts in epilogue) or LT (dec).
// grid (NN/64, 8, ZR_NZ); pbuf slab z: [NN][512]
__global__ __launch_bounds__(256) void k_zr_ks(
    const float* __restrict__ A0, int K01, const float* __restrict__ A1,
    const float* __restrict__ H, const float* __restrict__ A3,
    const float* __restrict__ Wx, const float* __restrict__ Wh,
    float* __restrict__ pbuf)
{
    __shared__ __align__(16) unsigned short Ah[64][40], Al[64][40],
                                            Bh[64][40], Bl[64][40];
    int tid = threadIdx.x;
    int wid = tid >> 6, lane = tid & 63, lr = lane & 15, kg = lane >> 4;
    int m0 = blockIdx.x << 6;
    int g = blockIdx.y >> 2;
    int n0 = (blockIdx.y & 3) << 6;
    float4v acc[4];
#pragma unroll
    for (int t = 0; t < 4; t++) acc[t] = (float4v){0.f, 0.f, 0.f, 0.f};
    const float* As[4] = {A0, A1, H, A3};
    const int ldas[4] = {K01, K01, HE, HE};
    const float* Bs[4] = {
        Wx + (size_t)(g * 2 + 0) * K01 * HE + n0,
        Wx + (size_t)(g * 2 + 1) * K01 * HE + n0,
        Wh + (size_t)(g * 2 + 0) * HE * HE + n0,
        Wh + (size_t)(g * 2 + 1) * HE * HE + n0};
    const int Ks[4] = {K01, K01, HE, HE};
    int chunk = (2 * K01 + 2 * HE) / ZR_NZ;
    int lo = blockIdx.z * chunk, hi = lo + chunk;
    int off = 0;
#pragma unroll
    for (int s = 0; s < 4; s++) {
        int a = lo - off; a = a < 0 ? 0 : a;
        int b = hi - off; b = b > Ks[s] ? Ks[s] : b;
        if (b > a)
            mfma_seg<false>(Ah, Al, Bh, Bl, As[s] + a, ldas[s],
                            Bs[s] + (size_t)a * HE, HE, b - a,
                            m0, tid, wid, lr, kg, acc);
        off += Ks[s];
    }
    float* p = pbuf + (size_t)blockIdx.z * NN * 512;
    int cbase = (g << 8) + n0;
#pragma unroll
    for (int t = 0; t < 4; t++)
#pragma unroll
        for (int j = 0; j < 4; j++)
            p[(size_t)(m0 + (wid << 4) + (kg << 2) + j) * 512 + cbase + (t << 4) + lr] =
                acc[t][j];
}

// epilogue: + rank-2 (x,aggx) terms when Wx != nullptr (encoder)
__global__ void k_zr_ep(const float* __restrict__ pbuf,
                        const float* __restrict__ bx, const float* __restrict__ bh,
                        const float* __restrict__ H,
                        const float* __restrict__ x2, const float* __restrict__ ax2,
                        const float* __restrict__ Wx,
                        float* __restrict__ gz, float* __restrict__ hr)
{
    int i = blockIdx.x * 256 + threadIdx.x;  // < NN*512/4
    const float4* p = (const float4*)pbuf;
    const size_t S = (size_t)NN * 512 / 4;
    float4 a = p[i];
#pragma unroll
    for (int z = 1; z < ZR_NZ; z++) {
        float4 v = p[(size_t)z * S + i];
        a.x += v.x; a.y += v.y; a.z += v.z; a.w += v.w;
    }
    int row = i >> 7, c = (i & 127) << 2;
    int g = c >> 8, cc = c & 255;
    if (Wx) {
        float x0 = x2[2 * row], x1 = x2[2 * row + 1];
        float q0 = ax2[2 * row], q1 = ax2[2 * row + 1];
        const float* W0 = Wx + (size_t)(g * 2 + 0) * FIN * HE;
        const float* W1 = Wx + (size_t)(g * 2 + 1) * FIN * HE;
        float4 w00 = *(const float4*)&W0[cc];
        float4 w01 = *(const float4*)&W0[HE + cc];
        float4 w10 = *(const float4*)&W1[cc];
        float4 w11 = *(const float4*)&W1[HE + cc];
        a.x += x0 * w00.x + x1 * w01.x + q0 * w10.x + q1 * w11.x;
        a.y += x0 * w00.y + x1 * w01.y + q0 * w10.y + q1 * w11.y;
        a.z += x0 * w00.z + x1 * w01.z + q0 * w10.z + q1 * w11.z;
        a.w += x0 * w00.w + x1 * w01.w + q0 * w10.w + q1 * w11.w;
    }
    float4 b0 = *(const float4*)&bx[c];
    float4 b1 = *(const float4*)&bh[c];
    float4 s;
    s.x = 1.f / (1.f + expf(-(a.x + b0.x + b1.x)));
    s.y = 1.f / (1.f + expf(-(a.y + b0.y + b1.y)));
    s.z = 1.f / (1.f + expf(-(a.z + b0.z + b1.z)));
    s.w = 1.f / (1.f + expf(-(a.w + b0.w + b1.w)));
    if (c < HE) {
        *(float4*)&gz[(size_t)row * HE + c] = s;
    } else {
        float4 h = *(const float4*)&H[(size_t)row * HE + cc];
        s.x *= h.x; s.y *= h.y; s.z *= h.z; s.w *= h.w;
        *(float4*)&hr[(size_t)row * HE + cc] = s;
    }
}

// candidate gate K-split (MFMA). grid (NN/64, 4, GT_NZ); slab z: [NN][256]
__global__ __launch_bounds__(256) void k_gt_ks(
    const float* __restrict__ A0, int K01, const float* __restrict__ A1,
    const float* __restrict__ hr, const float* __restrict__ A3,
    const float* __restrict__ Wx2, const float* __restrict__ Wh2,
    float* __restrict__ pbuf)
{
    __shared__ __align__(16) unsigned short Ah[64][40], Al[64][40],
                                            Bh[64][40], Bl[64][40];
    int tid = threadIdx.x;
    int wid = tid >> 6, lane = tid & 63, lr = lane & 15, kg = lane >> 4;
    int m0 = blockIdx.x << 6;
    int n0 = blockIdx.y << 6;
    float4v acc[4];
#pragma unroll
    for (int t = 0; t < 4; t++) acc[t] = (float4v){0.f, 0.f, 0.f, 0.f};
    const float* As[4] = {A0, A1, hr, A3};
    const int ldas[4] = {K01, K01, HE, HE};
    const float* Bs[4] = {
        Wx2 + n0,
        Wx2 + (size_t)K01 * HE + n0,
        Wh2 + n0,
        Wh2 + (size_t)HE * HE + n0};
    const int Ks[4] = {K01, K01, HE, HE};
    int chunk = (2 * K01 + 2 * HE) / GT_NZ;
    int lo = blockIdx.z * chunk, hi = lo + chunk;
    int off = 0;
#pragma unroll
    for (int s = 0; s < 4; s++) {
        int a = lo - off; a = a < 0 ? 0 : a;
        int b = hi - off; b = b > Ks[s] ? Ks[s] : b;
        if (b > a)
            mfma_seg<false>(Ah, Al, Bh, Bl, As[s] + a, ldas[s],
                            Bs[s] + (size_t)a * HE, HE, b - a,
                            m0, tid, wid, lr, kg, acc);
        off += Ks[s];
    }
    float* p = pbuf + (size_t)blockIdx.z * NN * HE;
#pragma unroll
    for (int t = 0; t < 4; t++)
#pragma unroll
        for (int j = 0; j < 4; j++)
            p[(size_t)(m0 + (wid << 4) + (kg << 2) + j) * HE + n0 + (t << 4) + lr] =
                acc[t][j];
}

// epilogue: H = z*H + (1-z)*tanh(sum + rank2 + b); rank2 when Wx2 != nullptr
__global__ void k_gt_ep(const float* __restrict__ pbuf,
                        const float* __restrict__ bx2, const float* __restrict__ bh2,
                        const float* __restrict__ gz,
                        const float* __restrict__ x2, const float* __restrict__ ax2,
                        const float* __restrict__ Wx2,
                        float* __restrict__ H)
{
    int i = blockIdx.x * 256 + threadIdx.x;  // < NN*256/4
    const float4* p = (const float4*)pbuf;
    const size_t S = (size_t)NN * HE / 4;
    float4 a = p[i];
#pragma unroll
    for (int z = 1; z < GT_NZ; z++) {
        float4 v = p[(size_t)z * S + i];
        a.x += v.x; a.y += v.y; a.z += v.z; a.w += v.w;
    }
    int row = i >> 6, c = (i & 63) << 2;
    if (Wx2) {
        float x0 = x2[2 * row], x1 = x2[2 * row + 1];
        float q0 = ax2[2 * row], q1 = ax2[2 * row + 1];
        float4 w00 = *(const float4*)&Wx2[c];
        float4 w01 = *(const float4*)&Wx2[HE + c];
        float4 w10 = *(const float4*)&Wx2[2 * HE + c];
        float4 w11 = *(const float4*)&Wx2[3 * HE + c];
        a.x += x0 * w00.x + x1 * w01.x + q0 * w10.x + q1 * w11.x;
        a.y += x0 * w00.y + x1 * w01.y + q0 * w10.y + q1 * w11.y;
        a.z += x0 * w00.z + x1 * w01.z + q0 * w10.z + q1 * w11.z;
        a.w += x0 * w00.w + x1 * w01.w + q0 * w10.w + q1 * w11.w;
    }
    float4 b0 = *(const float4*)&bx2[c];
    float4 b1 = *(const float4*)&bh2[c];
    size_t idx = (size_t)row * HE + c;
    float4 z = *(const float4*)&gz[idx];
    float4 h = *(const float4*)&H[idx];
    float4 o;
    o.x = z.x * h.x + (1.f - z.x) * tanhf(a.x + b0.x + b1.x);
    o.y = z.y * h.y + (1.f - z.y) * tanhf(a.y + b0.y + b1.y);
    o.z = z.z * h.z + (1.f - z.z) * tanhf(a.z + b0.z + b1.z);
    o.w = z.w * h.w + (1.f - z.w) * tanhf(a.w + b0.w + b1.w);
    *(float4*)&H[idx] = o;
}

// latent linear K-split (MFMA, relu on A): grid (NN/64, 2, LIN_NZ); slab [NN][128]
__global__ __launch_bounds__(256) void k_lin_ks(
    const float* __restrict__ A, const float* __restrict__ B,
    float* __restrict__ pbuf)
{
    __shared__ __align__(16) unsigned short Ah[64][40], Al[64][40],
                                            Bh[64][40], Bl[64][40];
    int tid = threadIdx.x;
    int wid = tid >> 6, lane = tid & 63, lr = lane & 15, kg = lane >> 4;
    int m0 = blockIdx.x << 6;
    int n0 = blockIdx.y << 6;
    int lo = blockIdx.z << 5;  // 32 per slice
    float4v acc[4];
#pragma unroll
    for (int t = 0; t < 4; t++) acc[t] = (float4v){0.f, 0.f, 0.f, 0.f};
    mfma_seg<true>(Ah, Al, Bh, Bl, A + lo, HE, B + (size_t)lo * LT + n0, LT, 32,
                   m0, tid, wid, lr, kg, acc);
    float* p = pbuf + (size_t)blockIdx.z * NN * LT;
#pragma unroll
    for (int t = 0; t < 4; t++)
#pragma unroll
        for (int j = 0; j < 4; j++)
            p[(size_t)(m0 + (wid << 4) + (kg << 2) + j) * LT + n0 + (t << 4) + lr] =
                acc[t][j];
}

__global__ void k_lin_ep(const float* __restrict__ pbuf,
                         const float* __restrict__ bias, float* __restrict__ out)
{
    int i = blockIdx.x * 256 + threadIdx.x;  // < NN*128/4
    const float4* p = (const float4*)pbuf;
    const size_t S = (size_t)NN * LT / 4;
    int c = (i & 31) << 2;
    float4 bb = *(const float4*)&bias[c];
    float4 s = make_float4(bb.x, bb.y, bb.z, bb.w);
#pragma unroll
    for (int z = 0; z < LIN_NZ; z++) {
        float4 v = p[z * S + i];
        s.x += v.x; s.y += v.y; s.z += v.z; s.w += v.w;
    }
    ((float4*)out)[i] = s;
}

// y_hat = relu(H) @ dlinW + dlinb : one wave per row
__global__ void k_declin(const float* __restrict__ A, const float* __restrict__ B,
                         const float* __restrict__ bias, float* __restrict__ out) {
    int w = threadIdx.x >> 6, lane = threadIdx.x & 63;
    int m = blockIdx.x * 4 + w;
    float4 a = *(const float4*)&A[(size_t)m * HE + (lane << 2)];
    float av[4] = {a.x, a.y, a.z, a.w};
    float a0 = 0.f, a1 = 0.f;
#pragma unroll
    for (int j = 0; j < 4; j++) {
        float v = fmaxf(av[j], 0.f);
        float2 b = *(const float2*)&B[((lane << 2) + j) * 2];
        a0 = fmaf(v, b.x, a0);
        a1 = fmaf(v, b.y, a1);
    }
    for (int off = 32; off > 0; off >>= 1) {
        a0 += __shfl_down(a0, off, 64);
        a1 += __shfl_down(a1, off, 64);
    }
    if (lane == 0) {
        out[2 * m] = a0 + bias[0];
        out[2 * m + 1] = a1 + bias[1];
    }
}

extern "C" void kernel_launch(void* const* d_in, const int* in_sizes, int n_in,
                              void* d_out, int out_size, void* d_ws, size_t ws_size,
                              hipStream_t stream) {
    (void)in_sizes; (void)n_in; (void)out_size; (void)ws_size;
    const float* x_seq = (const float*)d_in[0];
    const int* ei = (const int*)d_in[1];
    const float* ews = (const float*)d_in[2];
    const float* h_enc_in = (const float*)d_in[3];
    const float* h_dec_in = (const float*)d_in[4];
    const float* encWx = (const float*)d_in[5];
    const float* encbx = (const float*)d_in[6];
    const float* encWh = (const float*)d_in[7];
    const float* encbh = (const float*)d_in[8];
    const float* elinW = (const float*)d_in[9];
    const float* elinb = (const float*)d_in[10];
    const float* decWx = (const float*)d_in[11];
    const float* decbx = (const float*)d_in[12];
    const float* decWh = (const float*)d_in[13];
    const float* decbh = (const float*)d_in[14];
    const float* dlinW = (const float*)d_in[15];
    const float* dlinb = (const float*)d_in[16];
    float* out = (float*)d_out;

    float* W = (float*)d_ws;
    float* h_enc = W; W += (size_t)NN * HE;
    float* h_dec = W; W += (size_t)NN * HE;
    float* aggx  = W; W += (size_t)NN * HE;
    float* aggh  = W; W += (size_t)NN * HE;
    float* hr    = W; W += (size_t)NN * HE;
    float* agghr = W; W += (size_t)NN * HE;
    float* gz    = W; W += (size_t)NN * HE;
    float* zlat  = W; W += (size_t)NN * LT;
    float* yhat  = W; W += (size_t)NN * FIN;
    float* deg   = W; W += NN;          // deg + cnt adjacent: one memset
    int*   cnt   = (int*)W; W += NN;
    float* dinv  = W; W += NN;
    float* csr_nrm = W; W += EE;
    float* Mm    = W; W += (size_t)NN * NN;
    unsigned short* Mb = (unsigned short*)W; W += (size_t)NN * NN / 2;
    float* pbuf  = W; W += (size_t)ZR_NZ * NN * 512;  // 16 MB, shared by all K-splits
    int* roff = (int*)W;
    int* cur  = roff + (NN + 2);
    int* csr_src = cur + NN;

    hipMemcpyAsync(h_enc, h_enc_in, sizeof(float) * NN * HE, hipMemcpyDeviceToDevice, stream);
    hipMemcpyAsync(h_dec, h_dec_in, sizeof(float) * NN * HE, hipMemcpyDeviceToDevice, stream);

    for (int step = 0; step < T_OBS + PREDN - 1; ++step) {
        bool sparse = step < T_OBS;
        const float* xin;
        if (sparse) {
            const int* srcp = ei + (size_t)step * 2 * EE;
            const int* dstp = srcp + EE;
            const float* ewt = ews + (size_t)step * EE;
            hipMemsetAsync(deg, 0, sizeof(float) * NN * 2, stream);  // deg + cnt
            k_degcnt<<<EE / 256, 256, 0, stream>>>(srcp, dstp, ewt, deg, cnt);
            k_scan<<<1, 256, 0, stream>>>(cnt, deg, roff, cur, dinv);
            k_scatter2<<<EE / 256, 256, 0, stream>>>(srcp, dstp, ewt, dinv, cur,
                                                     csr_src, csr_nrm);
            xin = x_seq + (size_t)step * NN * FIN;
        } else {
            k_ddeg<<<NN, 256, 0, stream>>>(yhat, dinv);
            k_dM<<<(NN * NN) / 256, 256, 0, stream>>>(yhat, dinv, Mm, Mb);
            xin = yhat;
        }

        // ======= encoder GRU (x: F=2 via rank-2 epilogue, H: h_enc) =======
        if (sparse) k_spmm2<<<NN / 256, 256, 0, stream>>>(roff, csr_src, csr_nrm, xin, aggx);
        else        k_dmv2<<<NN, 256, 0, stream>>>(Mm, xin, aggx);
        if (sparse) {
            k_spmm_v<HE><<<NN / 4, 256, 0, stream>>>(roff, csr_src, csr_nrm, h_enc, aggh);
        } else {
            k_dmm_mf<HE><<<dim3(NN / 64, HE / 64, DMM_NZ), 256, 0, stream>>>(Mb, h_enc, pbuf);
            k_redks<HE, DMM_NZ><<<NN * HE / 4 / 256, 256, 0, stream>>>(pbuf, aggh);
        }
        k_zr_ks<<<dim3(NN / 64, 8, ZR_NZ), 256, 0, stream>>>(xin, 0, aggx, h_enc, aggh,
                                                             encWx, encWh, pbuf);
        k_zr_ep<<<NN * 512 / 4 / 256, 256, 0, stream>>>(pbuf, encbx, encbh, h_enc,
                                                        xin, aggx, encWx, gz, hr);
        if (sparse) {
            k_spmm_v<HE><<<NN / 4, 256, 0, stream>>>(roff, csr_src, csr_nrm, hr, agghr);
        } else {
            k_dmm_mf<HE><<<dim3(NN / 64, HE / 64, DMM_NZ), 256, 0, stream>>>(Mb, hr, pbuf);
            k_redks<HE, DMM_NZ><<<NN * HE / 4 / 256, 256, 0, stream>>>(pbuf, agghr);
        }
        k_gt_ks<<<dim3(NN / 64, 4, GT_NZ), 256, 0, stream>>>(xin, 0, aggx, hr, agghr,
                                                             encWx + 4 * FIN * HE,
                                                             encWh + 4 * HE * HE, pbuf);
        k_gt_ep<<<NN * HE / 4 / 256, 256, 0, stream>>>(pbuf, encbx + 2 * HE,
                                                       encbh + 2 * HE, gz,
                                                       xin, aggx, encWx + 4 * FIN * HE,
                                                       h_enc);
        k_lin_ks<<<dim3(NN / 64, 2, LIN_NZ), 256, 0, stream>>>(h_enc, elinW, pbuf);
        k_lin_ep<<<NN * LT / 4 / 256, 256, 0, stream>>>(pbuf, elinb, zlat);

        // ======= decoder GRU (x: zlat F=128, H: h_dec) =======
        if (sparse) {
            k_spmm_v<LT><<<NN / 4, 256, 0, stream>>>(roff, csr_src, csr_nrm, zlat, aggx);
        } else {
            k_dmm_mf<LT><<<dim3(NN / 64, LT / 64, DMM_NZ), 256, 0, stream>>>(Mb, zlat, pbuf);
            k_redks<LT, DMM_NZ><<<NN * LT / 4 / 256, 256, 0, stream>>>(pbuf, aggx);
        }
        if (sparse) {
            k_spmm_v<HE><<<NN / 4, 256, 0, stream>>>(roff, csr_src, csr_nrm, h_dec, aggh);
        } else {
            k_dmm_mf<HE><<<dim3(NN / 64, HE / 64, DMM_NZ), 256, 0, stream>>>(Mb, h_dec, pbuf);
            k_redks<HE, DMM_NZ><<<NN * HE / 4 / 256, 256, 0, stream>>>(pbuf, aggh);
        }
        k_zr_ks<<<dim3(NN / 64, 8, ZR_NZ), 256, 0, stream>>>(zlat, LT, aggx, h_dec, aggh,
                                                             decWx, decWh, pbuf);
        k_zr_ep<<<NN * 512 / 4 / 256, 256, 0, stream>>>(pbuf, decbx, decbh, h_dec,
                                                        nullptr, nullptr, nullptr, gz, hr);
        if (sparse) {
            k_spmm_v<HE><<<NN / 4, 256, 0, stream>>>(roff, csr_src, csr_nrm, hr, agghr);
        } else {
            k_dmm_mf<HE><<<dim3(NN / 64, HE / 64, DMM_NZ), 256, 0, stream>>>(Mb, hr, pbuf);
            k_redks<HE, DMM_NZ><<<NN * HE / 4 / 256, 256, 0, stream>>>(pbuf, agghr);
        }
        k_gt_ks<<<dim3(NN / 64, 4, GT_NZ), 256, 0, stream>>>(zlat, LT, aggx, hr, agghr,
                                                             decWx + 4 * LT * HE,
                                                             decWh + 4 * HE * HE, pbuf);
        k_gt_ep<<<NN * HE / 4 / 256, 256, 0, stream>>>(pbuf, decbx + 2 * HE,
                                                       decbh + 2 * HE, gz,
                                                       nullptr, nullptr, nullptr,
                                                       h_dec);
        k_declin<<<NN / 4, 256, 0, stream>>>(h_dec, dlinW, dlinb, yhat);

        if (step >= T_OBS - 1) {
            hipMemcpyAsync(out + (size_t)(step - (T_OBS - 1)) * NN * FIN, yhat,
                           sizeof(float) * NN * FIN, hipMemcpyDeviceToDevice, stream);
        }
    }
}